// Round 11
// baseline (259.395 us; speedup 1.0000x reference)
//
#include <hip/hip_runtime.h>
#include <hip/hip_bf16.h>
#include <math.h>

#define BG 8
#define NNODES 256
#define KNN 16
#define NG 12
#define CH 128
#define MTOT 2048
#define TWO_PI_F 6.283185307179586f

typedef __attribute__((ext_vector_type(8))) short bfrag;
typedef __attribute__((ext_vector_type(4))) float f32x4;

// ---------- helpers ----------

__device__ __forceinline__ float gelu_t(float x) {
  float x3 = x * x * x;
  float y = 0.7978845608028654f * (x + 0.044715f * x3);
  float e = __expf(2.0f * y);
  float th = 1.0f - 2.0f / (e + 1.0f);
  return 0.5f * x * (1.0f + th);
}

__device__ __forceinline__ unsigned packbf2(float a, float b) {
  unsigned ua = __float_as_uint(a), ub = __float_as_uint(b);
  ua = (ua + 0x7fffu + ((ua >> 16) & 1u)) >> 16;    // RNE to bf16
  ub = (ub + 0x7fffu + ((ub >> 16) & 1u)) >> 16;
  return ua | (ub << 16);
}
__device__ __forceinline__ unsigned short f2bf(float f) {
  unsigned u = __float_as_uint(f);
  u = (u + 0x7fffu + ((u >> 16) & 1u)) >> 16;
  return (unsigned short)u;
}
__device__ __forceinline__ float ubf_lo(unsigned p) { return __uint_as_float(p << 16); }
__device__ __forceinline__ float ubf_hi(unsigned p) { return __uint_as_float(p & 0xffff0000u); }

// gelu via sigmoid form; exp2-domain, ~7 insts
__device__ __forceinline__ float gelu_s(float x) {
  const float A  = -2.0f * 0.7978845608028654f * 1.4426950408889634f;
  const float CA = A * 0.044715f;
  float x2 = x * x;
  float q  = __builtin_fmaf(CA, x2, A);
  float t  = x * q;
  float e; asm("v_exp_f32 %0, %1" : "=v"(e) : "v"(t));     // 2^t
  float d = 1.0f + e;
  float r; asm("v_rcp_f32 %0, %1" : "=v"(r) : "v"(d));
  return x * r;
}

__device__ __forceinline__ unsigned pkcvt(float a, float b) {
  unsigned r;
  asm("v_cvt_pk_bf16_f32 %0, %1, %2" : "=v"(r) : "v"(a), "v"(b));
  return r;
}

__device__ __forceinline__ void cossin(float w, float& c, float& s) {
  float f; asm("v_fract_f32 %0, %1" : "=v"(f) : "v"(w));
  asm("v_cos_f32 %0, %1" : "=v"(c) : "v"(f));
  asm("v_sin_f32 %0, %1" : "=v"(s) : "v"(f));
}

__device__ __forceinline__ unsigned long long shfl_xor64(unsigned long long v, int st) {
  unsigned lo = (unsigned)v, hi = (unsigned)(v >> 32);
  lo = __shfl_xor(lo, st, 64);
  hi = __shfl_xor(hi, st, 64);
  return ((unsigned long long)hi << 32) | lo;
}

// ---------- kNN: one wave per node ----------

__global__ __launch_bounds__(256) void knn_kernel(const float* __restrict__ pos,
                                                  int* __restrict__ knn) {
  __shared__ float sx[NNODES], sy[NNODES], sz[NNODES];
  int w = threadIdx.x >> 6, lane = threadIdx.x & 63;
  int node = blockIdx.x * 4 + w;
  int b = node >> 8;
  int gbase = b * NNODES;
  int t = threadIdx.x;
  sx[t] = pos[(gbase + t) * 3 + 0];
  sy[t] = pos[(gbase + t) * 3 + 1];
  sz[t] = pos[(gbase + t) * 3 + 2];
  __syncthreads();
  int i = node & 255;
  float xi = sx[i], yi = sy[i], zi = sz[i];
  unsigned long long key[4];
#pragma unroll
  for (int u = 0; u < 4; ++u) {
    int j = lane * 4 + u;
    float dx = xi - sx[j], dy = yi - sy[j], dz = zi - sz[j];
    float d = dx * dx + dy * dy + dz * dz;
    key[u] = ((unsigned long long)__float_as_uint(d) << 32) | (unsigned)j;
  }
  {
    unsigned long long tmp;
#define CSWAP(a, bq) if (key[bq] < key[a]) { tmp = key[a]; key[a] = key[bq]; key[bq] = tmp; }
    CSWAP(0, 1) CSWAP(2, 3) CSWAP(0, 2) CSWAP(1, 3) CSWAP(1, 2)
#undef CSWAP
  }
  int ptr = 0;
#pragma unroll 1
  for (int r = 0; r < KNN; ++r) {
    unsigned long long cand = (ptr < 4) ? key[ptr] : ~0ULL;
    unsigned long long mn = cand;
#pragma unroll
    for (int st = 1; st < 64; st <<= 1) {
      unsigned long long o = shfl_xor64(mn, st);
      if (o < mn) mn = o;
    }
    if (cand == mn) ptr++;
    if (lane == 0) knn[node * KNN + r] = gbase + (int)(mn & 0xffffffffu);
  }
}

// ---------- kb_R -> kR ----------

__global__ void kbr_kernel(const float* __restrict__ grid, const float* __restrict__ BR,
                           const float* __restrict__ WR1, const float* __restrict__ bR1,
                           const float* __restrict__ WR2, const float* __restrict__ bR2,
                           const float* __restrict__ WkR1, const float* __restrict__ WkR2,
                           float* __restrict__ kR1, float* __restrict__ kR2) {
  int r = blockIdx.x;
  int p = r / NG, o = r % NG;
  int c = threadIdx.x;
  float a = grid[p * 3 + 0] * grid[o * 3 + 0] + grid[p * 3 + 1] * grid[o * 3 + 1] +
            grid[p * 3 + 2] * grid[o * 3 + 2];
  __shared__ float fb[CH], hh[CH];
  {
    int j = c & 63;
    float pv = TWO_PI_F * (a * BR[j]);
    fb[c] = (c < 64) ? cosf(pv) : sinf(pv);
  }
  __syncthreads();
  float acc = bR1[c];
  for (int i = 0; i < CH; ++i) acc += fb[i] * WR1[i * CH + c];
  float h1 = gelu_t(acc);
  __syncthreads();
  hh[c] = h1;
  __syncthreads();
  acc = bR2[c];
  for (int i = 0; i < CH; ++i) acc += hh[i] * WR2[i * CH + c];
  float h2 = gelu_t(acc);
  __syncthreads();
  fb[c] = h2;
  __syncthreads();
  float t1 = 0.f, t2 = 0.f;
  for (int i = 0; i < CH; ++i) {
    float v = fb[i];
    t1 += v * WkR1[i * CH + c];
    t2 += v * WkR2[i * CH + c];
  }
  kR1[r * CH + c] = t1;
  kR2[r * CH + c] = t2;
}

// ---------- fiber einsum (fallback path only) ----------

__global__ void einsum_kernel(const float* __restrict__ x1, const float* __restrict__ kR,
                              float* __restrict__ x2) {
  int m = blockIdx.x, c = threadIdx.x;
  float v[NG];
#pragma unroll
  for (int o = 0; o < NG; ++o) v[o] = x1[((size_t)m * NG + o) * CH + c];
#pragma unroll
  for (int p = 0; p < NG; ++p) {
    float acc = 0.f;
#pragma unroll
    for (int o = 0; o < NG; ++o) acc += v[o] * kR[(p * NG + o) * CH + c];
    x2[((size_t)m * NG + p) * CH + c] = acc * (1.0f / NG);
  }
}

// ---------- weight fragment packing (all 8 matrices, one launch) ----------
// fragment element (tile,ks,lane,j) = W[ks*32 + (lane>>4)*8 + j][tile*16 + (lane&15)]

__device__ __forceinline__ void pack_body(const float* __restrict__ W, int K, int N,
                                          unsigned short* __restrict__ out, int tid) {
  int lane = tid & 63;
  int t = tid >> 6;
  int ksteps = K / 32;
  int ks = t % ksteps, tile = t / ksteps;
  int col = tile * 16 + (lane & 15);
  int k0 = ks * 32 + (lane >> 4) * 8;
#pragma unroll
  for (int j = 0; j < 8; ++j)
    out[(size_t)tid * 8 + j] = f2bf(W[(size_t)(k0 + j) * N + col]);
}

__global__ __launch_bounds__(256) void pack_all_kernel(
    const float* __restrict__ W1a, const float* __restrict__ W2a,
    const float* __restrict__ W1b, const float* __restrict__ W2b,
    const float* __restrict__ wx1, const float* __restrict__ wx2,
    const float* __restrict__ wk1, const float* __restrict__ wk2,
    unsigned short* __restrict__ o1a, unsigned short* __restrict__ o2a,
    unsigned short* __restrict__ o1b, unsigned short* __restrict__ o2b,
    unsigned short* __restrict__ ox1, unsigned short* __restrict__ ox2,
    unsigned short* __restrict__ ok1, unsigned short* __restrict__ ok2) {
  int blk = blockIdx.x;
  if (blk < 32)        pack_body(W1a, CH, 4 * CH, o1a, blk * 256 + threadIdx.x);
  else if (blk < 64)   pack_body(W2a, 4 * CH, CH, o2a, (blk - 32) * 256 + threadIdx.x);
  else if (blk < 96)   pack_body(W1b, CH, 4 * CH, o1b, (blk - 64) * 256 + threadIdx.x);
  else if (blk < 128)  pack_body(W2b, 4 * CH, CH, o2b, (blk - 96) * 256 + threadIdx.x);
  else if (blk < 136)  pack_body(wx1, CH, CH, ox1, (blk - 128) * 256 + threadIdx.x);
  else if (blk < 144)  pack_body(wx2, CH, CH, ox2, (blk - 136) * 256 + threadIdx.x);
  else if (blk < 152)  pack_body(wk1, CH, CH, ok1, (blk - 144) * 256 + threadIdx.x);
  else                 pack_body(wk2, CH, CH, ok2, (blk - 152) * 256 + threadIdx.x);
}

// ---------- fused layer-1 edge pipeline + t2 precompute ----------
// r10 structure + HALF-PHASE LDS transpose: B-fragment ks only needs the
// C-outputs of jt tiles {2ks, 2ks+1}, so each GEMM stage runs in two
// half-phases (jt 0-3 -> read ks 0,1; jt 4-7 -> read ks 2,3) over a
// half-size buffer. LDS 48 KB -> 24 KB => 6 blocks/CU (24 waves) while
// keeping full-stage live ranges (ff dead before h1f) and 3-tile weight
// amortization. Wave-private in-order DS makes the buffer reuse safe.

__global__ __launch_bounds__(256) void kbx_fused_kernel(
    const float* __restrict__ pos, const int* __restrict__ knn,
    const float* __restrict__ grid, const float* __restrict__ Bx,
    const uint4* __restrict__ w1f, const float* __restrict__ bx1,
    const uint4* __restrict__ w2f, const float* __restrict__ bx2,
    const uint4* __restrict__ wk1f, const uint4* __restrict__ wk2f,
    const float* __restrict__ x, const float* __restrict__ kR,
    uint2* __restrict__ t2g, float* __restrict__ x2out) {
  __shared__ uint4 hb[4][3][128];          // 24 KB half-tile transpose buffers
  float* x1s = (float*)hb;                 // aliased AFTER barrier (6 KB)
  int m = blockIdx.x;
  int tid = threadIdx.x, lane = tid & 63, w = tid >> 6;
  int r = lane & 15, gq = lane >> 4;

  int src = knn[m * KNN + r];
  float rx = pos[src * 3 + 0] - pos[m * 3 + 0];
  float ry = pos[src * 3 + 1] - pos[m * 3 + 1];
  float rz = pos[src * 3 + 2] - pos[m * 3 + 2];

  float4 brA0 = *(const float4*)(Bx + gq * 8);
  float4 brA1 = *(const float4*)(Bx + gq * 8 + 4);
  float4 brB0 = *(const float4*)(Bx + 32 + gq * 8);
  float4 brB1 = *(const float4*)(Bx + 32 + gq * 8 + 4);
  float4 bzA0 = *(const float4*)(Bx + 64 + gq * 8);
  float4 bzA1 = *(const float4*)(Bx + 64 + gq * 8 + 4);
  float4 bzB0 = *(const float4*)(Bx + 96 + gq * 8);
  float4 bzB1 = *(const float4*)(Bx + 96 + gq * 8 + 4);
  float brA[8] = {brA0.x, brA0.y, brA0.z, brA0.w, brA1.x, brA1.y, brA1.z, brA1.w};
  float brB[8] = {brB0.x, brB0.y, brB0.z, brB0.w, brB1.x, brB1.y, brB1.z, brB1.w};
  float bzA[8] = {bzA0.x, bzA0.y, bzA0.z, bzA0.w, bzA1.x, bzA1.y, bzA1.z, bzA1.w};
  float bzB[8] = {bzB0.x, bzB0.y, bzB0.z, bzB0.w, bzB1.x, bzB1.y, bzB1.z, bzB1.w};

  // ---- RFF features as B-fragments for all 3 tiles
  bfrag ff[3][4];
#pragma unroll
  for (int t = 0; t < 3; ++t) {
    int o = w * 3 + t;
    float gx = grid[o * 3 + 0], gy = grid[o * 3 + 1], gz = grid[o * 3 + 2];
    float z = rx * gx + ry * gy + rz * gz;
    float ux = rx - z * gx, uy = ry - z * gy, uz = rz - z * gz;
    float rxy = sqrtf(ux * ux + uy * uy + uz * uz);
    float cA[8], sA[8], cB[8], sB[8];
#pragma unroll
    for (int u = 0; u < 8; ++u) {
      float wA = __builtin_fmaf(z, bzA[u], rxy * brA[u]);
      float wB = __builtin_fmaf(z, bzB[u], rxy * brB[u]);
      cossin(wA, cA[u], sA[u]);
      cossin(wB, cB[u], sB[u]);
    }
    uint4 q;
    q.x = pkcvt(cA[0], cA[1]); q.y = pkcvt(cA[2], cA[3]);
    q.z = pkcvt(cA[4], cA[5]); q.w = pkcvt(cA[6], cA[7]);
    ff[t][0] = __builtin_bit_cast(bfrag, q);
    q.x = pkcvt(cB[0], cB[1]); q.y = pkcvt(cB[2], cB[3]);
    q.z = pkcvt(cB[4], cB[5]); q.w = pkcvt(cB[6], cB[7]);
    ff[t][1] = __builtin_bit_cast(bfrag, q);
    q.x = pkcvt(sA[0], sA[1]); q.y = pkcvt(sA[2], sA[3]);
    q.z = pkcvt(sA[4], sA[5]); q.w = pkcvt(sA[6], sA[7]);
    ff[t][2] = __builtin_bit_cast(bfrag, q);
    q.x = pkcvt(sB[0], sB[1]); q.y = pkcvt(sB[2], sB[3]);
    q.z = pkcvt(sB[4], sB[5]); q.w = pkcvt(sB[6], sB[7]);
    ff[t][3] = __builtin_bit_cast(bfrag, q);
  }

  // ---- GEMM1: h1 = gelu(f @ Wx1 + bx1), half-phase LDS transpose
  bfrag h1f[3][4];
#pragma unroll 1
  for (int h = 0; h < 2; ++h) {
#pragma unroll 2
    for (int jl = 0; jl < 4; ++jl) {
      int jt = h * 4 + jl;
      bfrag wf[4];
#pragma unroll
      for (int ks = 0; ks < 4; ++ks)
        wf[ks] = __builtin_bit_cast(bfrag, w1f[(jt * 4 + ks) * 64 + lane]);
      float4 bb = *(const float4*)(bx1 + jt * 16 + gq * 4);
      int cu = jl * 2 + (gq >> 1);           // 0..7 within half
#pragma unroll
      for (int t = 0; t < 3; ++t) {
        f32x4 acc;
        acc[0] = bb.x; acc[1] = bb.y; acc[2] = bb.z; acc[3] = bb.w;
#pragma unroll
        for (int ks = 0; ks < 4; ++ks)
          acc = __builtin_amdgcn_mfma_f32_16x16x32_bf16(wf[ks], ff[t][ks], acc, 0, 0, 0);
        unsigned p0 = pkcvt(gelu_s(acc[0]), gelu_s(acc[1]));
        unsigned p1 = pkcvt(gelu_s(acc[2]), gelu_s(acc[3]));
        ((uint2*)&hb[w][t][0])[r * 16 + ((cu ^ (r & 7)) << 1) + (gq & 1)] =
            make_uint2(p0, p1);
      }
    }
#pragma unroll
    for (int t = 0; t < 3; ++t)
#pragma unroll
      for (int ksl = 0; ksl < 2; ++ksl)
        h1f[t][h * 2 + ksl] = __builtin_bit_cast(bfrag,
            hb[w][t][r * 8 + ((ksl * 4 + gq) ^ (r & 7))]);
  }

  // ---- GEMM2: h2 = gelu(h1 @ Wx2 + bx2), half-phase LDS transpose
  bfrag h2f[3][4];
#pragma unroll 1
  for (int h = 0; h < 2; ++h) {
#pragma unroll 2
    for (int jl = 0; jl < 4; ++jl) {
      int jt = h * 4 + jl;
      bfrag wf[4];
#pragma unroll
      for (int ks = 0; ks < 4; ++ks)
        wf[ks] = __builtin_bit_cast(bfrag, w2f[(jt * 4 + ks) * 64 + lane]);
      float4 bb = *(const float4*)(bx2 + jt * 16 + gq * 4);
      int cu = jl * 2 + (gq >> 1);
#pragma unroll
      for (int t = 0; t < 3; ++t) {
        f32x4 acc;
        acc[0] = bb.x; acc[1] = bb.y; acc[2] = bb.z; acc[3] = bb.w;
#pragma unroll
        for (int ks = 0; ks < 4; ++ks)
          acc = __builtin_amdgcn_mfma_f32_16x16x32_bf16(wf[ks], h1f[t][ks], acc, 0, 0, 0);
        unsigned p0 = pkcvt(gelu_s(acc[0]), gelu_s(acc[1]));
        unsigned p1 = pkcvt(gelu_s(acc[2]), gelu_s(acc[3]));
        ((uint2*)&hb[w][t][0])[r * 16 + ((cu ^ (r & 7)) << 1) + (gq & 1)] =
            make_uint2(p0, p1);
      }
    }
#pragma unroll
    for (int t = 0; t < 3; ++t)
#pragma unroll
      for (int ksl = 0; ksl < 2; ++ksl)
        h2f[t][h * 2 + ksl] = __builtin_bit_cast(bfrag,
            hb[w][t][r * 8 + ((ksl * 4 + gq) ^ (r & 7))]);
  }

  __syncthreads();   // all transpose reads done -> x1s may alias hb

  // ---- merged GEMM3a+3b: two independent MFMA streams share h2f; the
  // scattered x-gather and the shuffle-reduce of 3a hide under 3b's MFMAs.
#pragma unroll 2
  for (int jt = 0; jt < 8; ++jt) {
    bfrag wfa[4], wfb[4];
#pragma unroll
    for (int ks = 0; ks < 4; ++ks) {
      wfa[ks] = __builtin_bit_cast(bfrag, wk1f[(jt * 4 + ks) * 64 + lane]);
      wfb[ks] = __builtin_bit_cast(bfrag, wk2f[(jt * 4 + ks) * 64 + lane]);
    }
#pragma unroll
    for (int t = 0; t < 3; ++t) {
      int o = w * 3 + t;
      int tile = m * NG + o;
      // issue gather early: independent of MFMA results
      float4 xv = *(const float4*)(x + ((size_t)src * NG + o) * CH + jt * 16 + gq * 4);
      f32x4 acc1, acc2;
      acc1[0] = 0.f; acc1[1] = 0.f; acc1[2] = 0.f; acc1[3] = 0.f;
      acc2[0] = 0.f; acc2[1] = 0.f; acc2[2] = 0.f; acc2[3] = 0.f;
#pragma unroll
      for (int ks = 0; ks < 4; ++ks) {
        acc1 = __builtin_amdgcn_mfma_f32_16x16x32_bf16(wfa[ks], h2f[t][ks], acc1, 0, 0, 0);
        acc2 = __builtin_amdgcn_mfma_f32_16x16x32_bf16(wfb[ks], h2f[t][ks], acc2, 0, 0, 0);
      }
      // t2 store first (no cross-lane dependency)
      uint2 pv;
      pv.x = pkcvt(acc2[0], acc2[1]);
      pv.y = pkcvt(acc2[2], acc2[3]);
      t2g[((size_t)tile * 8 + jt) * 64 + lane] = pv;
      // gather-mul + k-mean reduce
      acc1[0] *= xv.x; acc1[1] *= xv.y; acc1[2] *= xv.z; acc1[3] *= xv.w;
#pragma unroll
      for (int st = 1; st < 16; st <<= 1) {
        acc1[0] += __shfl_xor(acc1[0], st, 64);
        acc1[1] += __shfl_xor(acc1[1], st, 64);
        acc1[2] += __shfl_xor(acc1[2], st, 64);
        acc1[3] += __shfl_xor(acc1[3], st, 64);
      }
      if (r == 0) {
        int c0 = jt * 16 + gq * 4;
        float4 sv;
        sv.x = acc1[0] * (1.f / 16.f); sv.y = acc1[1] * (1.f / 16.f);
        sv.z = acc1[2] * (1.f / 16.f); sv.w = acc1[3] * (1.f / 16.f);
        *(float4*)&x1s[o * CH + c0] = sv;
      }
    }
  }
  __syncthreads();

  // ---- fused fiber einsum: x2[m,p,c] = (1/NG) sum_o x1s[o][c]*kR[(p*NG+o)*CH+c]
  int c = tid & 127, p0 = tid >> 7;
  float v[NG];
#pragma unroll
  for (int o = 0; o < NG; ++o) v[o] = x1s[o * CH + c];
#pragma unroll
  for (int pp = 0; pp < 6; ++pp) {
    int p = p0 * 6 + pp;
    float acc = 0.f;
#pragma unroll
    for (int o = 0; o < NG; ++o) acc += v[o] * kR[(p * NG + o) * CH + c];
    x2out[((size_t)m * NG + p) * CH + c] = acc * (1.0f / NG);
  }
}

// ---------- layer-2: stream t2, gather out, k-mean, fused einsum ----------

__global__ __launch_bounds__(256) void msg3b_kernel(
    const float* __restrict__ x, const int* __restrict__ knn,
    const uint2* __restrict__ t2g, const float* __restrict__ kR,
    float* __restrict__ x2out) {
  __shared__ float x1s[NG][CH];   // 6 KB
  int m = blockIdx.x;
  int tid = threadIdx.x, lane = tid & 63, w = tid >> 6;
  int r = lane & 15, gq = lane >> 4;
  int src = knn[m * KNN + r];

#pragma unroll 1
  for (int jt = 0; jt < 8; ++jt) {
#pragma unroll
    for (int t = 0; t < 3; ++t) {
      int o = w * 3 + t;
      int tile = m * NG + o;
      uint2 tv = t2g[((size_t)tile * 8 + jt) * 64 + lane];
      float4 xv = *(const float4*)(x + ((size_t)src * NG + o) * CH + jt * 16 + gq * 4);
      float a0 = ubf_lo(tv.x) * xv.x;
      float a1 = ubf_hi(tv.x) * xv.y;
      float a2 = ubf_lo(tv.y) * xv.z;
      float a3 = ubf_hi(tv.y) * xv.w;
#pragma unroll
      for (int st = 1; st < 16; st <<= 1) {
        a0 += __shfl_xor(a0, st, 64);
        a1 += __shfl_xor(a1, st, 64);
        a2 += __shfl_xor(a2, st, 64);
        a3 += __shfl_xor(a3, st, 64);
      }
      if (r == 0) {
        int c0 = jt * 16 + gq * 4;
        x1s[o][c0 + 0] = a0 * (1.f / 16.f);
        x1s[o][c0 + 1] = a1 * (1.f / 16.f);
        x1s[o][c0 + 2] = a2 * (1.f / 16.f);
        x1s[o][c0 + 3] = a3 * (1.f / 16.f);
      }
    }
  }
  __syncthreads();

  int c = tid & 127, p0 = tid >> 7;
  float v[NG];
#pragma unroll
  for (int o = 0; o < NG; ++o) v[o] = x1s[o][c];
#pragma unroll
  for (int pp = 0; pp < 6; ++pp) {
    int p = p0 * 6 + pp;
    float acc = 0.f;
#pragma unroll
    for (int o = 0; o < NG; ++o) acc += v[o] * kR[(p * NG + o) * CH + c];
    x2out[((size_t)m * NG + p) * CH + c] = acc * (1.0f / NG);
  }
}

// ---------- FALLBACK: round-4 fused edge pipeline (used if ws too small) ----------

__global__ __launch_bounds__(256) void msg_mfma_kernel(
    const float* __restrict__ x, const float* __restrict__ pos,
    const int* __restrict__ knn, const float* __restrict__ grid,
    const float* __restrict__ Bx,
    const uint4* __restrict__ w1f, const float* __restrict__ bx1,
    const uint4* __restrict__ w2f, const float* __restrict__ bx2,
    const uint4* __restrict__ wkf,
    float* __restrict__ x1out) {
  __shared__ uint4 hb[4][3][256];
  int m = blockIdx.x;
  int tid = threadIdx.x, lane = tid & 63, w = tid >> 6;
  int r = lane & 15, gq = lane >> 4;

  int src = knn[m * KNN + r];
  float rx = pos[src * 3 + 0] - pos[m * 3 + 0];
  float ry = pos[src * 3 + 1] - pos[m * 3 + 1];
  float rz = pos[src * 3 + 2] - pos[m * 3 + 2];

  bfrag ff[3][4];
#pragma unroll
  for (int t = 0; t < 3; ++t) {
    int o = w * 3 + t;
    float gx = grid[o * 3 + 0], gy = grid[o * 3 + 1], gz = grid[o * 3 + 2];
    float z = rx * gx + ry * gy + rz * gz;
    float ux = rx - z * gx, uy = ry - z * gy, uz = rz - z * gz;
    float rxy = sqrtf(ux * ux + uy * uy + uz * uz);
#pragma unroll
    for (int ks = 0; ks < 4; ++ks) {
      uint4 q;
      unsigned pk[4];
#pragma unroll
      for (int jh = 0; jh < 4; ++jh) {
        float v[2];
#pragma unroll
        for (int u = 0; u < 2; ++u) {
          int i = ks * 32 + gq * 8 + jh * 2 + u;
          int j = i & 63;
          float pv = TWO_PI_F * (rxy * Bx[j] + z * Bx[64 + j]);
          v[u] = (i < 64) ? __cosf(pv) : __sinf(pv);
        }
        pk[jh] = packbf2(v[0], v[1]);
      }
      q.x = pk[0]; q.y = pk[1]; q.z = pk[2]; q.w = pk[3];
      ff[t][ks] = __builtin_bit_cast(bfrag, q);
    }
  }

#pragma unroll 1
  for (int jt = 0; jt < 8; ++jt) {
    bfrag wf[4];
#pragma unroll
    for (int ks = 0; ks < 4; ++ks)
      wf[ks] = __builtin_bit_cast(bfrag, w1f[(jt * 4 + ks) * 64 + lane]);
    float4 bb = *(const float4*)(bx1 + jt * 16 + gq * 4);
    int cu = jt * 2 + (gq >> 1);
#pragma unroll
    for (int t = 0; t < 3; ++t) {
      f32x4 acc;
      acc[0] = bb.x; acc[1] = bb.y; acc[2] = bb.z; acc[3] = bb.w;
#pragma unroll
      for (int ks = 0; ks < 4; ++ks)
        acc = __builtin_amdgcn_mfma_f32_16x16x32_bf16(wf[ks], ff[t][ks], acc, 0, 0, 0);
      unsigned p0 = packbf2(gelu_t(acc[0]), gelu_t(acc[1]));
      unsigned p1 = packbf2(gelu_t(acc[2]), gelu_t(acc[3]));
      ((uint2*)&hb[w][t][0])[r * 32 + ((cu ^ r) << 1) + (gq & 1)] = make_uint2(p0, p1);
    }
  }
  bfrag h1f[3][4];
#pragma unroll
  for (int t = 0; t < 3; ++t)
#pragma unroll
    for (int ks = 0; ks < 4; ++ks)
      h1f[t][ks] = __builtin_bit_cast(bfrag, hb[w][t][r * 16 + ((ks * 4 + gq) ^ r)]);

#pragma unroll 1
  for (int jt = 0; jt < 8; ++jt) {
    bfrag wf[4];
#pragma unroll
    for (int ks = 0; ks < 4; ++ks)
      wf[ks] = __builtin_bit_cast(bfrag, w2f[(jt * 4 + ks) * 64 + lane]);
    float4 bb = *(const float4*)(bx2 + jt * 16 + gq * 4);
    int cu = jt * 2 + (gq >> 1);
#pragma unroll
    for (int t = 0; t < 3; ++t) {
      f32x4 acc;
      acc[0] = bb.x; acc[1] = bb.y; acc[2] = bb.z; acc[3] = bb.w;
#pragma unroll
      for (int ks = 0; ks < 4; ++ks)
        acc = __builtin_amdgcn_mfma_f32_16x16x32_bf16(wf[ks], h1f[t][ks], acc, 0, 0, 0);
      unsigned p0 = packbf2(gelu_t(acc[0]), gelu_t(acc[1]));
      unsigned p1 = packbf2(gelu_t(acc[2]), gelu_t(acc[3]));
      ((uint2*)&hb[w][t][0])[r * 32 + ((cu ^ r) << 1) + (gq & 1)] = make_uint2(p0, p1);
    }
  }
  bfrag h2f[3][4];
#pragma unroll
  for (int t = 0; t < 3; ++t)
#pragma unroll
    for (int ks = 0; ks < 4; ++ks)
      h2f[t][ks] = __builtin_bit_cast(bfrag, hb[w][t][r * 16 + ((ks * 4 + gq) ^ r)]);

#pragma unroll 1
  for (int jt = 0; jt < 8; ++jt) {
    bfrag wf[4];
#pragma unroll
    for (int ks = 0; ks < 4; ++ks)
      wf[ks] = __builtin_bit_cast(bfrag, wkf[(jt * 4 + ks) * 64 + lane]);
#pragma unroll
    for (int t = 0; t < 3; ++t) {
      int o = w * 3 + t;
      f32x4 acc;
      acc[0] = 0.f; acc[1] = 0.f; acc[2] = 0.f; acc[3] = 0.f;
#pragma unroll
      for (int ks = 0; ks < 4; ++ks)
        acc = __builtin_amdgcn_mfma_f32_16x16x32_bf16(wf[ks], h2f[t][ks], acc, 0, 0, 0);
      float4 xv = *(const float4*)(x + ((size_t)src * NG + o) * CH + jt * 16 + gq * 4);
      acc[0] *= xv.x; acc[1] *= xv.y; acc[2] *= xv.z; acc[3] *= xv.w;
#pragma unroll
      for (int st = 1; st < 16; st <<= 1) {
        acc[0] += __shfl_xor(acc[0], st, 64);
        acc[1] += __shfl_xor(acc[1], st, 64);
        acc[2] += __shfl_xor(acc[2], st, 64);
        acc[3] += __shfl_xor(acc[3], st, 64);
      }
      if (r == 0) {
        float4 sv;
        sv.x = acc[0] * (1.f / 16.f); sv.y = acc[1] * (1.f / 16.f);
        sv.z = acc[2] * (1.f / 16.f); sv.w = acc[3] * (1.f / 16.f);
        *(float4*)(x1out + ((size_t)m * NG + o) * CH + jt * 16 + gq * 4) = sv;
      }
    }
  }
}

// ---------- LN + ConvNeXt MLP via MFMA ----------

__global__ __launch_bounds__(256) void mlp_mfma_kernel(
    const float* __restrict__ xin, const float* __restrict__ x2,
    const float* __restrict__ g, const float* __restrict__ b,
    const uint4* __restrict__ w1t, const float* __restrict__ b1,
    const uint4* __restrict__ w2t, const float* __restrict__ b2,
    const float* __restrict__ s, float* __restrict__ xout) {
  __shared__ uint4 smem[1280];
  int tid = threadIdx.x;
  int rowbase = blockIdx.x * 16;

  {
    int row = tid >> 4, p = tid & 15;
    const float4* xr = (const float4*)(x2 + (size_t)(rowbase + row) * CH + p * 8);
    float4 v0 = xr[0], v1 = xr[1];
    float sum = v0.x + v0.y + v0.z + v0.w + v1.x + v1.y + v1.z + v1.w;
    sum += __shfl_xor(sum, 1, 64); sum += __shfl_xor(sum, 2, 64);
    sum += __shfl_xor(sum, 4, 64); sum += __shfl_xor(sum, 8, 64);
    float mu = sum * (1.0f / CH);
    float sq = 0.f;
    {
      float d;
      d = v0.x - mu; sq += d * d; d = v0.y - mu; sq += d * d;
      d = v0.z - mu; sq += d * d; d = v0.w - mu; sq += d * d;
      d = v1.x - mu; sq += d * d; d = v1.y - mu; sq += d * d;
      d = v1.z - mu; sq += d * d; d = v1.w - mu; sq += d * d;
    }
    sq += __shfl_xor(sq, 1, 64); sq += __shfl_xor(sq, 2, 64);
    sq += __shfl_xor(sq, 4, 64); sq += __shfl_xor(sq, 8, 64);
    float rstd = rsqrtf(sq * (1.0f / CH) + 1e-5f);
    const float4* gv = (const float4*)(g + p * 8);
    const float4* bv = (const float4*)(b + p * 8);
    float4 g0 = gv[0], g1 = gv[1], b0 = bv[0], b1v = bv[1];
    float n0 = (v0.x - mu) * rstd * g0.x + b0.x;
    float n1 = (v0.y - mu) * rstd * g0.y + b0.y;
    float n2 = (v0.z - mu) * rstd * g0.z + b0.z;
    float n3 = (v0.w - mu) * rstd * g0.w + b0.w;
    float n4 = (v1.x - mu) * rstd * g1.x + b1v.x;
    float n5 = (v1.y - mu) * rstd * g1.y + b1v.y;
    float n6 = (v1.z - mu) * rstd * g1.z + b1v.z;
    float n7 = (v1.w - mu) * rstd * g1.w + b1v.w;
    uint4 pk;
    pk.x = packbf2(n0, n1); pk.y = packbf2(n2, n3);
    pk.z = packbf2(n4, n5); pk.w = packbf2(n6, n7);
    smem[row * 16 + (p ^ row)] = pk;
  }
  __syncthreads();

  int lane = tid & 63, w = tid >> 6;
  int r = lane & 15, gq = lane >> 4;

  bfrag xf[4];
#pragma unroll
  for (int ks = 0; ks < 4; ++ks) {
    uint4 raw = smem[r * 16 + ((ks * 4 + gq) ^ r)];
    xf[ks] = __builtin_bit_cast(bfrag, raw);
  }

  uint2* hb2 = (uint2*)smem;
#pragma unroll 2
  for (int jj = 0; jj < 8; ++jj) {
    int jt = w * 8 + jj;
    f32x4 acc;
    {
      float4 bb = *(const float4*)(b1 + jt * 16 + gq * 4);
      acc[0] = bb.x; acc[1] = bb.y; acc[2] = bb.z; acc[3] = bb.w;
    }
#pragma unroll
    for (int ks = 0; ks < 4; ++ks) {
      uint4 raw = w1t[(jt * 4 + ks) * 64 + lane];
      bfrag a = __builtin_bit_cast(bfrag, raw);
      acc = __builtin_amdgcn_mfma_f32_16x16x32_bf16(a, xf[ks], acc, 0, 0, 0);
    }
    unsigned p0 = packbf2(gelu_t(acc[0]), gelu_t(acc[1]));
    unsigned p1 = packbf2(gelu_t(acc[2]), gelu_t(acc[3]));
    int sl = (jt * 2 + (gq >> 1)) ^ r;
    hb2[512 + r * 128 + sl * 2 + (gq & 1)] = make_uint2(p0, p1);
  }
  __syncthreads();

#pragma unroll 2
  for (int cc = 0; cc < 2; ++cc) {
    int ct = w * 2 + cc;
    f32x4 acc;
    {
      float4 bb = *(const float4*)(b2 + ct * 16 + gq * 4);
      acc[0] = bb.x; acc[1] = bb.y; acc[2] = bb.z; acc[3] = bb.w;
    }
#pragma unroll
    for (int ks = 0; ks < 16; ++ks) {
      uint4 hraw = smem[256 + r * 64 + ((ks * 4 + gq) ^ r)];
      bfrag hf = __builtin_bit_cast(bfrag, hraw);
      uint4 wraw = w2t[(ct * 16 + ks) * 64 + lane];
      bfrag wf = __builtin_bit_cast(bfrag, wraw);
      acc = __builtin_amdgcn_mfma_f32_16x16x32_bf16(wf, hf, acc, 0, 0, 0);
    }
    int c0 = ct * 16 + gq * 4;
    size_t ro = (size_t)(rowbase + r) * CH + c0;
    float4 xi = *(const float4*)(xin + ro);
    float4 sv = *(const float4*)(s + c0);
    float4 ov;
    ov.x = xi.x + sv.x * acc[0];
    ov.y = xi.y + sv.y * acc[1];
    ov.z = xi.z + sv.z * acc[2];
    ov.w = xi.w + sv.w * acc[3];
    *(float4*)(xout + ro) = ov;
  }
}

// ---------- launch ----------

extern "C" void kernel_launch(void* const* d_in, const int* in_sizes, int n_in,
                              void* d_out, int out_size, void* d_ws, size_t ws_size,
                              hipStream_t stream) {
  (void)in_sizes; (void)n_in; (void)out_size;
  const float* x    = (const float*)d_in[0];
  const float* pos  = (const float*)d_in[1];
  const float* grid = (const float*)d_in[2];
  const float* Bx   = (const float*)d_in[3];
  float* out = (float*)d_out;

  char* wsb = (char*)d_ws;
  int* knn   = (int*)wsb;                                   // 131072 B
  float* kR1 = (float*)(wsb + 131072);
  float* kR2 = kR1 + NG * NG * CH;
  float* x1  = kR2 + NG * NG * CH;
  float* x2  = x1 + (size_t)MTOT * NG * CH;
  unsigned short* w1ta = (unsigned short*)(x2 + (size_t)MTOT * NG * CH);
  unsigned short* w2ta = w1ta + 65536;
  unsigned short* w1tb = w2ta + 65536;
  unsigned short* w2tb = w1tb + 65536;
  unsigned short* wx1f = w2tb + 65536;     // 16384 each
  unsigned short* wx2f = wx1f + 16384;
  unsigned short* wk1f = wx2f + 16384;
  unsigned short* wk2f = wk1f + 16384;
  uint2* t2g = (uint2*)(wk2f + 16384);     // 100,663,296 B
  size_t need = (size_t)26099712 + (size_t)MTOT * NG * 4 * 64 * 16;
  bool big_ws = ws_size >= need;

  knn_kernel<<<MTOT / 4, 256, 0, stream>>>(pos, knn);
  kbr_kernel<<<NG * NG, CH, 0, stream>>>(grid, (const float*)d_in[4],
                                         (const float*)d_in[9], (const float*)d_in[10],
                                         (const float*)d_in[11], (const float*)d_in[12],
                                         (const float*)d_in[14], (const float*)d_in[23],
                                         kR1, kR2);
  pack_all_kernel<<<160, 256, 0, stream>>>(
      (const float*)d_in[17], (const float*)d_in[19],
      (const float*)d_in[26], (const float*)d_in[28],
      (const float*)d_in[5], (const float*)d_in[7],
      (const float*)d_in[13], (const float*)d_in[22],
      w1ta, w2ta, w1tb, w2tb, wx1f, wx2f, wk1f, wk2f);

  if (big_ws) {
    // layer 1 (fused edge pipeline + t2 precompute + einsum)
    kbx_fused_kernel<<<MTOT, 256, 0, stream>>>(pos, knn, grid, Bx,
        (const uint4*)wx1f, (const float*)d_in[6],
        (const uint4*)wx2f, (const float*)d_in[8],
        (const uint4*)wk1f, (const uint4*)wk2f,
        x, kR1, t2g, x2);
    mlp_mfma_kernel<<<(MTOT * NG) / 16, 256, 0, stream>>>(x, x2,
        (const float*)d_in[15], (const float*)d_in[16],
        (const uint4*)w1ta, (const float*)d_in[18],
        (const uint4*)w2ta, (const float*)d_in[20],
        (const float*)d_in[21], out);
    // layer 2 (stream t2 + gather out + einsum)
    msg3b_kernel<<<MTOT, 256, 0, stream>>>(out, knn, (const uint2*)t2g, kR2, x2);
    mlp_mfma_kernel<<<(MTOT * NG) / 16, 256, 0, stream>>>(out, x2,
        (const float*)d_in[24], (const float*)d_in[25],
        (const uint4*)w1tb, (const float*)d_in[27],
        (const uint4*)w2tb, (const float*)d_in[29],
        (const float*)d_in[30], out);
  } else {
    msg_mfma_kernel<<<MTOT, 256, 0, stream>>>(x, pos, knn, grid, Bx,
        (const uint4*)wx1f, (const float*)d_in[6],
        (const uint4*)wx2f, (const float*)d_in[8],
        (const uint4*)wk1f, x1);
    einsum_kernel<<<MTOT, CH, 0, stream>>>(x1, kR1, x2);
    mlp_mfma_kernel<<<(MTOT * NG) / 16, 256, 0, stream>>>(x, x2,
        (const float*)d_in[15], (const float*)d_in[16],
        (const uint4*)w1ta, (const float*)d_in[18],
        (const uint4*)w2ta, (const float*)d_in[20],
        (const float*)d_in[21], out);
    msg_mfma_kernel<<<MTOT, 256, 0, stream>>>(out, pos, knn, grid, Bx,
        (const uint4*)wx1f, (const float*)d_in[6],
        (const uint4*)wx2f, (const float*)d_in[8],
        (const uint4*)wk2f, x1);
    einsum_kernel<<<MTOT, CH, 0, stream>>>(x1, kR2, x2);
    mlp_mfma_kernel<<<(MTOT * NG) / 16, 256, 0, stream>>>(out, x2,
        (const float*)d_in[24], (const float*)d_in[25],
        (const uint4*)w1tb, (const float*)d_in[27],
        (const uint4*)w2tb, (const float*)d_in[29],
        (const float*)d_in[30], out);
  }
}

// Round 12
// 222.272 us; speedup vs baseline: 1.1670x; 1.1670x over previous
//
#include <hip/hip_runtime.h>
#include <hip/hip_bf16.h>
#include <math.h>

#define BG 8
#define NNODES 256
#define KNN 16
#define NG 12
#define CH 128
#define MTOT 2048
#define TWO_PI_F 6.283185307179586f

typedef __attribute__((ext_vector_type(8))) short bfrag;
typedef __attribute__((ext_vector_type(4))) float f32x4;

// ---------- helpers ----------

__device__ __forceinline__ float gelu_t(float x) {
  float x3 = x * x * x;
  float y = 0.7978845608028654f * (x + 0.044715f * x3);
  float e = __expf(2.0f * y);
  float th = 1.0f - 2.0f / (e + 1.0f);
  return 0.5f * x * (1.0f + th);
}

__device__ __forceinline__ unsigned packbf2(float a, float b) {
  unsigned ua = __float_as_uint(a), ub = __float_as_uint(b);
  ua = (ua + 0x7fffu + ((ua >> 16) & 1u)) >> 16;    // RNE to bf16
  ub = (ub + 0x7fffu + ((ub >> 16) & 1u)) >> 16;
  return ua | (ub << 16);
}
__device__ __forceinline__ unsigned short f2bf(float f) {
  unsigned u = __float_as_uint(f);
  u = (u + 0x7fffu + ((u >> 16) & 1u)) >> 16;
  return (unsigned short)u;
}
__device__ __forceinline__ float ubf_lo(unsigned p) { return __uint_as_float(p << 16); }
__device__ __forceinline__ float ubf_hi(unsigned p) { return __uint_as_float(p & 0xffff0000u); }

// gelu via sigmoid form; exp2-domain, ~7 insts
__device__ __forceinline__ float gelu_s(float x) {
  const float A  = -2.0f * 0.7978845608028654f * 1.4426950408889634f;
  const float CA = A * 0.044715f;
  float x2 = x * x;
  float q  = __builtin_fmaf(CA, x2, A);
  float t  = x * q;
  float e; asm("v_exp_f32 %0, %1" : "=v"(e) : "v"(t));     // 2^t
  float d = 1.0f + e;
  float r; asm("v_rcp_f32 %0, %1" : "=v"(r) : "v"(d));
  return x * r;
}

__device__ __forceinline__ unsigned pkcvt(float a, float b) {
  unsigned r;
  asm("v_cvt_pk_bf16_f32 %0, %1, %2" : "=v"(r) : "v"(a), "v"(b));
  return r;
}

__device__ __forceinline__ void cossin(float w, float& c, float& s) {
  float f; asm("v_fract_f32 %0, %1" : "=v"(f) : "v"(w));
  asm("v_cos_f32 %0, %1" : "=v"(c) : "v"(f));
  asm("v_sin_f32 %0, %1" : "=v"(s) : "v"(f));
}

__device__ __forceinline__ unsigned long long shfl_xor64(unsigned long long v, int st) {
  unsigned lo = (unsigned)v, hi = (unsigned)(v >> 32);
  lo = __shfl_xor(lo, st, 64);
  hi = __shfl_xor(hi, st, 64);
  return ((unsigned long long)hi << 32) | lo;
}

// ---------- kNN: one wave per node ----------

__global__ __launch_bounds__(256) void knn_kernel(const float* __restrict__ pos,
                                                  int* __restrict__ knn) {
  __shared__ float sx[NNODES], sy[NNODES], sz[NNODES];
  int w = threadIdx.x >> 6, lane = threadIdx.x & 63;
  int node = blockIdx.x * 4 + w;
  int b = node >> 8;
  int gbase = b * NNODES;
  int t = threadIdx.x;
  sx[t] = pos[(gbase + t) * 3 + 0];
  sy[t] = pos[(gbase + t) * 3 + 1];
  sz[t] = pos[(gbase + t) * 3 + 2];
  __syncthreads();
  int i = node & 255;
  float xi = sx[i], yi = sy[i], zi = sz[i];
  unsigned long long key[4];
#pragma unroll
  for (int u = 0; u < 4; ++u) {
    int j = lane * 4 + u;
    float dx = xi - sx[j], dy = yi - sy[j], dz = zi - sz[j];
    float d = dx * dx + dy * dy + dz * dz;
    key[u] = ((unsigned long long)__float_as_uint(d) << 32) | (unsigned)j;
  }
  {
    unsigned long long tmp;
#define CSWAP(a, bq) if (key[bq] < key[a]) { tmp = key[a]; key[a] = key[bq]; key[bq] = tmp; }
    CSWAP(0, 1) CSWAP(2, 3) CSWAP(0, 2) CSWAP(1, 3) CSWAP(1, 2)
#undef CSWAP
  }
  int ptr = 0;
#pragma unroll 1
  for (int r = 0; r < KNN; ++r) {
    unsigned long long cand = (ptr < 4) ? key[ptr] : ~0ULL;
    unsigned long long mn = cand;
#pragma unroll
    for (int st = 1; st < 64; st <<= 1) {
      unsigned long long o = shfl_xor64(mn, st);
      if (o < mn) mn = o;
    }
    if (cand == mn) ptr++;
    if (lane == 0) knn[node * KNN + r] = gbase + (int)(mn & 0xffffffffu);
  }
}

// ---------- kb_R -> kR ----------

__global__ void kbr_kernel(const float* __restrict__ grid, const float* __restrict__ BR,
                           const float* __restrict__ WR1, const float* __restrict__ bR1,
                           const float* __restrict__ WR2, const float* __restrict__ bR2,
                           const float* __restrict__ WkR1, const float* __restrict__ WkR2,
                           float* __restrict__ kR1, float* __restrict__ kR2) {
  int r = blockIdx.x;
  int p = r / NG, o = r % NG;
  int c = threadIdx.x;
  float a = grid[p * 3 + 0] * grid[o * 3 + 0] + grid[p * 3 + 1] * grid[o * 3 + 1] +
            grid[p * 3 + 2] * grid[o * 3 + 2];
  __shared__ float fb[CH], hh[CH];
  {
    int j = c & 63;
    float pv = TWO_PI_F * (a * BR[j]);
    fb[c] = (c < 64) ? cosf(pv) : sinf(pv);
  }
  __syncthreads();
  float acc = bR1[c];
  for (int i = 0; i < CH; ++i) acc += fb[i] * WR1[i * CH + c];
  float h1 = gelu_t(acc);
  __syncthreads();
  hh[c] = h1;
  __syncthreads();
  acc = bR2[c];
  for (int i = 0; i < CH; ++i) acc += hh[i] * WR2[i * CH + c];
  float h2 = gelu_t(acc);
  __syncthreads();
  fb[c] = h2;
  __syncthreads();
  float t1 = 0.f, t2 = 0.f;
  for (int i = 0; i < CH; ++i) {
    float v = fb[i];
    t1 += v * WkR1[i * CH + c];
    t2 += v * WkR2[i * CH + c];
  }
  kR1[r * CH + c] = t1;
  kR2[r * CH + c] = t2;
}

// ---------- fiber einsum (fallback path only) ----------

__global__ void einsum_kernel(const float* __restrict__ x1, const float* __restrict__ kR,
                              float* __restrict__ x2) {
  int m = blockIdx.x, c = threadIdx.x;
  float v[NG];
#pragma unroll
  for (int o = 0; o < NG; ++o) v[o] = x1[((size_t)m * NG + o) * CH + c];
#pragma unroll
  for (int p = 0; p < NG; ++p) {
    float acc = 0.f;
#pragma unroll
    for (int o = 0; o < NG; ++o) acc += v[o] * kR[(p * NG + o) * CH + c];
    x2[((size_t)m * NG + p) * CH + c] = acc * (1.0f / NG);
  }
}

// ---------- weight fragment packing (all 8 matrices, one launch) ----------
// fragment element (tile,ks,lane,j) = W[ks*32 + (lane>>4)*8 + j][tile*16 + (lane&15)]

__device__ __forceinline__ void pack_body(const float* __restrict__ W, int K, int N,
                                          unsigned short* __restrict__ out, int tid) {
  int lane = tid & 63;
  int t = tid >> 6;
  int ksteps = K / 32;
  int ks = t % ksteps, tile = t / ksteps;
  int col = tile * 16 + (lane & 15);
  int k0 = ks * 32 + (lane >> 4) * 8;
#pragma unroll
  for (int j = 0; j < 8; ++j)
    out[(size_t)tid * 8 + j] = f2bf(W[(size_t)(k0 + j) * N + col]);
}

__global__ __launch_bounds__(256) void pack_all_kernel(
    const float* __restrict__ W1a, const float* __restrict__ W2a,
    const float* __restrict__ W1b, const float* __restrict__ W2b,
    const float* __restrict__ wx1, const float* __restrict__ wx2,
    const float* __restrict__ wk1, const float* __restrict__ wk2,
    unsigned short* __restrict__ o1a, unsigned short* __restrict__ o2a,
    unsigned short* __restrict__ o1b, unsigned short* __restrict__ o2b,
    unsigned short* __restrict__ ox1, unsigned short* __restrict__ ox2,
    unsigned short* __restrict__ ok1, unsigned short* __restrict__ ok2) {
  int blk = blockIdx.x;
  if (blk < 32)        pack_body(W1a, CH, 4 * CH, o1a, blk * 256 + threadIdx.x);
  else if (blk < 64)   pack_body(W2a, 4 * CH, CH, o2a, (blk - 32) * 256 + threadIdx.x);
  else if (blk < 96)   pack_body(W1b, CH, 4 * CH, o1b, (blk - 64) * 256 + threadIdx.x);
  else if (blk < 128)  pack_body(W2b, 4 * CH, CH, o2b, (blk - 96) * 256 + threadIdx.x);
  else if (blk < 136)  pack_body(wx1, CH, CH, ox1, (blk - 128) * 256 + threadIdx.x);
  else if (blk < 144)  pack_body(wx2, CH, CH, ox2, (blk - 136) * 256 + threadIdx.x);
  else if (blk < 152)  pack_body(wk1, CH, CH, ok1, (blk - 144) * 256 + threadIdx.x);
  else                 pack_body(wk2, CH, CH, ok2, (blk - 152) * 256 + threadIdx.x);
}

// ---------- fused layer-1 edge pipeline + t2 precompute ----------
// Half-phase LDS transpose with FULLY UNROLLED phase loop (r11 bug: runtime
// phase index forced h1f/h2f into scratch -> 307 MB spill traffic; rule #20).
// LDS 24 KB => 6 blocks/CU while keeping full-stage live ranges and 3-tile
// weight amortization. Wave-private in-order DS makes buffer reuse safe.

__global__ __launch_bounds__(256) void kbx_fused_kernel(
    const float* __restrict__ pos, const int* __restrict__ knn,
    const float* __restrict__ grid, const float* __restrict__ Bx,
    const uint4* __restrict__ w1f, const float* __restrict__ bx1,
    const uint4* __restrict__ w2f, const float* __restrict__ bx2,
    const uint4* __restrict__ wk1f, const uint4* __restrict__ wk2f,
    const float* __restrict__ x, const float* __restrict__ kR,
    uint2* __restrict__ t2g, float* __restrict__ x2out) {
  __shared__ uint4 hb[4][3][128];          // 24 KB half-tile transpose buffers
  float* x1s = (float*)hb;                 // aliased AFTER barrier (6 KB)
  int m = blockIdx.x;
  int tid = threadIdx.x, lane = tid & 63, w = tid >> 6;
  int r = lane & 15, gq = lane >> 4;

  int src = knn[m * KNN + r];
  float rx = pos[src * 3 + 0] - pos[m * 3 + 0];
  float ry = pos[src * 3 + 1] - pos[m * 3 + 1];
  float rz = pos[src * 3 + 2] - pos[m * 3 + 2];

  float4 brA0 = *(const float4*)(Bx + gq * 8);
  float4 brA1 = *(const float4*)(Bx + gq * 8 + 4);
  float4 brB0 = *(const float4*)(Bx + 32 + gq * 8);
  float4 brB1 = *(const float4*)(Bx + 32 + gq * 8 + 4);
  float4 bzA0 = *(const float4*)(Bx + 64 + gq * 8);
  float4 bzA1 = *(const float4*)(Bx + 64 + gq * 8 + 4);
  float4 bzB0 = *(const float4*)(Bx + 96 + gq * 8);
  float4 bzB1 = *(const float4*)(Bx + 96 + gq * 8 + 4);
  float brA[8] = {brA0.x, brA0.y, brA0.z, brA0.w, brA1.x, brA1.y, brA1.z, brA1.w};
  float brB[8] = {brB0.x, brB0.y, brB0.z, brB0.w, brB1.x, brB1.y, brB1.z, brB1.w};
  float bzA[8] = {bzA0.x, bzA0.y, bzA0.z, bzA0.w, bzA1.x, bzA1.y, bzA1.z, bzA1.w};
  float bzB[8] = {bzB0.x, bzB0.y, bzB0.z, bzB0.w, bzB1.x, bzB1.y, bzB1.z, bzB1.w};

  // ---- RFF features as B-fragments for all 3 tiles
  bfrag ff[3][4];
#pragma unroll
  for (int t = 0; t < 3; ++t) {
    int o = w * 3 + t;
    float gx = grid[o * 3 + 0], gy = grid[o * 3 + 1], gz = grid[o * 3 + 2];
    float z = rx * gx + ry * gy + rz * gz;
    float ux = rx - z * gx, uy = ry - z * gy, uz = rz - z * gz;
    float rxy = sqrtf(ux * ux + uy * uy + uz * uz);
    float cA[8], sA[8], cB[8], sB[8];
#pragma unroll
    for (int u = 0; u < 8; ++u) {
      float wA = __builtin_fmaf(z, bzA[u], rxy * brA[u]);
      float wB = __builtin_fmaf(z, bzB[u], rxy * brB[u]);
      cossin(wA, cA[u], sA[u]);
      cossin(wB, cB[u], sB[u]);
    }
    uint4 q;
    q.x = pkcvt(cA[0], cA[1]); q.y = pkcvt(cA[2], cA[3]);
    q.z = pkcvt(cA[4], cA[5]); q.w = pkcvt(cA[6], cA[7]);
    ff[t][0] = __builtin_bit_cast(bfrag, q);
    q.x = pkcvt(cB[0], cB[1]); q.y = pkcvt(cB[2], cB[3]);
    q.z = pkcvt(cB[4], cB[5]); q.w = pkcvt(cB[6], cB[7]);
    ff[t][1] = __builtin_bit_cast(bfrag, q);
    q.x = pkcvt(sA[0], sA[1]); q.y = pkcvt(sA[2], sA[3]);
    q.z = pkcvt(sA[4], sA[5]); q.w = pkcvt(sA[6], sA[7]);
    ff[t][2] = __builtin_bit_cast(bfrag, q);
    q.x = pkcvt(sB[0], sB[1]); q.y = pkcvt(sB[2], sB[3]);
    q.z = pkcvt(sB[4], sB[5]); q.w = pkcvt(sB[6], sB[7]);
    ff[t][3] = __builtin_bit_cast(bfrag, q);
  }

  // ---- GEMM1: h1 = gelu(f @ Wx1 + bx1), half-phase LDS transpose
  bfrag h1f[3][4];
#pragma unroll
  for (int h = 0; h < 2; ++h) {           // FULLY unrolled: indices compile-time
#pragma unroll 2
    for (int jl = 0; jl < 4; ++jl) {
      int jt = h * 4 + jl;
      bfrag wf[4];
#pragma unroll
      for (int ks = 0; ks < 4; ++ks)
        wf[ks] = __builtin_bit_cast(bfrag, w1f[(jt * 4 + ks) * 64 + lane]);
      float4 bb = *(const float4*)(bx1 + jt * 16 + gq * 4);
      int cu = jl * 2 + (gq >> 1);         // 0..7 within half
#pragma unroll
      for (int t = 0; t < 3; ++t) {
        f32x4 acc;
        acc[0] = bb.x; acc[1] = bb.y; acc[2] = bb.z; acc[3] = bb.w;
#pragma unroll
        for (int ks = 0; ks < 4; ++ks)
          acc = __builtin_amdgcn_mfma_f32_16x16x32_bf16(wf[ks], ff[t][ks], acc, 0, 0, 0);
        unsigned p0 = pkcvt(gelu_s(acc[0]), gelu_s(acc[1]));
        unsigned p1 = pkcvt(gelu_s(acc[2]), gelu_s(acc[3]));
        ((uint2*)&hb[w][t][0])[r * 16 + ((cu ^ (r & 7)) << 1) + (gq & 1)] =
            make_uint2(p0, p1);
      }
    }
#pragma unroll
    for (int t = 0; t < 3; ++t)
#pragma unroll
      for (int ksl = 0; ksl < 2; ++ksl)
        h1f[t][h * 2 + ksl] = __builtin_bit_cast(bfrag,
            hb[w][t][r * 8 + ((ksl * 4 + gq) ^ (r & 7))]);
  }

  // ---- GEMM2: h2 = gelu(h1 @ Wx2 + bx2), half-phase LDS transpose
  bfrag h2f[3][4];
#pragma unroll
  for (int h = 0; h < 2; ++h) {           // FULLY unrolled
#pragma unroll 2
    for (int jl = 0; jl < 4; ++jl) {
      int jt = h * 4 + jl;
      bfrag wf[4];
#pragma unroll
      for (int ks = 0; ks < 4; ++ks)
        wf[ks] = __builtin_bit_cast(bfrag, w2f[(jt * 4 + ks) * 64 + lane]);
      float4 bb = *(const float4*)(bx2 + jt * 16 + gq * 4);
      int cu = jl * 2 + (gq >> 1);
#pragma unroll
      for (int t = 0; t < 3; ++t) {
        f32x4 acc;
        acc[0] = bb.x; acc[1] = bb.y; acc[2] = bb.z; acc[3] = bb.w;
#pragma unroll
        for (int ks = 0; ks < 4; ++ks)
          acc = __builtin_amdgcn_mfma_f32_16x16x32_bf16(wf[ks], h1f[t][ks], acc, 0, 0, 0);
        unsigned p0 = pkcvt(gelu_s(acc[0]), gelu_s(acc[1]));
        unsigned p1 = pkcvt(gelu_s(acc[2]), gelu_s(acc[3]));
        ((uint2*)&hb[w][t][0])[r * 16 + ((cu ^ (r & 7)) << 1) + (gq & 1)] =
            make_uint2(p0, p1);
      }
    }
#pragma unroll
    for (int t = 0; t < 3; ++t)
#pragma unroll
      for (int ksl = 0; ksl < 2; ++ksl)
        h2f[t][h * 2 + ksl] = __builtin_bit_cast(bfrag,
            hb[w][t][r * 8 + ((ksl * 4 + gq) ^ (r & 7))]);
  }

  __syncthreads();   // all transpose reads done -> x1s may alias hb

  // ---- merged GEMM3a+3b: two independent MFMA streams share h2f; the
  // scattered x-gather and the shuffle-reduce of 3a hide under 3b's MFMAs.
#pragma unroll 2
  for (int jt = 0; jt < 8; ++jt) {
    bfrag wfa[4], wfb[4];
#pragma unroll
    for (int ks = 0; ks < 4; ++ks) {
      wfa[ks] = __builtin_bit_cast(bfrag, wk1f[(jt * 4 + ks) * 64 + lane]);
      wfb[ks] = __builtin_bit_cast(bfrag, wk2f[(jt * 4 + ks) * 64 + lane]);
    }
#pragma unroll
    for (int t = 0; t < 3; ++t) {
      int o = w * 3 + t;
      int tile = m * NG + o;
      // issue gather early: independent of MFMA results
      float4 xv = *(const float4*)(x + ((size_t)src * NG + o) * CH + jt * 16 + gq * 4);
      f32x4 acc1, acc2;
      acc1[0] = 0.f; acc1[1] = 0.f; acc1[2] = 0.f; acc1[3] = 0.f;
      acc2[0] = 0.f; acc2[1] = 0.f; acc2[2] = 0.f; acc2[3] = 0.f;
#pragma unroll
      for (int ks = 0; ks < 4; ++ks) {
        acc1 = __builtin_amdgcn_mfma_f32_16x16x32_bf16(wfa[ks], h2f[t][ks], acc1, 0, 0, 0);
        acc2 = __builtin_amdgcn_mfma_f32_16x16x32_bf16(wfb[ks], h2f[t][ks], acc2, 0, 0, 0);
      }
      // t2 store first (no cross-lane dependency)
      uint2 pv;
      pv.x = pkcvt(acc2[0], acc2[1]);
      pv.y = pkcvt(acc2[2], acc2[3]);
      t2g[((size_t)tile * 8 + jt) * 64 + lane] = pv;
      // gather-mul + k-mean reduce
      acc1[0] *= xv.x; acc1[1] *= xv.y; acc1[2] *= xv.z; acc1[3] *= xv.w;
#pragma unroll
      for (int st = 1; st < 16; st <<= 1) {
        acc1[0] += __shfl_xor(acc1[0], st, 64);
        acc1[1] += __shfl_xor(acc1[1], st, 64);
        acc1[2] += __shfl_xor(acc1[2], st, 64);
        acc1[3] += __shfl_xor(acc1[3], st, 64);
      }
      if (r == 0) {
        int c0 = jt * 16 + gq * 4;
        float4 sv;
        sv.x = acc1[0] * (1.f / 16.f); sv.y = acc1[1] * (1.f / 16.f);
        sv.z = acc1[2] * (1.f / 16.f); sv.w = acc1[3] * (1.f / 16.f);
        *(float4*)&x1s[o * CH + c0] = sv;
      }
    }
  }
  __syncthreads();

  // ---- fused fiber einsum: x2[m,p,c] = (1/NG) sum_o x1s[o][c]*kR[(p*NG+o)*CH+c]
  int c = tid & 127, p0 = tid >> 7;
  float v[NG];
#pragma unroll
  for (int o = 0; o < NG; ++o) v[o] = x1s[o * CH + c];
#pragma unroll
  for (int pp = 0; pp < 6; ++pp) {
    int p = p0 * 6 + pp;
    float acc = 0.f;
#pragma unroll
    for (int o = 0; o < NG; ++o) acc += v[o] * kR[(p * NG + o) * CH + c];
    x2out[((size_t)m * NG + p) * CH + c] = acc * (1.0f / NG);
  }
}

// ---------- layer-2: stream t2, gather out, k-mean, fused einsum ----------

__global__ __launch_bounds__(256) void msg3b_kernel(
    const float* __restrict__ x, const int* __restrict__ knn,
    const uint2* __restrict__ t2g, const float* __restrict__ kR,
    float* __restrict__ x2out) {
  __shared__ float x1s[NG][CH];   // 6 KB
  int m = blockIdx.x;
  int tid = threadIdx.x, lane = tid & 63, w = tid >> 6;
  int r = lane & 15, gq = lane >> 4;
  int src = knn[m * KNN + r];

#pragma unroll 1
  for (int jt = 0; jt < 8; ++jt) {
#pragma unroll
    for (int t = 0; t < 3; ++t) {
      int o = w * 3 + t;
      int tile = m * NG + o;
      uint2 tv = t2g[((size_t)tile * 8 + jt) * 64 + lane];
      float4 xv = *(const float4*)(x + ((size_t)src * NG + o) * CH + jt * 16 + gq * 4);
      float a0 = ubf_lo(tv.x) * xv.x;
      float a1 = ubf_hi(tv.x) * xv.y;
      float a2 = ubf_lo(tv.y) * xv.z;
      float a3 = ubf_hi(tv.y) * xv.w;
#pragma unroll
      for (int st = 1; st < 16; st <<= 1) {
        a0 += __shfl_xor(a0, st, 64);
        a1 += __shfl_xor(a1, st, 64);
        a2 += __shfl_xor(a2, st, 64);
        a3 += __shfl_xor(a3, st, 64);
      }
      if (r == 0) {
        int c0 = jt * 16 + gq * 4;
        x1s[o][c0 + 0] = a0 * (1.f / 16.f);
        x1s[o][c0 + 1] = a1 * (1.f / 16.f);
        x1s[o][c0 + 2] = a2 * (1.f / 16.f);
        x1s[o][c0 + 3] = a3 * (1.f / 16.f);
      }
    }
  }
  __syncthreads();

  int c = tid & 127, p0 = tid >> 7;
  float v[NG];
#pragma unroll
  for (int o = 0; o < NG; ++o) v[o] = x1s[o][c];
#pragma unroll
  for (int pp = 0; pp < 6; ++pp) {
    int p = p0 * 6 + pp;
    float acc = 0.f;
#pragma unroll
    for (int o = 0; o < NG; ++o) acc += v[o] * kR[(p * NG + o) * CH + c];
    x2out[((size_t)m * NG + p) * CH + c] = acc * (1.0f / NG);
  }
}

// ---------- FALLBACK: round-4 fused edge pipeline (used if ws too small) ----------

__global__ __launch_bounds__(256) void msg_mfma_kernel(
    const float* __restrict__ x, const float* __restrict__ pos,
    const int* __restrict__ knn, const float* __restrict__ grid,
    const float* __restrict__ Bx,
    const uint4* __restrict__ w1f, const float* __restrict__ bx1,
    const uint4* __restrict__ w2f, const float* __restrict__ bx2,
    const uint4* __restrict__ wkf,
    float* __restrict__ x1out) {
  __shared__ uint4 hb[4][3][256];
  int m = blockIdx.x;
  int tid = threadIdx.x, lane = tid & 63, w = tid >> 6;
  int r = lane & 15, gq = lane >> 4;

  int src = knn[m * KNN + r];
  float rx = pos[src * 3 + 0] - pos[m * 3 + 0];
  float ry = pos[src * 3 + 1] - pos[m * 3 + 1];
  float rz = pos[src * 3 + 2] - pos[m * 3 + 2];

  bfrag ff[3][4];
#pragma unroll
  for (int t = 0; t < 3; ++t) {
    int o = w * 3 + t;
    float gx = grid[o * 3 + 0], gy = grid[o * 3 + 1], gz = grid[o * 3 + 2];
    float z = rx * gx + ry * gy + rz * gz;
    float ux = rx - z * gx, uy = ry - z * gy, uz = rz - z * gz;
    float rxy = sqrtf(ux * ux + uy * uy + uz * uz);
#pragma unroll
    for (int ks = 0; ks < 4; ++ks) {
      uint4 q;
      unsigned pk[4];
#pragma unroll
      for (int jh = 0; jh < 4; ++jh) {
        float v[2];
#pragma unroll
        for (int u = 0; u < 2; ++u) {
          int i = ks * 32 + gq * 8 + jh * 2 + u;
          int j = i & 63;
          float pv = TWO_PI_F * (rxy * Bx[j] + z * Bx[64 + j]);
          v[u] = (i < 64) ? __cosf(pv) : __sinf(pv);
        }
        pk[jh] = packbf2(v[0], v[1]);
      }
      q.x = pk[0]; q.y = pk[1]; q.z = pk[2]; q.w = pk[3];
      ff[t][ks] = __builtin_bit_cast(bfrag, q);
    }
  }

#pragma unroll 1
  for (int jt = 0; jt < 8; ++jt) {
    bfrag wf[4];
#pragma unroll
    for (int ks = 0; ks < 4; ++ks)
      wf[ks] = __builtin_bit_cast(bfrag, w1f[(jt * 4 + ks) * 64 + lane]);
    float4 bb = *(const float4*)(bx1 + jt * 16 + gq * 4);
    int cu = jt * 2 + (gq >> 1);
#pragma unroll
    for (int t = 0; t < 3; ++t) {
      f32x4 acc;
      acc[0] = bb.x; acc[1] = bb.y; acc[2] = bb.z; acc[3] = bb.w;
#pragma unroll
      for (int ks = 0; ks < 4; ++ks)
        acc = __builtin_amdgcn_mfma_f32_16x16x32_bf16(wf[ks], ff[t][ks], acc, 0, 0, 0);
      unsigned p0 = packbf2(gelu_t(acc[0]), gelu_t(acc[1]));
      unsigned p1 = packbf2(gelu_t(acc[2]), gelu_t(acc[3]));
      ((uint2*)&hb[w][t][0])[r * 32 + ((cu ^ r) << 1) + (gq & 1)] = make_uint2(p0, p1);
    }
  }
  bfrag h1f[3][4];
#pragma unroll
  for (int t = 0; t < 3; ++t)
#pragma unroll
    for (int ks = 0; ks < 4; ++ks)
      h1f[t][ks] = __builtin_bit_cast(bfrag, hb[w][t][r * 16 + ((ks * 4 + gq) ^ r)]);

#pragma unroll 1
  for (int jt = 0; jt < 8; ++jt) {
    bfrag wf[4];
#pragma unroll
    for (int ks = 0; ks < 4; ++ks)
      wf[ks] = __builtin_bit_cast(bfrag, w2f[(jt * 4 + ks) * 64 + lane]);
    float4 bb = *(const float4*)(bx2 + jt * 16 + gq * 4);
    int cu = jt * 2 + (gq >> 1);
#pragma unroll
    for (int t = 0; t < 3; ++t) {
      f32x4 acc;
      acc[0] = bb.x; acc[1] = bb.y; acc[2] = bb.z; acc[3] = bb.w;
#pragma unroll
      for (int ks = 0; ks < 4; ++ks)
        acc = __builtin_amdgcn_mfma_f32_16x16x32_bf16(wf[ks], h1f[t][ks], acc, 0, 0, 0);
      unsigned p0 = packbf2(gelu_t(acc[0]), gelu_t(acc[1]));
      unsigned p1 = packbf2(gelu_t(acc[2]), gelu_t(acc[3]));
      ((uint2*)&hb[w][t][0])[r * 32 + ((cu ^ r) << 1) + (gq & 1)] = make_uint2(p0, p1);
    }
  }
  bfrag h2f[3][4];
#pragma unroll
  for (int t = 0; t < 3; ++t)
#pragma unroll
    for (int ks = 0; ks < 4; ++ks)
      h2f[t][ks] = __builtin_bit_cast(bfrag, hb[w][t][r * 16 + ((ks * 4 + gq) ^ r)]);

#pragma unroll 1
  for (int jt = 0; jt < 8; ++jt) {
    bfrag wf[4];
#pragma unroll
    for (int ks = 0; ks < 4; ++ks)
      wf[ks] = __builtin_bit_cast(bfrag, wkf[(jt * 4 + ks) * 64 + lane]);
#pragma unroll
    for (int t = 0; t < 3; ++t) {
      int o = w * 3 + t;
      f32x4 acc;
      acc[0] = 0.f; acc[1] = 0.f; acc[2] = 0.f; acc[3] = 0.f;
#pragma unroll
      for (int ks = 0; ks < 4; ++ks)
        acc = __builtin_amdgcn_mfma_f32_16x16x32_bf16(wf[ks], h2f[t][ks], acc, 0, 0, 0);
      float4 xv = *(const float4*)(x + ((size_t)src * NG + o) * CH + jt * 16 + gq * 4);
      acc[0] *= xv.x; acc[1] *= xv.y; acc[2] *= xv.z; acc[3] *= xv.w;
#pragma unroll
      for (int st = 1; st < 16; st <<= 1) {
        acc[0] += __shfl_xor(acc[0], st, 64);
        acc[1] += __shfl_xor(acc[1], st, 64);
        acc[2] += __shfl_xor(acc[2], st, 64);
        acc[3] += __shfl_xor(acc[3], st, 64);
      }
      if (r == 0) {
        float4 sv;
        sv.x = acc[0] * (1.f / 16.f); sv.y = acc[1] * (1.f / 16.f);
        sv.z = acc[2] * (1.f / 16.f); sv.w = acc[3] * (1.f / 16.f);
        *(float4*)(x1out + ((size_t)m * NG + o) * CH + jt * 16 + gq * 4) = sv;
      }
    }
  }
}

// ---------- LN + ConvNeXt MLP via MFMA ----------

__global__ __launch_bounds__(256) void mlp_mfma_kernel(
    const float* __restrict__ xin, const float* __restrict__ x2,
    const float* __restrict__ g, const float* __restrict__ b,
    const uint4* __restrict__ w1t, const float* __restrict__ b1,
    const uint4* __restrict__ w2t, const float* __restrict__ b2,
    const float* __restrict__ s, float* __restrict__ xout) {
  __shared__ uint4 smem[1280];
  int tid = threadIdx.x;
  int rowbase = blockIdx.x * 16;

  {
    int row = tid >> 4, p = tid & 15;
    const float4* xr = (const float4*)(x2 + (size_t)(rowbase + row) * CH + p * 8);
    float4 v0 = xr[0], v1 = xr[1];
    float sum = v0.x + v0.y + v0.z + v0.w + v1.x + v1.y + v1.z + v1.w;
    sum += __shfl_xor(sum, 1, 64); sum += __shfl_xor(sum, 2, 64);
    sum += __shfl_xor(sum, 4, 64); sum += __shfl_xor(sum, 8, 64);
    float mu = sum * (1.0f / CH);
    float sq = 0.f;
    {
      float d;
      d = v0.x - mu; sq += d * d; d = v0.y - mu; sq += d * d;
      d = v0.z - mu; sq += d * d; d = v0.w - mu; sq += d * d;
      d = v1.x - mu; sq += d * d; d = v1.y - mu; sq += d * d;
      d = v1.z - mu; sq += d * d; d = v1.w - mu; sq += d * d;
    }
    sq += __shfl_xor(sq, 1, 64); sq += __shfl_xor(sq, 2, 64);
    sq += __shfl_xor(sq, 4, 64); sq += __shfl_xor(sq, 8, 64);
    float rstd = rsqrtf(sq * (1.0f / CH) + 1e-5f);
    const float4* gv = (const float4*)(g + p * 8);
    const float4* bv = (const float4*)(b + p * 8);
    float4 g0 = gv[0], g1 = gv[1], b0 = bv[0], b1v = bv[1];
    float n0 = (v0.x - mu) * rstd * g0.x + b0.x;
    float n1 = (v0.y - mu) * rstd * g0.y + b0.y;
    float n2 = (v0.z - mu) * rstd * g0.z + b0.z;
    float n3 = (v0.w - mu) * rstd * g0.w + b0.w;
    float n4 = (v1.x - mu) * rstd * g1.x + b1v.x;
    float n5 = (v1.y - mu) * rstd * g1.y + b1v.y;
    float n6 = (v1.z - mu) * rstd * g1.z + b1v.z;
    float n7 = (v1.w - mu) * rstd * g1.w + b1v.w;
    uint4 pk;
    pk.x = packbf2(n0, n1); pk.y = packbf2(n2, n3);
    pk.z = packbf2(n4, n5); pk.w = packbf2(n6, n7);
    smem[row * 16 + (p ^ row)] = pk;
  }
  __syncthreads();

  int lane = tid & 63, w = tid >> 6;
  int r = lane & 15, gq = lane >> 4;

  bfrag xf[4];
#pragma unroll
  for (int ks = 0; ks < 4; ++ks) {
    uint4 raw = smem[r * 16 + ((ks * 4 + gq) ^ r)];
    xf[ks] = __builtin_bit_cast(bfrag, raw);
  }

  uint2* hb2 = (uint2*)smem;
#pragma unroll 2
  for (int jj = 0; jj < 8; ++jj) {
    int jt = w * 8 + jj;
    f32x4 acc;
    {
      float4 bb = *(const float4*)(b1 + jt * 16 + gq * 4);
      acc[0] = bb.x; acc[1] = bb.y; acc[2] = bb.z; acc[3] = bb.w;
    }
#pragma unroll
    for (int ks = 0; ks < 4; ++ks) {
      uint4 raw = w1t[(jt * 4 + ks) * 64 + lane];
      bfrag a = __builtin_bit_cast(bfrag, raw);
      acc = __builtin_amdgcn_mfma_f32_16x16x32_bf16(a, xf[ks], acc, 0, 0, 0);
    }
    unsigned p0 = packbf2(gelu_t(acc[0]), gelu_t(acc[1]));
    unsigned p1 = packbf2(gelu_t(acc[2]), gelu_t(acc[3]));
    int sl = (jt * 2 + (gq >> 1)) ^ r;
    hb2[512 + r * 128 + sl * 2 + (gq & 1)] = make_uint2(p0, p1);
  }
  __syncthreads();

#pragma unroll 2
  for (int cc = 0; cc < 2; ++cc) {
    int ct = w * 2 + cc;
    f32x4 acc;
    {
      float4 bb = *(const float4*)(b2 + ct * 16 + gq * 4);
      acc[0] = bb.x; acc[1] = bb.y; acc[2] = bb.z; acc[3] = bb.w;
    }
#pragma unroll
    for (int ks = 0; ks < 16; ++ks) {
      uint4 hraw = smem[256 + r * 64 + ((ks * 4 + gq) ^ r)];
      bfrag hf = __builtin_bit_cast(bfrag, hraw);
      uint4 wraw = w2t[(ct * 16 + ks) * 64 + lane];
      bfrag wf = __builtin_bit_cast(bfrag, wraw);
      acc = __builtin_amdgcn_mfma_f32_16x16x32_bf16(wf, hf, acc, 0, 0, 0);
    }
    int c0 = ct * 16 + gq * 4;
    size_t ro = (size_t)(rowbase + r) * CH + c0;
    float4 xi = *(const float4*)(xin + ro);
    float4 sv = *(const float4*)(s + c0);
    float4 ov;
    ov.x = xi.x + sv.x * acc[0];
    ov.y = xi.y + sv.y * acc[1];
    ov.z = xi.z + sv.z * acc[2];
    ov.w = xi.w + sv.w * acc[3];
    *(float4*)(xout + ro) = ov;
  }
}

// ---------- launch ----------

extern "C" void kernel_launch(void* const* d_in, const int* in_sizes, int n_in,
                              void* d_out, int out_size, void* d_ws, size_t ws_size,
                              hipStream_t stream) {
  (void)in_sizes; (void)n_in; (void)out_size;
  const float* x    = (const float*)d_in[0];
  const float* pos  = (const float*)d_in[1];
  const float* grid = (const float*)d_in[2];
  const float* Bx   = (const float*)d_in[3];
  float* out = (float*)d_out;

  char* wsb = (char*)d_ws;
  int* knn   = (int*)wsb;                                   // 131072 B
  float* kR1 = (float*)(wsb + 131072);
  float* kR2 = kR1 + NG * NG * CH;
  float* x1  = kR2 + NG * NG * CH;
  float* x2  = x1 + (size_t)MTOT * NG * CH;
  unsigned short* w1ta = (unsigned short*)(x2 + (size_t)MTOT * NG * CH);
  unsigned short* w2ta = w1ta + 65536;
  unsigned short* w1tb = w2ta + 65536;
  unsigned short* w2tb = w1tb + 65536;
  unsigned short* wx1f = w2tb + 65536;     // 16384 each
  unsigned short* wx2f = wx1f + 16384;
  unsigned short* wk1f = wx2f + 16384;
  unsigned short* wk2f = wk1f + 16384;
  uint2* t2g = (uint2*)(wk2f + 16384);     // 100,663,296 B
  size_t need = (size_t)26099712 + (size_t)MTOT * NG * 4 * 64 * 16;
  bool big_ws = ws_size >= need;

  knn_kernel<<<MTOT / 4, 256, 0, stream>>>(pos, knn);
  kbr_kernel<<<NG * NG, CH, 0, stream>>>(grid, (const float*)d_in[4],
                                         (const float*)d_in[9], (const float*)d_in[10],
                                         (const float*)d_in[11], (const float*)d_in[12],
                                         (const float*)d_in[14], (const float*)d_in[23],
                                         kR1, kR2);
  pack_all_kernel<<<160, 256, 0, stream>>>(
      (const float*)d_in[17], (const float*)d_in[19],
      (const float*)d_in[26], (const float*)d_in[28],
      (const float*)d_in[5], (const float*)d_in[7],
      (const float*)d_in[13], (const float*)d_in[22],
      w1ta, w2ta, w1tb, w2tb, wx1f, wx2f, wk1f, wk2f);

  if (big_ws) {
    // layer 1 (fused edge pipeline + t2 precompute + einsum)
    kbx_fused_kernel<<<MTOT, 256, 0, stream>>>(pos, knn, grid, Bx,
        (const uint4*)wx1f, (const float*)d_in[6],
        (const uint4*)wx2f, (const float*)d_in[8],
        (const uint4*)wk1f, (const uint4*)wk2f,
        x, kR1, t2g, x2);
    mlp_mfma_kernel<<<(MTOT * NG) / 16, 256, 0, stream>>>(x, x2,
        (const float*)d_in[15], (const float*)d_in[16],
        (const uint4*)w1ta, (const float*)d_in[18],
        (const uint4*)w2ta, (const float*)d_in[20],
        (const float*)d_in[21], out);
    // layer 2 (stream t2 + gather out + einsum)
    msg3b_kernel<<<MTOT, 256, 0, stream>>>(out, knn, (const uint2*)t2g, kR2, x2);
    mlp_mfma_kernel<<<(MTOT * NG) / 16, 256, 0, stream>>>(out, x2,
        (const float*)d_in[24], (const float*)d_in[25],
        (const uint4*)w1tb, (const float*)d_in[27],
        (const uint4*)w2tb, (const float*)d_in[29],
        (const float*)d_in[30], out);
  } else {
    msg_mfma_kernel<<<MTOT, 256, 0, stream>>>(x, pos, knn, grid, Bx,
        (const uint4*)wx1f, (const float*)d_in[6],
        (const uint4*)wx2f, (const float*)d_in[8],
        (const uint4*)wk1f, x1);
    einsum_kernel<<<MTOT, CH, 0, stream>>>(x1, kR1, x2);
    mlp_mfma_kernel<<<(MTOT * NG) / 16, 256, 0, stream>>>(x, x2,
        (const float*)d_in[15], (const float*)d_in[16],
        (const uint4*)w1ta, (const float*)d_in[18],
        (const uint4*)w2ta, (const float*)d_in[20],
        (const float*)d_in[21], out);
    msg_mfma_kernel<<<MTOT, 256, 0, stream>>>(out, pos, knn, grid, Bx,
        (const uint4*)wx1f, (const float*)d_in[6],
        (const uint4*)wx2f, (const float*)d_in[8],
        (const uint4*)wk2f, x1);
    einsum_kernel<<<MTOT, CH, 0, stream>>>(x1, kR2, x2);
    mlp_mfma_kernel<<<(MTOT * NG) / 16, 256, 0, stream>>>(out, x2,
        (const float*)d_in[24], (const float*)d_in[25],
        (const uint4*)w1tb, (const float*)d_in[27],
        (const uint4*)w2tb, (const float*)d_in[29],
        (const float*)d_in[30], out);
  }
}

// Round 13
// 210.259 us; speedup vs baseline: 1.2337x; 1.0571x over previous
//
#include <hip/hip_runtime.h>
#include <hip/hip_bf16.h>
#include <math.h>

#define BG 8
#define NNODES 256
#define KNN 16
#define NG 12
#define CH 128
#define MTOT 2048
#define TWO_PI_F 6.283185307179586f

typedef __attribute__((ext_vector_type(8))) short bfrag;
typedef __attribute__((ext_vector_type(4))) float f32x4;

// ---------- helpers ----------

__device__ __forceinline__ float gelu_t(float x) {
  float x3 = x * x * x;
  float y = 0.7978845608028654f * (x + 0.044715f * x3);
  float e = __expf(2.0f * y);
  float th = 1.0f - 2.0f / (e + 1.0f);
  return 0.5f * x * (1.0f + th);
}

__device__ __forceinline__ unsigned packbf2(float a, float b) {
  unsigned ua = __float_as_uint(a), ub = __float_as_uint(b);
  ua = (ua + 0x7fffu + ((ua >> 16) & 1u)) >> 16;    // RNE to bf16
  ub = (ub + 0x7fffu + ((ub >> 16) & 1u)) >> 16;
  return ua | (ub << 16);
}
__device__ __forceinline__ unsigned short f2bf(float f) {
  unsigned u = __float_as_uint(f);
  u = (u + 0x7fffu + ((u >> 16) & 1u)) >> 16;
  return (unsigned short)u;
}
__device__ __forceinline__ float ubf_lo(unsigned p) { return __uint_as_float(p << 16); }
__device__ __forceinline__ float ubf_hi(unsigned p) { return __uint_as_float(p & 0xffff0000u); }

// gelu via sigmoid form; exp2-domain, ~7 insts
__device__ __forceinline__ float gelu_s(float x) {
  const float A  = -2.0f * 0.7978845608028654f * 1.4426950408889634f;
  const float CA = A * 0.044715f;
  float x2 = x * x;
  float q  = __builtin_fmaf(CA, x2, A);
  float t  = x * q;
  float e; asm("v_exp_f32 %0, %1" : "=v"(e) : "v"(t));     // 2^t
  float d = 1.0f + e;
  float r; asm("v_rcp_f32 %0, %1" : "=v"(r) : "v"(d));
  return x * r;
}

__device__ __forceinline__ unsigned pkcvt(float a, float b) {
  unsigned r;
  asm("v_cvt_pk_bf16_f32 %0, %1, %2" : "=v"(r) : "v"(a), "v"(b));
  return r;
}

__device__ __forceinline__ void cossin(float w, float& c, float& s) {
  float f; asm("v_fract_f32 %0, %1" : "=v"(f) : "v"(w));
  asm("v_cos_f32 %0, %1" : "=v"(c) : "v"(f));
  asm("v_sin_f32 %0, %1" : "=v"(s) : "v"(f));
}

// 16-lane row sum via DPP rotate-adds: 4 VALU insts, no LDS/bpermute path.
// After the 4 steps every lane in each 16-lane row holds the row's total.
__device__ __forceinline__ float dpp_sum16(float x) {
  asm("v_add_f32 %0, %0, %0 row_ror:8 row_mask:0xf bank_mask:0xf" : "+v"(x));
  asm("v_add_f32 %0, %0, %0 row_ror:4 row_mask:0xf bank_mask:0xf" : "+v"(x));
  asm("v_add_f32 %0, %0, %0 row_ror:2 row_mask:0xf bank_mask:0xf" : "+v"(x));
  asm("v_add_f32 %0, %0, %0 row_ror:1 row_mask:0xf bank_mask:0xf" : "+v"(x));
  return x;
}

__device__ __forceinline__ unsigned long long shfl_xor64(unsigned long long v, int st) {
  unsigned lo = (unsigned)v, hi = (unsigned)(v >> 32);
  lo = __shfl_xor(lo, st, 64);
  hi = __shfl_xor(hi, st, 64);
  return ((unsigned long long)hi << 32) | lo;
}

// ---------- kNN: one wave per node ----------

__global__ __launch_bounds__(256) void knn_kernel(const float* __restrict__ pos,
                                                  int* __restrict__ knn) {
  __shared__ float sx[NNODES], sy[NNODES], sz[NNODES];
  int w = threadIdx.x >> 6, lane = threadIdx.x & 63;
  int node = blockIdx.x * 4 + w;
  int b = node >> 8;
  int gbase = b * NNODES;
  int t = threadIdx.x;
  sx[t] = pos[(gbase + t) * 3 + 0];
  sy[t] = pos[(gbase + t) * 3 + 1];
  sz[t] = pos[(gbase + t) * 3 + 2];
  __syncthreads();
  int i = node & 255;
  float xi = sx[i], yi = sy[i], zi = sz[i];
  unsigned long long key[4];
#pragma unroll
  for (int u = 0; u < 4; ++u) {
    int j = lane * 4 + u;
    float dx = xi - sx[j], dy = yi - sy[j], dz = zi - sz[j];
    float d = dx * dx + dy * dy + dz * dz;
    key[u] = ((unsigned long long)__float_as_uint(d) << 32) | (unsigned)j;
  }
  {
    unsigned long long tmp;
#define CSWAP(a, bq) if (key[bq] < key[a]) { tmp = key[a]; key[a] = key[bq]; key[bq] = tmp; }
    CSWAP(0, 1) CSWAP(2, 3) CSWAP(0, 2) CSWAP(1, 3) CSWAP(1, 2)
#undef CSWAP
  }
  int ptr = 0;
#pragma unroll 1
  for (int r = 0; r < KNN; ++r) {
    unsigned long long cand = (ptr < 4) ? key[ptr] : ~0ULL;
    unsigned long long mn = cand;
#pragma unroll
    for (int st = 1; st < 64; st <<= 1) {
      unsigned long long o = shfl_xor64(mn, st);
      if (o < mn) mn = o;
    }
    if (cand == mn) ptr++;
    if (lane == 0) knn[node * KNN + r] = gbase + (int)(mn & 0xffffffffu);
  }
}

// ---------- kb_R -> kR ----------

__global__ void kbr_kernel(const float* __restrict__ grid, const float* __restrict__ BR,
                           const float* __restrict__ WR1, const float* __restrict__ bR1,
                           const float* __restrict__ WR2, const float* __restrict__ bR2,
                           const float* __restrict__ WkR1, const float* __restrict__ WkR2,
                           float* __restrict__ kR1, float* __restrict__ kR2) {
  int r = blockIdx.x;
  int p = r / NG, o = r % NG;
  int c = threadIdx.x;
  float a = grid[p * 3 + 0] * grid[o * 3 + 0] + grid[p * 3 + 1] * grid[o * 3 + 1] +
            grid[p * 3 + 2] * grid[o * 3 + 2];
  __shared__ float fb[CH], hh[CH];
  {
    int j = c & 63;
    float pv = TWO_PI_F * (a * BR[j]);
    fb[c] = (c < 64) ? cosf(pv) : sinf(pv);
  }
  __syncthreads();
  float acc = bR1[c];
  for (int i = 0; i < CH; ++i) acc += fb[i] * WR1[i * CH + c];
  float h1 = gelu_t(acc);
  __syncthreads();
  hh[c] = h1;
  __syncthreads();
  acc = bR2[c];
  for (int i = 0; i < CH; ++i) acc += hh[i] * WR2[i * CH + c];
  float h2 = gelu_t(acc);
  __syncthreads();
  fb[c] = h2;
  __syncthreads();
  float t1 = 0.f, t2 = 0.f;
  for (int i = 0; i < CH; ++i) {
    float v = fb[i];
    t1 += v * WkR1[i * CH + c];
    t2 += v * WkR2[i * CH + c];
  }
  kR1[r * CH + c] = t1;
  kR2[r * CH + c] = t2;
}

// ---------- fiber einsum (fallback path only) ----------

__global__ void einsum_kernel(const float* __restrict__ x1, const float* __restrict__ kR,
                              float* __restrict__ x2) {
  int m = blockIdx.x, c = threadIdx.x;
  float v[NG];
#pragma unroll
  for (int o = 0; o < NG; ++o) v[o] = x1[((size_t)m * NG + o) * CH + c];
#pragma unroll
  for (int p = 0; p < NG; ++p) {
    float acc = 0.f;
#pragma unroll
    for (int o = 0; o < NG; ++o) acc += v[o] * kR[(p * NG + o) * CH + c];
    x2[((size_t)m * NG + p) * CH + c] = acc * (1.0f / NG);
  }
}

// ---------- weight fragment packing (all 8 matrices, one launch) ----------
// fragment element (tile,ks,lane,j) = W[ks*32 + (lane>>4)*8 + j][tile*16 + (lane&15)]

__device__ __forceinline__ void pack_body(const float* __restrict__ W, int K, int N,
                                          unsigned short* __restrict__ out, int tid) {
  int lane = tid & 63;
  int t = tid >> 6;
  int ksteps = K / 32;
  int ks = t % ksteps, tile = t / ksteps;
  int col = tile * 16 + (lane & 15);
  int k0 = ks * 32 + (lane >> 4) * 8;
#pragma unroll
  for (int j = 0; j < 8; ++j)
    out[(size_t)tid * 8 + j] = f2bf(W[(size_t)(k0 + j) * N + col]);
}

__global__ __launch_bounds__(256) void pack_all_kernel(
    const float* __restrict__ W1a, const float* __restrict__ W2a,
    const float* __restrict__ W1b, const float* __restrict__ W2b,
    const float* __restrict__ wx1, const float* __restrict__ wx2,
    const float* __restrict__ wk1, const float* __restrict__ wk2,
    unsigned short* __restrict__ o1a, unsigned short* __restrict__ o2a,
    unsigned short* __restrict__ o1b, unsigned short* __restrict__ o2b,
    unsigned short* __restrict__ ox1, unsigned short* __restrict__ ox2,
    unsigned short* __restrict__ ok1, unsigned short* __restrict__ ok2) {
  int blk = blockIdx.x;
  if (blk < 32)        pack_body(W1a, CH, 4 * CH, o1a, blk * 256 + threadIdx.x);
  else if (blk < 64)   pack_body(W2a, 4 * CH, CH, o2a, (blk - 32) * 256 + threadIdx.x);
  else if (blk < 96)   pack_body(W1b, CH, 4 * CH, o1b, (blk - 64) * 256 + threadIdx.x);
  else if (blk < 128)  pack_body(W2b, 4 * CH, CH, o2b, (blk - 96) * 256 + threadIdx.x);
  else if (blk < 136)  pack_body(wx1, CH, CH, ox1, (blk - 128) * 256 + threadIdx.x);
  else if (blk < 144)  pack_body(wx2, CH, CH, ox2, (blk - 136) * 256 + threadIdx.x);
  else if (blk < 152)  pack_body(wk1, CH, CH, ok1, (blk - 144) * 256 + threadIdx.x);
  else                 pack_body(wk2, CH, CH, ok2, (blk - 152) * 256 + threadIdx.x);
}

// ---------- fused layer-1 edge pipeline + t2 precompute ----------
// r12 structure (24 KB half-phase LDS transpose, fully unrolled phases,
// merged GEMM3a+3b) + DPP rotate-add reductions replacing ds_bpermute
// butterflies (the 1.57M bank-conflict source).

__global__ __launch_bounds__(256) void kbx_fused_kernel(
    const float* __restrict__ pos, const int* __restrict__ knn,
    const float* __restrict__ grid, const float* __restrict__ Bx,
    const uint4* __restrict__ w1f, const float* __restrict__ bx1,
    const uint4* __restrict__ w2f, const float* __restrict__ bx2,
    const uint4* __restrict__ wk1f, const uint4* __restrict__ wk2f,
    const float* __restrict__ x, const float* __restrict__ kR,
    uint2* __restrict__ t2g, float* __restrict__ x2out) {
  __shared__ uint4 hb[4][3][128];          // 24 KB half-tile transpose buffers
  float* x1s = (float*)hb;                 // aliased AFTER barrier (6 KB)
  int m = blockIdx.x;
  int tid = threadIdx.x, lane = tid & 63, w = tid >> 6;
  int r = lane & 15, gq = lane >> 4;

  int src = knn[m * KNN + r];
  float rx = pos[src * 3 + 0] - pos[m * 3 + 0];
  float ry = pos[src * 3 + 1] - pos[m * 3 + 1];
  float rz = pos[src * 3 + 2] - pos[m * 3 + 2];

  float4 brA0 = *(const float4*)(Bx + gq * 8);
  float4 brA1 = *(const float4*)(Bx + gq * 8 + 4);
  float4 brB0 = *(const float4*)(Bx + 32 + gq * 8);
  float4 brB1 = *(const float4*)(Bx + 32 + gq * 8 + 4);
  float4 bzA0 = *(const float4*)(Bx + 64 + gq * 8);
  float4 bzA1 = *(const float4*)(Bx + 64 + gq * 8 + 4);
  float4 bzB0 = *(const float4*)(Bx + 96 + gq * 8);
  float4 bzB1 = *(const float4*)(Bx + 96 + gq * 8 + 4);
  float brA[8] = {brA0.x, brA0.y, brA0.z, brA0.w, brA1.x, brA1.y, brA1.z, brA1.w};
  float brB[8] = {brB0.x, brB0.y, brB0.z, brB0.w, brB1.x, brB1.y, brB1.z, brB1.w};
  float bzA[8] = {bzA0.x, bzA0.y, bzA0.z, bzA0.w, bzA1.x, bzA1.y, bzA1.z, bzA1.w};
  float bzB[8] = {bzB0.x, bzB0.y, bzB0.z, bzB0.w, bzB1.x, bzB1.y, bzB1.z, bzB1.w};

  // ---- RFF features as B-fragments for all 3 tiles
  bfrag ff[3][4];
#pragma unroll
  for (int t = 0; t < 3; ++t) {
    int o = w * 3 + t;
    float gx = grid[o * 3 + 0], gy = grid[o * 3 + 1], gz = grid[o * 3 + 2];
    float z = rx * gx + ry * gy + rz * gz;
    float ux = rx - z * gx, uy = ry - z * gy, uz = rz - z * gz;
    float rxy = sqrtf(ux * ux + uy * uy + uz * uz);
    float cA[8], sA[8], cB[8], sB[8];
#pragma unroll
    for (int u = 0; u < 8; ++u) {
      float wA = __builtin_fmaf(z, bzA[u], rxy * brA[u]);
      float wB = __builtin_fmaf(z, bzB[u], rxy * brB[u]);
      cossin(wA, cA[u], sA[u]);
      cossin(wB, cB[u], sB[u]);
    }
    uint4 q;
    q.x = pkcvt(cA[0], cA[1]); q.y = pkcvt(cA[2], cA[3]);
    q.z = pkcvt(cA[4], cA[5]); q.w = pkcvt(cA[6], cA[7]);
    ff[t][0] = __builtin_bit_cast(bfrag, q);
    q.x = pkcvt(cB[0], cB[1]); q.y = pkcvt(cB[2], cB[3]);
    q.z = pkcvt(cB[4], cB[5]); q.w = pkcvt(cB[6], cB[7]);
    ff[t][1] = __builtin_bit_cast(bfrag, q);
    q.x = pkcvt(sA[0], sA[1]); q.y = pkcvt(sA[2], sA[3]);
    q.z = pkcvt(sA[4], sA[5]); q.w = pkcvt(sA[6], sA[7]);
    ff[t][2] = __builtin_bit_cast(bfrag, q);
    q.x = pkcvt(sB[0], sB[1]); q.y = pkcvt(sB[2], sB[3]);
    q.z = pkcvt(sB[4], sB[5]); q.w = pkcvt(sB[6], sB[7]);
    ff[t][3] = __builtin_bit_cast(bfrag, q);
  }

  // ---- GEMM1: h1 = gelu(f @ Wx1 + bx1), half-phase LDS transpose
  bfrag h1f[3][4];
#pragma unroll
  for (int h = 0; h < 2; ++h) {           // fully unrolled (rule #20)
#pragma unroll 2
    for (int jl = 0; jl < 4; ++jl) {
      int jt = h * 4 + jl;
      bfrag wf[4];
#pragma unroll
      for (int ks = 0; ks < 4; ++ks)
        wf[ks] = __builtin_bit_cast(bfrag, w1f[(jt * 4 + ks) * 64 + lane]);
      float4 bb = *(const float4*)(bx1 + jt * 16 + gq * 4);
      int cu = jl * 2 + (gq >> 1);         // 0..7 within half
#pragma unroll
      for (int t = 0; t < 3; ++t) {
        f32x4 acc;
        acc[0] = bb.x; acc[1] = bb.y; acc[2] = bb.z; acc[3] = bb.w;
#pragma unroll
        for (int ks = 0; ks < 4; ++ks)
          acc = __builtin_amdgcn_mfma_f32_16x16x32_bf16(wf[ks], ff[t][ks], acc, 0, 0, 0);
        unsigned p0 = pkcvt(gelu_s(acc[0]), gelu_s(acc[1]));
        unsigned p1 = pkcvt(gelu_s(acc[2]), gelu_s(acc[3]));
        ((uint2*)&hb[w][t][0])[r * 16 + ((cu ^ (r & 7)) << 1) + (gq & 1)] =
            make_uint2(p0, p1);
      }
    }
#pragma unroll
    for (int t = 0; t < 3; ++t)
#pragma unroll
      for (int ksl = 0; ksl < 2; ++ksl)
        h1f[t][h * 2 + ksl] = __builtin_bit_cast(bfrag,
            hb[w][t][r * 8 + ((ksl * 4 + gq) ^ (r & 7))]);
  }

  // ---- GEMM2: h2 = gelu(h1 @ Wx2 + bx2), half-phase LDS transpose
  bfrag h2f[3][4];
#pragma unroll
  for (int h = 0; h < 2; ++h) {
#pragma unroll 2
    for (int jl = 0; jl < 4; ++jl) {
      int jt = h * 4 + jl;
      bfrag wf[4];
#pragma unroll
      for (int ks = 0; ks < 4; ++ks)
        wf[ks] = __builtin_bit_cast(bfrag, w2f[(jt * 4 + ks) * 64 + lane]);
      float4 bb = *(const float4*)(bx2 + jt * 16 + gq * 4);
      int cu = jl * 2 + (gq >> 1);
#pragma unroll
      for (int t = 0; t < 3; ++t) {
        f32x4 acc;
        acc[0] = bb.x; acc[1] = bb.y; acc[2] = bb.z; acc[3] = bb.w;
#pragma unroll
        for (int ks = 0; ks < 4; ++ks)
          acc = __builtin_amdgcn_mfma_f32_16x16x32_bf16(wf[ks], h1f[t][ks], acc, 0, 0, 0);
        unsigned p0 = pkcvt(gelu_s(acc[0]), gelu_s(acc[1]));
        unsigned p1 = pkcvt(gelu_s(acc[2]), gelu_s(acc[3]));
        ((uint2*)&hb[w][t][0])[r * 16 + ((cu ^ (r & 7)) << 1) + (gq & 1)] =
            make_uint2(p0, p1);
      }
    }
#pragma unroll
    for (int t = 0; t < 3; ++t)
#pragma unroll
      for (int ksl = 0; ksl < 2; ++ksl)
        h2f[t][h * 2 + ksl] = __builtin_bit_cast(bfrag,
            hb[w][t][r * 8 + ((ksl * 4 + gq) ^ (r & 7))]);
  }

  __syncthreads();   // all transpose reads done -> x1s may alias hb

  // ---- merged GEMM3a+3b with DPP reductions
#pragma unroll 2
  for (int jt = 0; jt < 8; ++jt) {
    bfrag wfa[4], wfb[4];
#pragma unroll
    for (int ks = 0; ks < 4; ++ks) {
      wfa[ks] = __builtin_bit_cast(bfrag, wk1f[(jt * 4 + ks) * 64 + lane]);
      wfb[ks] = __builtin_bit_cast(bfrag, wk2f[(jt * 4 + ks) * 64 + lane]);
    }
#pragma unroll
    for (int t = 0; t < 3; ++t) {
      int o = w * 3 + t;
      int tile = m * NG + o;
      // issue gather early: independent of MFMA results
      float4 xv = *(const float4*)(x + ((size_t)src * NG + o) * CH + jt * 16 + gq * 4);
      f32x4 acc1, acc2;
      acc1[0] = 0.f; acc1[1] = 0.f; acc1[2] = 0.f; acc1[3] = 0.f;
      acc2[0] = 0.f; acc2[1] = 0.f; acc2[2] = 0.f; acc2[3] = 0.f;
#pragma unroll
      for (int ks = 0; ks < 4; ++ks) {
        acc1 = __builtin_amdgcn_mfma_f32_16x16x32_bf16(wfa[ks], h2f[t][ks], acc1, 0, 0, 0);
        acc2 = __builtin_amdgcn_mfma_f32_16x16x32_bf16(wfb[ks], h2f[t][ks], acc2, 0, 0, 0);
      }
      // t2 store first (no cross-lane dependency)
      uint2 pv;
      pv.x = pkcvt(acc2[0], acc2[1]);
      pv.y = pkcvt(acc2[2], acc2[3]);
      t2g[((size_t)tile * 8 + jt) * 64 + lane] = pv;
      // gather-mul + k-mean reduce (DPP rotate-add, all-VALU)
      float s0 = dpp_sum16(acc1[0] * xv.x);
      float s1 = dpp_sum16(acc1[1] * xv.y);
      float s2 = dpp_sum16(acc1[2] * xv.z);
      float s3 = dpp_sum16(acc1[3] * xv.w);
      if (r == 0) {
        int c0 = jt * 16 + gq * 4;
        float4 sv;
        sv.x = s0 * (1.f / 16.f); sv.y = s1 * (1.f / 16.f);
        sv.z = s2 * (1.f / 16.f); sv.w = s3 * (1.f / 16.f);
        *(float4*)&x1s[o * CH + c0] = sv;
      }
    }
  }
  __syncthreads();

  // ---- fused fiber einsum: x2[m,p,c] = (1/NG) sum_o x1s[o][c]*kR[(p*NG+o)*CH+c]
  int c = tid & 127, p0 = tid >> 7;
  float v[NG];
#pragma unroll
  for (int o = 0; o < NG; ++o) v[o] = x1s[o * CH + c];
#pragma unroll
  for (int pp = 0; pp < 6; ++pp) {
    int p = p0 * 6 + pp;
    float acc = 0.f;
#pragma unroll
    for (int o = 0; o < NG; ++o) acc += v[o] * kR[(p * NG + o) * CH + c];
    x2out[((size_t)m * NG + p) * CH + c] = acc * (1.0f / NG);
  }
}

// ---------- layer-2: stream t2, gather out, k-mean (DPP), fused einsum ----------

__global__ __launch_bounds__(256) void msg3b_kernel(
    const float* __restrict__ x, const int* __restrict__ knn,
    const uint2* __restrict__ t2g, const float* __restrict__ kR,
    float* __restrict__ x2out) {
  __shared__ float x1s[NG][CH];   // 6 KB
  int m = blockIdx.x;
  int tid = threadIdx.x, lane = tid & 63, w = tid >> 6;
  int r = lane & 15, gq = lane >> 4;
  int src = knn[m * KNN + r];

#pragma unroll 1
  for (int jt = 0; jt < 8; ++jt) {
#pragma unroll
    for (int t = 0; t < 3; ++t) {
      int o = w * 3 + t;
      int tile = m * NG + o;
      uint2 tv = t2g[((size_t)tile * 8 + jt) * 64 + lane];
      float4 xv = *(const float4*)(x + ((size_t)src * NG + o) * CH + jt * 16 + gq * 4);
      float a0 = dpp_sum16(ubf_lo(tv.x) * xv.x);
      float a1 = dpp_sum16(ubf_hi(tv.x) * xv.y);
      float a2 = dpp_sum16(ubf_lo(tv.y) * xv.z);
      float a3 = dpp_sum16(ubf_hi(tv.y) * xv.w);
      if (r == 0) {
        int c0 = jt * 16 + gq * 4;
        x1s[o][c0 + 0] = a0 * (1.f / 16.f);
        x1s[o][c0 + 1] = a1 * (1.f / 16.f);
        x1s[o][c0 + 2] = a2 * (1.f / 16.f);
        x1s[o][c0 + 3] = a3 * (1.f / 16.f);
      }
    }
  }
  __syncthreads();

  int c = tid & 127, p0 = tid >> 7;
  float v[NG];
#pragma unroll
  for (int o = 0; o < NG; ++o) v[o] = x1s[o][c];
#pragma unroll
  for (int pp = 0; pp < 6; ++pp) {
    int p = p0 * 6 + pp;
    float acc = 0.f;
#pragma unroll
    for (int o = 0; o < NG; ++o) acc += v[o] * kR[(p * NG + o) * CH + c];
    x2out[((size_t)m * NG + p) * CH + c] = acc * (1.0f / NG);
  }
}

// ---------- FALLBACK: round-4 fused edge pipeline (used if ws too small) ----------

__global__ __launch_bounds__(256) void msg_mfma_kernel(
    const float* __restrict__ x, const float* __restrict__ pos,
    const int* __restrict__ knn, const float* __restrict__ grid,
    const float* __restrict__ Bx,
    const uint4* __restrict__ w1f, const float* __restrict__ bx1,
    const uint4* __restrict__ w2f, const float* __restrict__ bx2,
    const uint4* __restrict__ wkf,
    float* __restrict__ x1out) {
  __shared__ uint4 hb[4][3][256];
  int m = blockIdx.x;
  int tid = threadIdx.x, lane = tid & 63, w = tid >> 6;
  int r = lane & 15, gq = lane >> 4;

  int src = knn[m * KNN + r];
  float rx = pos[src * 3 + 0] - pos[m * 3 + 0];
  float ry = pos[src * 3 + 1] - pos[m * 3 + 1];
  float rz = pos[src * 3 + 2] - pos[m * 3 + 2];

  bfrag ff[3][4];
#pragma unroll
  for (int t = 0; t < 3; ++t) {
    int o = w * 3 + t;
    float gx = grid[o * 3 + 0], gy = grid[o * 3 + 1], gz = grid[o * 3 + 2];
    float z = rx * gx + ry * gy + rz * gz;
    float ux = rx - z * gx, uy = ry - z * gy, uz = rz - z * gz;
    float rxy = sqrtf(ux * ux + uy * uy + uz * uz);
#pragma unroll
    for (int ks = 0; ks < 4; ++ks) {
      uint4 q;
      unsigned pk[4];
#pragma unroll
      for (int jh = 0; jh < 4; ++jh) {
        float v[2];
#pragma unroll
        for (int u = 0; u < 2; ++u) {
          int i = ks * 32 + gq * 8 + jh * 2 + u;
          int j = i & 63;
          float pv = TWO_PI_F * (rxy * Bx[j] + z * Bx[64 + j]);
          v[u] = (i < 64) ? __cosf(pv) : __sinf(pv);
        }
        pk[jh] = packbf2(v[0], v[1]);
      }
      q.x = pk[0]; q.y = pk[1]; q.z = pk[2]; q.w = pk[3];
      ff[t][ks] = __builtin_bit_cast(bfrag, q);
    }
  }

#pragma unroll 1
  for (int jt = 0; jt < 8; ++jt) {
    bfrag wf[4];
#pragma unroll
    for (int ks = 0; ks < 4; ++ks)
      wf[ks] = __builtin_bit_cast(bfrag, w1f[(jt * 4 + ks) * 64 + lane]);
    float4 bb = *(const float4*)(bx1 + jt * 16 + gq * 4);
    int cu = jt * 2 + (gq >> 1);
#pragma unroll
    for (int t = 0; t < 3; ++t) {
      f32x4 acc;
      acc[0] = bb.x; acc[1] = bb.y; acc[2] = bb.z; acc[3] = bb.w;
#pragma unroll
      for (int ks = 0; ks < 4; ++ks)
        acc = __builtin_amdgcn_mfma_f32_16x16x32_bf16(wf[ks], ff[t][ks], acc, 0, 0, 0);
      unsigned p0 = packbf2(gelu_t(acc[0]), gelu_t(acc[1]));
      unsigned p1 = packbf2(gelu_t(acc[2]), gelu_t(acc[3]));
      ((uint2*)&hb[w][t][0])[r * 32 + ((cu ^ r) << 1) + (gq & 1)] = make_uint2(p0, p1);
    }
  }
  bfrag h1f[3][4];
#pragma unroll
  for (int t = 0; t < 3; ++t)
#pragma unroll
    for (int ks = 0; ks < 4; ++ks)
      h1f[t][ks] = __builtin_bit_cast(bfrag, hb[w][t][r * 16 + ((ks * 4 + gq) ^ r)]);

#pragma unroll 1
  for (int jt = 0; jt < 8; ++jt) {
    bfrag wf[4];
#pragma unroll
    for (int ks = 0; ks < 4; ++ks)
      wf[ks] = __builtin_bit_cast(bfrag, w2f[(jt * 4 + ks) * 64 + lane]);
    float4 bb = *(const float4*)(bx2 + jt * 16 + gq * 4);
    int cu = jt * 2 + (gq >> 1);
#pragma unroll
    for (int t = 0; t < 3; ++t) {
      f32x4 acc;
      acc[0] = bb.x; acc[1] = bb.y; acc[2] = bb.z; acc[3] = bb.w;
#pragma unroll
      for (int ks = 0; ks < 4; ++ks)
        acc = __builtin_amdgcn_mfma_f32_16x16x32_bf16(wf[ks], h1f[t][ks], acc, 0, 0, 0);
      unsigned p0 = packbf2(gelu_t(acc[0]), gelu_t(acc[1]));
      unsigned p1 = packbf2(gelu_t(acc[2]), gelu_t(acc[3]));
      ((uint2*)&hb[w][t][0])[r * 32 + ((cu ^ r) << 1) + (gq & 1)] = make_uint2(p0, p1);
    }
  }
  bfrag h2f[3][4];
#pragma unroll
  for (int t = 0; t < 3; ++t)
#pragma unroll
    for (int ks = 0; ks < 4; ++ks)
      h2f[t][ks] = __builtin_bit_cast(bfrag, hb[w][t][r * 16 + ((ks * 4 + gq) ^ r)]);

#pragma unroll 1
  for (int jt = 0; jt < 8; ++jt) {
    bfrag wf[4];
#pragma unroll
    for (int ks = 0; ks < 4; ++ks)
      wf[ks] = __builtin_bit_cast(bfrag, wkf[(jt * 4 + ks) * 64 + lane]);
#pragma unroll
    for (int t = 0; t < 3; ++t) {
      int o = w * 3 + t;
      f32x4 acc;
      acc[0] = 0.f; acc[1] = 0.f; acc[2] = 0.f; acc[3] = 0.f;
#pragma unroll
      for (int ks = 0; ks < 4; ++ks)
        acc = __builtin_amdgcn_mfma_f32_16x16x32_bf16(wf[ks], h2f[t][ks], acc, 0, 0, 0);
      float4 xv = *(const float4*)(x + ((size_t)src * NG + o) * CH + jt * 16 + gq * 4);
      acc[0] *= xv.x; acc[1] *= xv.y; acc[2] *= xv.z; acc[3] *= xv.w;
#pragma unroll
      for (int st = 1; st < 16; st <<= 1) {
        acc[0] += __shfl_xor(acc[0], st, 64);
        acc[1] += __shfl_xor(acc[1], st, 64);
        acc[2] += __shfl_xor(acc[2], st, 64);
        acc[3] += __shfl_xor(acc[3], st, 64);
      }
      if (r == 0) {
        float4 sv;
        sv.x = acc[0] * (1.f / 16.f); sv.y = acc[1] * (1.f / 16.f);
        sv.z = acc[2] * (1.f / 16.f); sv.w = acc[3] * (1.f / 16.f);
        *(float4*)(x1out + ((size_t)m * NG + o) * CH + jt * 16 + gq * 4) = sv;
      }
    }
  }
}

// ---------- LN + ConvNeXt MLP via MFMA ----------

__global__ __launch_bounds__(256) void mlp_mfma_kernel(
    const float* __restrict__ xin, const float* __restrict__ x2,
    const float* __restrict__ g, const float* __restrict__ b,
    const uint4* __restrict__ w1t, const float* __restrict__ b1,
    const uint4* __restrict__ w2t, const float* __restrict__ b2,
    const float* __restrict__ s, float* __restrict__ xout) {
  __shared__ uint4 smem[1280];
  int tid = threadIdx.x;
  int rowbase = blockIdx.x * 16;

  {
    int row = tid >> 4, p = tid & 15;
    const float4* xr = (const float4*)(x2 + (size_t)(rowbase + row) * CH + p * 8);
    float4 v0 = xr[0], v1 = xr[1];
    float sum = v0.x + v0.y + v0.z + v0.w + v1.x + v1.y + v1.z + v1.w;
    sum = dpp_sum16(sum);
    float mu = sum * (1.0f / CH);
    float sq = 0.f;
    {
      float d;
      d = v0.x - mu; sq += d * d; d = v0.y - mu; sq += d * d;
      d = v0.z - mu; sq += d * d; d = v0.w - mu; sq += d * d;
      d = v1.x - mu; sq += d * d; d = v1.y - mu; sq += d * d;
      d = v1.z - mu; sq += d * d; d = v1.w - mu; sq += d * d;
    }
    sq = dpp_sum16(sq);
    float rstd = rsqrtf(sq * (1.0f / CH) + 1e-5f);
    const float4* gv = (const float4*)(g + p * 8);
    const float4* bv = (const float4*)(b + p * 8);
    float4 g0 = gv[0], g1 = gv[1], b0 = bv[0], b1v = bv[1];
    float n0 = (v0.x - mu) * rstd * g0.x + b0.x;
    float n1 = (v0.y - mu) * rstd * g0.y + b0.y;
    float n2 = (v0.z - mu) * rstd * g0.z + b0.z;
    float n3 = (v0.w - mu) * rstd * g0.w + b0.w;
    float n4 = (v1.x - mu) * rstd * g1.x + b1v.x;
    float n5 = (v1.y - mu) * rstd * g1.y + b1v.y;
    float n6 = (v1.z - mu) * rstd * g1.z + b1v.z;
    float n7 = (v1.w - mu) * rstd * g1.w + b1v.w;
    uint4 pk;
    pk.x = packbf2(n0, n1); pk.y = packbf2(n2, n3);
    pk.z = packbf2(n4, n5); pk.w = packbf2(n6, n7);
    smem[row * 16 + (p ^ row)] = pk;
  }
  __syncthreads();

  int lane = tid & 63, w = tid >> 6;
  int r = lane & 15, gq = lane >> 4;

  bfrag xf[4];
#pragma unroll
  for (int ks = 0; ks < 4; ++ks) {
    uint4 raw = smem[r * 16 + ((ks * 4 + gq) ^ r)];
    xf[ks] = __builtin_bit_cast(bfrag, raw);
  }

  uint2* hb2 = (uint2*)smem;
#pragma unroll 2
  for (int jj = 0; jj < 8; ++jj) {
    int jt = w * 8 + jj;
    f32x4 acc;
    {
      float4 bb = *(const float4*)(b1 + jt * 16 + gq * 4);
      acc[0] = bb.x; acc[1] = bb.y; acc[2] = bb.z; acc[3] = bb.w;
    }
#pragma unroll
    for (int ks = 0; ks < 4; ++ks) {
      uint4 raw = w1t[(jt * 4 + ks) * 64 + lane];
      bfrag a = __builtin_bit_cast(bfrag, raw);
      acc = __builtin_amdgcn_mfma_f32_16x16x32_bf16(a, xf[ks], acc, 0, 0, 0);
    }
    unsigned p0 = packbf2(gelu_t(acc[0]), gelu_t(acc[1]));
    unsigned p1 = packbf2(gelu_t(acc[2]), gelu_t(acc[3]));
    int sl = (jt * 2 + (gq >> 1)) ^ r;
    hb2[512 + r * 128 + sl * 2 + (gq & 1)] = make_uint2(p0, p1);
  }
  __syncthreads();

#pragma unroll 2
  for (int cc = 0; cc < 2; ++cc) {
    int ct = w * 2 + cc;
    f32x4 acc;
    {
      float4 bb = *(const float4*)(b2 + ct * 16 + gq * 4);
      acc[0] = bb.x; acc[1] = bb.y; acc[2] = bb.z; acc[3] = bb.w;
    }
#pragma unroll
    for (int ks = 0; ks < 16; ++ks) {
      uint4 hraw = smem[256 + r * 64 + ((ks * 4 + gq) ^ r)];
      bfrag hf = __builtin_bit_cast(bfrag, hraw);
      uint4 wraw = w2t[(ct * 16 + ks) * 64 + lane];
      bfrag wf = __builtin_bit_cast(bfrag, wraw);
      acc = __builtin_amdgcn_mfma_f32_16x16x32_bf16(wf, hf, acc, 0, 0, 0);
    }
    int c0 = ct * 16 + gq * 4;
    size_t ro = (size_t)(rowbase + r) * CH + c0;
    float4 xi = *(const float4*)(xin + ro);
    float4 sv = *(const float4*)(s + c0);
    float4 ov;
    ov.x = xi.x + sv.x * acc[0];
    ov.y = xi.y + sv.y * acc[1];
    ov.z = xi.z + sv.z * acc[2];
    ov.w = xi.w + sv.w * acc[3];
    *(float4*)(xout + ro) = ov;
  }
}

// ---------- launch ----------

extern "C" void kernel_launch(void* const* d_in, const int* in_sizes, int n_in,
                              void* d_out, int out_size, void* d_ws, size_t ws_size,
                              hipStream_t stream) {
  (void)in_sizes; (void)n_in; (void)out_size;
  const float* x    = (const float*)d_in[0];
  const float* pos  = (const float*)d_in[1];
  const float* grid = (const float*)d_in[2];
  const float* Bx   = (const float*)d_in[3];
  float* out = (float*)d_out;

  char* wsb = (char*)d_ws;
  int* knn   = (int*)wsb;                                   // 131072 B
  float* kR1 = (float*)(wsb + 131072);
  float* kR2 = kR1 + NG * NG * CH;
  float* x1  = kR2 + NG * NG * CH;
  float* x2  = x1 + (size_t)MTOT * NG * CH;
  unsigned short* w1ta = (unsigned short*)(x2 + (size_t)MTOT * NG * CH);
  unsigned short* w2ta = w1ta + 65536;
  unsigned short* w1tb = w2ta + 65536;
  unsigned short* w2tb = w1tb + 65536;
  unsigned short* wx1f = w2tb + 65536;     // 16384 each
  unsigned short* wx2f = wx1f + 16384;
  unsigned short* wk1f = wx2f + 16384;
  unsigned short* wk2f = wk1f + 16384;
  uint2* t2g = (uint2*)(wk2f + 16384);     // 100,663,296 B
  size_t need = (size_t)26099712 + (size_t)MTOT * NG * 4 * 64 * 16;
  bool big_ws = ws_size >= need;

  knn_kernel<<<MTOT / 4, 256, 0, stream>>>(pos, knn);
  kbr_kernel<<<NG * NG, CH, 0, stream>>>(grid, (const float*)d_in[4],
                                         (const float*)d_in[9], (const float*)d_in[10],
                                         (const float*)d_in[11], (const float*)d_in[12],
                                         (const float*)d_in[14], (const float*)d_in[23],
                                         kR1, kR2);
  pack_all_kernel<<<160, 256, 0, stream>>>(
      (const float*)d_in[17], (const float*)d_in[19],
      (const float*)d_in[26], (const float*)d_in[28],
      (const float*)d_in[5], (const float*)d_in[7],
      (const float*)d_in[13], (const float*)d_in[22],
      w1ta, w2ta, w1tb, w2tb, wx1f, wx2f, wk1f, wk2f);

  if (big_ws) {
    // layer 1 (fused edge pipeline + t2 precompute + einsum)
    kbx_fused_kernel<<<MTOT, 256, 0, stream>>>(pos, knn, grid, Bx,
        (const uint4*)wx1f, (const float*)d_in[6],
        (const uint4*)wx2f, (const float*)d_in[8],
        (const uint4*)wk1f, (const uint4*)wk2f,
        x, kR1, t2g, x2);
    mlp_mfma_kernel<<<(MTOT * NG) / 16, 256, 0, stream>>>(x, x2,
        (const float*)d_in[15], (const float*)d_in[16],
        (const uint4*)w1ta, (const float*)d_in[18],
        (const uint4*)w2ta, (const float*)d_in[20],
        (const float*)d_in[21], out);
    // layer 2 (stream t2 + gather out + einsum)
    msg3b_kernel<<<MTOT, 256, 0, stream>>>(out, knn, (const uint2*)t2g, kR2, x2);
    mlp_mfma_kernel<<<(MTOT * NG) / 16, 256, 0, stream>>>(out, x2,
        (const float*)d_in[24], (const float*)d_in[25],
        (const uint4*)w1tb, (const float*)d_in[27],
        (const uint4*)w2tb, (const float*)d_in[29],
        (const float*)d_in[30], out);
  } else {
    msg_mfma_kernel<<<MTOT, 256, 0, stream>>>(x, pos, knn, grid, Bx,
        (const uint4*)wx1f, (const float*)d_in[6],
        (const uint4*)wx2f, (const float*)d_in[8],
        (const uint4*)wk1f, x1);
    einsum_kernel<<<MTOT, CH, 0, stream>>>(x1, kR1, x2);
    mlp_mfma_kernel<<<(MTOT * NG) / 16, 256, 0, stream>>>(x, x2,
        (const float*)d_in[15], (const float*)d_in[16],
        (const uint4*)w1ta, (const float*)d_in[18],
        (const uint4*)w2ta, (const float*)d_in[20],
        (const float*)d_in[21], out);
    msg_mfma_kernel<<<MTOT, 256, 0, stream>>>(out, pos, knn, grid, Bx,
        (const uint4*)wx1f, (const float*)d_in[6],
        (const uint4*)wx2f, (const float*)d_in[8],
        (const uint4*)wk2f, x1);
    einsum_kernel<<<MTOT, CH, 0, stream>>>(x1, kR2, x2);
    mlp_mfma_kernel<<<(MTOT * NG) / 16, 256, 0, stream>>>(out, x2,
        (const float*)d_in[24], (const float*)d_in[25],
        (const uint4*)w1tb, (const float*)d_in[27],
        (const uint4*)w2tb, (const float*)d_in[29],
        (const float*)d_in[30], out);
  }
}

// Round 14
// 204.139 us; speedup vs baseline: 1.2707x; 1.0300x over previous
//
#include <hip/hip_runtime.h>
#include <hip/hip_bf16.h>
#include <math.h>

#define BG 8
#define NNODES 256
#define KNN 16
#define NG 12
#define CH 128
#define MTOT 2048
#define TWO_PI_F 6.283185307179586f

typedef __attribute__((ext_vector_type(8))) short bfrag;
typedef __attribute__((ext_vector_type(4))) float f32x4;

// ---------- helpers ----------

__device__ __forceinline__ float gelu_t(float x) {
  float x3 = x * x * x;
  float y = 0.7978845608028654f * (x + 0.044715f * x3);
  float e = __expf(2.0f * y);
  float th = 1.0f - 2.0f / (e + 1.0f);
  return 0.5f * x * (1.0f + th);
}

__device__ __forceinline__ unsigned packbf2(float a, float b) {
  unsigned ua = __float_as_uint(a), ub = __float_as_uint(b);
  ua = (ua + 0x7fffu + ((ua >> 16) & 1u)) >> 16;    // RNE to bf16
  ub = (ub + 0x7fffu + ((ub >> 16) & 1u)) >> 16;
  return ua | (ub << 16);
}
__device__ __forceinline__ unsigned short f2bf(float f) {
  unsigned u = __float_as_uint(f);
  u = (u + 0x7fffu + ((u >> 16) & 1u)) >> 16;
  return (unsigned short)u;
}
__device__ __forceinline__ float ubf_lo(unsigned p) { return __uint_as_float(p << 16); }
__device__ __forceinline__ float ubf_hi(unsigned p) { return __uint_as_float(p & 0xffff0000u); }

// gelu via sigmoid form; exp2-domain, ~7 insts
__device__ __forceinline__ float gelu_s(float x) {
  const float A  = -2.0f * 0.7978845608028654f * 1.4426950408889634f;
  const float CA = A * 0.044715f;
  float x2 = x * x;
  float q  = __builtin_fmaf(CA, x2, A);
  float t  = x * q;
  float e; asm("v_exp_f32 %0, %1" : "=v"(e) : "v"(t));     // 2^t
  float d = 1.0f + e;
  float r; asm("v_rcp_f32 %0, %1" : "=v"(r) : "v"(d));
  return x * r;
}

__device__ __forceinline__ unsigned pkcvt(float a, float b) {
  unsigned r;
  asm("v_cvt_pk_bf16_f32 %0, %1, %2" : "=v"(r) : "v"(a), "v"(b));
  return r;
}

__device__ __forceinline__ void cossin(float w, float& c, float& s) {
  float f; asm("v_fract_f32 %0, %1" : "=v"(f) : "v"(w));
  asm("v_cos_f32 %0, %1" : "=v"(c) : "v"(f));
  asm("v_sin_f32 %0, %1" : "=v"(s) : "v"(f));
}

// 16-lane row sum via DPP rotate-adds: 4 VALU insts, no LDS/bpermute path.
__device__ __forceinline__ float dpp_sum16(float x) {
  asm("v_add_f32 %0, %0, %0 row_ror:8 row_mask:0xf bank_mask:0xf" : "+v"(x));
  asm("v_add_f32 %0, %0, %0 row_ror:4 row_mask:0xf bank_mask:0xf" : "+v"(x));
  asm("v_add_f32 %0, %0, %0 row_ror:2 row_mask:0xf bank_mask:0xf" : "+v"(x));
  asm("v_add_f32 %0, %0, %0 row_ror:1 row_mask:0xf bank_mask:0xf" : "+v"(x));
  return x;
}

__device__ __forceinline__ unsigned long long shfl_xor64(unsigned long long v, int st) {
  unsigned lo = (unsigned)v, hi = (unsigned)(v >> 32);
  lo = __shfl_xor(lo, st, 64);
  hi = __shfl_xor(hi, st, 64);
  return ((unsigned long long)hi << 32) | lo;
}

// ---------- kNN: one wave per node ----------

__global__ __launch_bounds__(256) void knn_kernel(const float* __restrict__ pos,
                                                  int* __restrict__ knn) {
  __shared__ float sx[NNODES], sy[NNODES], sz[NNODES];
  int w = threadIdx.x >> 6, lane = threadIdx.x & 63;
  int node = blockIdx.x * 4 + w;
  int b = node >> 8;
  int gbase = b * NNODES;
  int t = threadIdx.x;
  sx[t] = pos[(gbase + t) * 3 + 0];
  sy[t] = pos[(gbase + t) * 3 + 1];
  sz[t] = pos[(gbase + t) * 3 + 2];
  __syncthreads();
  int i = node & 255;
  float xi = sx[i], yi = sy[i], zi = sz[i];
  unsigned long long key[4];
#pragma unroll
  for (int u = 0; u < 4; ++u) {
    int j = lane * 4 + u;
    float dx = xi - sx[j], dy = yi - sy[j], dz = zi - sz[j];
    float d = dx * dx + dy * dy + dz * dz;
    key[u] = ((unsigned long long)__float_as_uint(d) << 32) | (unsigned)j;
  }
  {
    unsigned long long tmp;
#define CSWAP(a, bq) if (key[bq] < key[a]) { tmp = key[a]; key[a] = key[bq]; key[bq] = tmp; }
    CSWAP(0, 1) CSWAP(2, 3) CSWAP(0, 2) CSWAP(1, 3) CSWAP(1, 2)
#undef CSWAP
  }
  int ptr = 0;
#pragma unroll 1
  for (int r = 0; r < KNN; ++r) {
    unsigned long long cand = (ptr < 4) ? key[ptr] : ~0ULL;
    unsigned long long mn = cand;
#pragma unroll
    for (int st = 1; st < 64; st <<= 1) {
      unsigned long long o = shfl_xor64(mn, st);
      if (o < mn) mn = o;
    }
    if (cand == mn) ptr++;
    if (lane == 0) knn[node * KNN + r] = gbase + (int)(mn & 0xffffffffu);
  }
}

// ---------- kb_R -> kR ----------

__global__ void kbr_kernel(const float* __restrict__ grid, const float* __restrict__ BR,
                           const float* __restrict__ WR1, const float* __restrict__ bR1,
                           const float* __restrict__ WR2, const float* __restrict__ bR2,
                           const float* __restrict__ WkR1, const float* __restrict__ WkR2,
                           float* __restrict__ kR1, float* __restrict__ kR2) {
  int r = blockIdx.x;
  int p = r / NG, o = r % NG;
  int c = threadIdx.x;
  float a = grid[p * 3 + 0] * grid[o * 3 + 0] + grid[p * 3 + 1] * grid[o * 3 + 1] +
            grid[p * 3 + 2] * grid[o * 3 + 2];
  __shared__ float fb[CH], hh[CH];
  {
    int j = c & 63;
    float pv = TWO_PI_F * (a * BR[j]);
    fb[c] = (c < 64) ? cosf(pv) : sinf(pv);
  }
  __syncthreads();
  float acc = bR1[c];
  for (int i = 0; i < CH; ++i) acc += fb[i] * WR1[i * CH + c];
  float h1 = gelu_t(acc);
  __syncthreads();
  hh[c] = h1;
  __syncthreads();
  acc = bR2[c];
  for (int i = 0; i < CH; ++i) acc += hh[i] * WR2[i * CH + c];
  float h2 = gelu_t(acc);
  __syncthreads();
  fb[c] = h2;
  __syncthreads();
  float t1 = 0.f, t2 = 0.f;
  for (int i = 0; i < CH; ++i) {
    float v = fb[i];
    t1 += v * WkR1[i * CH + c];
    t2 += v * WkR2[i * CH + c];
  }
  kR1[r * CH + c] = t1;
  kR2[r * CH + c] = t2;
}

// ---------- fiber einsum (fallback path only) ----------

__global__ void einsum_kernel(const float* __restrict__ x1, const float* __restrict__ kR,
                              float* __restrict__ x2) {
  int m = blockIdx.x, c = threadIdx.x;
  float v[NG];
#pragma unroll
  for (int o = 0; o < NG; ++o) v[o] = x1[((size_t)m * NG + o) * CH + c];
#pragma unroll
  for (int p = 0; p < NG; ++p) {
    float acc = 0.f;
#pragma unroll
    for (int o = 0; o < NG; ++o) acc += v[o] * kR[(p * NG + o) * CH + c];
    x2[((size_t)m * NG + p) * CH + c] = acc * (1.0f / NG);
  }
}

// ---------- weight fragment packing (all 8 matrices, one launch) ----------

__device__ __forceinline__ void pack_body(const float* __restrict__ W, int K, int N,
                                          unsigned short* __restrict__ out, int tid) {
  int lane = tid & 63;
  int t = tid >> 6;
  int ksteps = K / 32;
  int ks = t % ksteps, tile = t / ksteps;
  int col = tile * 16 + (lane & 15);
  int k0 = ks * 32 + (lane >> 4) * 8;
#pragma unroll
  for (int j = 0; j < 8; ++j)
    out[(size_t)tid * 8 + j] = f2bf(W[(size_t)(k0 + j) * N + col]);
}

__global__ __launch_bounds__(256) void pack_all_kernel(
    const float* __restrict__ W1a, const float* __restrict__ W2a,
    const float* __restrict__ W1b, const float* __restrict__ W2b,
    const float* __restrict__ wx1, const float* __restrict__ wx2,
    const float* __restrict__ wk1, const float* __restrict__ wk2,
    unsigned short* __restrict__ o1a, unsigned short* __restrict__ o2a,
    unsigned short* __restrict__ o1b, unsigned short* __restrict__ o2b,
    unsigned short* __restrict__ ox1, unsigned short* __restrict__ ox2,
    unsigned short* __restrict__ ok1, unsigned short* __restrict__ ok2) {
  int blk = blockIdx.x;
  if (blk < 32)        pack_body(W1a, CH, 4 * CH, o1a, blk * 256 + threadIdx.x);
  else if (blk < 64)   pack_body(W2a, 4 * CH, CH, o2a, (blk - 32) * 256 + threadIdx.x);
  else if (blk < 96)   pack_body(W1b, CH, 4 * CH, o1b, (blk - 64) * 256 + threadIdx.x);
  else if (blk < 128)  pack_body(W2b, 4 * CH, CH, o2b, (blk - 96) * 256 + threadIdx.x);
  else if (blk < 136)  pack_body(wx1, CH, CH, ox1, (blk - 128) * 256 + threadIdx.x);
  else if (blk < 144)  pack_body(wx2, CH, CH, ox2, (blk - 136) * 256 + threadIdx.x);
  else if (blk < 152)  pack_body(wk1, CH, CH, ok1, (blk - 144) * 256 + threadIdx.x);
  else                 pack_body(wk2, CH, CH, ok2, (blk - 152) * 256 + threadIdx.x);
}

// ---------- fused layer-1 edge pipeline + t2 precompute (unchanged from r13) ----------

__global__ __launch_bounds__(256) void kbx_fused_kernel(
    const float* __restrict__ pos, const int* __restrict__ knn,
    const float* __restrict__ grid, const float* __restrict__ Bx,
    const uint4* __restrict__ w1f, const float* __restrict__ bx1,
    const uint4* __restrict__ w2f, const float* __restrict__ bx2,
    const uint4* __restrict__ wk1f, const uint4* __restrict__ wk2f,
    const float* __restrict__ x, const float* __restrict__ kR,
    uint2* __restrict__ t2g, float* __restrict__ x2out) {
  __shared__ uint4 hb[4][3][128];          // 24 KB half-tile transpose buffers
  float* x1s = (float*)hb;                 // aliased AFTER barrier (6 KB)
  int m = blockIdx.x;
  int tid = threadIdx.x, lane = tid & 63, w = tid >> 6;
  int r = lane & 15, gq = lane >> 4;

  int src = knn[m * KNN + r];
  float rx = pos[src * 3 + 0] - pos[m * 3 + 0];
  float ry = pos[src * 3 + 1] - pos[m * 3 + 1];
  float rz = pos[src * 3 + 2] - pos[m * 3 + 2];

  float4 brA0 = *(const float4*)(Bx + gq * 8);
  float4 brA1 = *(const float4*)(Bx + gq * 8 + 4);
  float4 brB0 = *(const float4*)(Bx + 32 + gq * 8);
  float4 brB1 = *(const float4*)(Bx + 32 + gq * 8 + 4);
  float4 bzA0 = *(const float4*)(Bx + 64 + gq * 8);
  float4 bzA1 = *(const float4*)(Bx + 64 + gq * 8 + 4);
  float4 bzB0 = *(const float4*)(Bx + 96 + gq * 8);
  float4 bzB1 = *(const float4*)(Bx + 96 + gq * 8 + 4);
  float brA[8] = {brA0.x, brA0.y, brA0.z, brA0.w, brA1.x, brA1.y, brA1.z, brA1.w};
  float brB[8] = {brB0.x, brB0.y, brB0.z, brB0.w, brB1.x, brB1.y, brB1.z, brB1.w};
  float bzA[8] = {bzA0.x, bzA0.y, bzA0.z, bzA0.w, bzA1.x, bzA1.y, bzA1.z, bzA1.w};
  float bzB[8] = {bzB0.x, bzB0.y, bzB0.z, bzB0.w, bzB1.x, bzB1.y, bzB1.z, bzB1.w};

  // ---- RFF features as B-fragments for all 3 tiles
  bfrag ff[3][4];
#pragma unroll
  for (int t = 0; t < 3; ++t) {
    int o = w * 3 + t;
    float gx = grid[o * 3 + 0], gy = grid[o * 3 + 1], gz = grid[o * 3 + 2];
    float z = rx * gx + ry * gy + rz * gz;
    float ux = rx - z * gx, uy = ry - z * gy, uz = rz - z * gz;
    float rxy = sqrtf(ux * ux + uy * uy + uz * uz);
    float cA[8], sA[8], cB[8], sB[8];
#pragma unroll
    for (int u = 0; u < 8; ++u) {
      float wA = __builtin_fmaf(z, bzA[u], rxy * brA[u]);
      float wB = __builtin_fmaf(z, bzB[u], rxy * brB[u]);
      cossin(wA, cA[u], sA[u]);
      cossin(wB, cB[u], sB[u]);
    }
    uint4 q;
    q.x = pkcvt(cA[0], cA[1]); q.y = pkcvt(cA[2], cA[3]);
    q.z = pkcvt(cA[4], cA[5]); q.w = pkcvt(cA[6], cA[7]);
    ff[t][0] = __builtin_bit_cast(bfrag, q);
    q.x = pkcvt(cB[0], cB[1]); q.y = pkcvt(cB[2], cB[3]);
    q.z = pkcvt(cB[4], cB[5]); q.w = pkcvt(cB[6], cB[7]);
    ff[t][1] = __builtin_bit_cast(bfrag, q);
    q.x = pkcvt(sA[0], sA[1]); q.y = pkcvt(sA[2], sA[3]);
    q.z = pkcvt(sA[4], sA[5]); q.w = pkcvt(sA[6], sA[7]);
    ff[t][2] = __builtin_bit_cast(bfrag, q);
    q.x = pkcvt(sB[0], sB[1]); q.y = pkcvt(sB[2], sB[3]);
    q.z = pkcvt(sB[4], sB[5]); q.w = pkcvt(sB[6], sB[7]);
    ff[t][3] = __builtin_bit_cast(bfrag, q);
  }

  // ---- GEMM1: h1 = gelu(f @ Wx1 + bx1), half-phase LDS transpose
  bfrag h1f[3][4];
#pragma unroll
  for (int h = 0; h < 2; ++h) {           // fully unrolled (rule #20)
#pragma unroll 2
    for (int jl = 0; jl < 4; ++jl) {
      int jt = h * 4 + jl;
      bfrag wf[4];
#pragma unroll
      for (int ks = 0; ks < 4; ++ks)
        wf[ks] = __builtin_bit_cast(bfrag, w1f[(jt * 4 + ks) * 64 + lane]);
      float4 bb = *(const float4*)(bx1 + jt * 16 + gq * 4);
      int cu = jl * 2 + (gq >> 1);         // 0..7 within half
#pragma unroll
      for (int t = 0; t < 3; ++t) {
        f32x4 acc;
        acc[0] = bb.x; acc[1] = bb.y; acc[2] = bb.z; acc[3] = bb.w;
#pragma unroll
        for (int ks = 0; ks < 4; ++ks)
          acc = __builtin_amdgcn_mfma_f32_16x16x32_bf16(wf[ks], ff[t][ks], acc, 0, 0, 0);
        unsigned p0 = pkcvt(gelu_s(acc[0]), gelu_s(acc[1]));
        unsigned p1 = pkcvt(gelu_s(acc[2]), gelu_s(acc[3]));
        ((uint2*)&hb[w][t][0])[r * 16 + ((cu ^ (r & 7)) << 1) + (gq & 1)] =
            make_uint2(p0, p1);
      }
    }
#pragma unroll
    for (int t = 0; t < 3; ++t)
#pragma unroll
      for (int ksl = 0; ksl < 2; ++ksl)
        h1f[t][h * 2 + ksl] = __builtin_bit_cast(bfrag,
            hb[w][t][r * 8 + ((ksl * 4 + gq) ^ (r & 7))]);
  }

  // ---- GEMM2: h2 = gelu(h1 @ Wx2 + bx2), half-phase LDS transpose
  bfrag h2f[3][4];
#pragma unroll
  for (int h = 0; h < 2; ++h) {
#pragma unroll 2
    for (int jl = 0; jl < 4; ++jl) {
      int jt = h * 4 + jl;
      bfrag wf[4];
#pragma unroll
      for (int ks = 0; ks < 4; ++ks)
        wf[ks] = __builtin_bit_cast(bfrag, w2f[(jt * 4 + ks) * 64 + lane]);
      float4 bb = *(const float4*)(bx2 + jt * 16 + gq * 4);
      int cu = jl * 2 + (gq >> 1);
#pragma unroll
      for (int t = 0; t < 3; ++t) {
        f32x4 acc;
        acc[0] = bb.x; acc[1] = bb.y; acc[2] = bb.z; acc[3] = bb.w;
#pragma unroll
        for (int ks = 0; ks < 4; ++ks)
          acc = __builtin_amdgcn_mfma_f32_16x16x32_bf16(wf[ks], h1f[t][ks], acc, 0, 0, 0);
        unsigned p0 = pkcvt(gelu_s(acc[0]), gelu_s(acc[1]));
        unsigned p1 = pkcvt(gelu_s(acc[2]), gelu_s(acc[3]));
        ((uint2*)&hb[w][t][0])[r * 16 + ((cu ^ (r & 7)) << 1) + (gq & 1)] =
            make_uint2(p0, p1);
      }
    }
#pragma unroll
    for (int t = 0; t < 3; ++t)
#pragma unroll
      for (int ksl = 0; ksl < 2; ++ksl)
        h2f[t][h * 2 + ksl] = __builtin_bit_cast(bfrag,
            hb[w][t][r * 8 + ((ksl * 4 + gq) ^ (r & 7))]);
  }

  __syncthreads();   // all transpose reads done -> x1s may alias hb

  // ---- merged GEMM3a+3b with DPP reductions
#pragma unroll 2
  for (int jt = 0; jt < 8; ++jt) {
    bfrag wfa[4], wfb[4];
#pragma unroll
    for (int ks = 0; ks < 4; ++ks) {
      wfa[ks] = __builtin_bit_cast(bfrag, wk1f[(jt * 4 + ks) * 64 + lane]);
      wfb[ks] = __builtin_bit_cast(bfrag, wk2f[(jt * 4 + ks) * 64 + lane]);
    }
#pragma unroll
    for (int t = 0; t < 3; ++t) {
      int o = w * 3 + t;
      int tile = m * NG + o;
      float4 xv = *(const float4*)(x + ((size_t)src * NG + o) * CH + jt * 16 + gq * 4);
      f32x4 acc1, acc2;
      acc1[0] = 0.f; acc1[1] = 0.f; acc1[2] = 0.f; acc1[3] = 0.f;
      acc2[0] = 0.f; acc2[1] = 0.f; acc2[2] = 0.f; acc2[3] = 0.f;
#pragma unroll
      for (int ks = 0; ks < 4; ++ks) {
        acc1 = __builtin_amdgcn_mfma_f32_16x16x32_bf16(wfa[ks], h2f[t][ks], acc1, 0, 0, 0);
        acc2 = __builtin_amdgcn_mfma_f32_16x16x32_bf16(wfb[ks], h2f[t][ks], acc2, 0, 0, 0);
      }
      uint2 pv;
      pv.x = pkcvt(acc2[0], acc2[1]);
      pv.y = pkcvt(acc2[2], acc2[3]);
      t2g[((size_t)tile * 8 + jt) * 64 + lane] = pv;
      float s0 = dpp_sum16(acc1[0] * xv.x);
      float s1 = dpp_sum16(acc1[1] * xv.y);
      float s2 = dpp_sum16(acc1[2] * xv.z);
      float s3 = dpp_sum16(acc1[3] * xv.w);
      if (r == 0) {
        int c0 = jt * 16 + gq * 4;
        float4 sv;
        sv.x = s0 * (1.f / 16.f); sv.y = s1 * (1.f / 16.f);
        sv.z = s2 * (1.f / 16.f); sv.w = s3 * (1.f / 16.f);
        *(float4*)&x1s[o * CH + c0] = sv;
      }
    }
  }
  __syncthreads();

  // ---- fused fiber einsum
  int c = tid & 127, p0 = tid >> 7;
  float v[NG];
#pragma unroll
  for (int o = 0; o < NG; ++o) v[o] = x1s[o * CH + c];
#pragma unroll
  for (int pp = 0; pp < 6; ++pp) {
    int p = p0 * 6 + pp;
    float acc = 0.f;
#pragma unroll
    for (int o = 0; o < NG; ++o) acc += v[o] * kR[(p * NG + o) * CH + c];
    x2out[((size_t)m * NG + p) * CH + c] = acc * (1.0f / NG);
  }
}

// ---------- layer-2: stream t2, gather out, k-mean (DPP), fused einsum ----------

__global__ __launch_bounds__(256) void msg3b_kernel(
    const float* __restrict__ x, const int* __restrict__ knn,
    const uint2* __restrict__ t2g, const float* __restrict__ kR,
    float* __restrict__ x2out) {
  __shared__ float x1s[NG][CH];   // 6 KB
  int m = blockIdx.x;
  int tid = threadIdx.x, lane = tid & 63, w = tid >> 6;
  int r = lane & 15, gq = lane >> 4;
  int src = knn[m * KNN + r];

#pragma unroll 1
  for (int jt = 0; jt < 8; ++jt) {
#pragma unroll
    for (int t = 0; t < 3; ++t) {
      int o = w * 3 + t;
      int tile = m * NG + o;
      uint2 tv = t2g[((size_t)tile * 8 + jt) * 64 + lane];
      float4 xv = *(const float4*)(x + ((size_t)src * NG + o) * CH + jt * 16 + gq * 4);
      float a0 = dpp_sum16(ubf_lo(tv.x) * xv.x);
      float a1 = dpp_sum16(ubf_hi(tv.x) * xv.y);
      float a2 = dpp_sum16(ubf_lo(tv.y) * xv.z);
      float a3 = dpp_sum16(ubf_hi(tv.y) * xv.w);
      if (r == 0) {
        int c0 = jt * 16 + gq * 4;
        x1s[o][c0 + 0] = a0 * (1.f / 16.f);
        x1s[o][c0 + 1] = a1 * (1.f / 16.f);
        x1s[o][c0 + 2] = a2 * (1.f / 16.f);
        x1s[o][c0 + 3] = a3 * (1.f / 16.f);
      }
    }
  }
  __syncthreads();

  int c = tid & 127, p0 = tid >> 7;
  float v[NG];
#pragma unroll
  for (int o = 0; o < NG; ++o) v[o] = x1s[o][c];
#pragma unroll
  for (int pp = 0; pp < 6; ++pp) {
    int p = p0 * 6 + pp;
    float acc = 0.f;
#pragma unroll
    for (int o = 0; o < NG; ++o) acc += v[o] * kR[(p * NG + o) * CH + c];
    x2out[((size_t)m * NG + p) * CH + c] = acc * (1.0f / NG);
  }
}

// ---------- FALLBACK: round-4 fused edge pipeline (used if ws too small) ----------

__global__ __launch_bounds__(256) void msg_mfma_kernel(
    const float* __restrict__ x, const float* __restrict__ pos,
    const int* __restrict__ knn, const float* __restrict__ grid,
    const float* __restrict__ Bx,
    const uint4* __restrict__ w1f, const float* __restrict__ bx1,
    const uint4* __restrict__ w2f, const float* __restrict__ bx2,
    const uint4* __restrict__ wkf,
    float* __restrict__ x1out) {
  __shared__ uint4 hb[4][3][256];
  int m = blockIdx.x;
  int tid = threadIdx.x, lane = tid & 63, w = tid >> 6;
  int r = lane & 15, gq = lane >> 4;

  int src = knn[m * KNN + r];
  float rx = pos[src * 3 + 0] - pos[m * 3 + 0];
  float ry = pos[src * 3 + 1] - pos[m * 3 + 1];
  float rz = pos[src * 3 + 2] - pos[m * 3 + 2];

  bfrag ff[3][4];
#pragma unroll
  for (int t = 0; t < 3; ++t) {
    int o = w * 3 + t;
    float gx = grid[o * 3 + 0], gy = grid[o * 3 + 1], gz = grid[o * 3 + 2];
    float z = rx * gx + ry * gy + rz * gz;
    float ux = rx - z * gx, uy = ry - z * gy, uz = rz - z * gz;
    float rxy = sqrtf(ux * ux + uy * uy + uz * uz);
#pragma unroll
    for (int ks = 0; ks < 4; ++ks) {
      uint4 q;
      unsigned pk[4];
#pragma unroll
      for (int jh = 0; jh < 4; ++jh) {
        float v[2];
#pragma unroll
        for (int u = 0; u < 2; ++u) {
          int i = ks * 32 + gq * 8 + jh * 2 + u;
          int j = i & 63;
          float pv = TWO_PI_F * (rxy * Bx[j] + z * Bx[64 + j]);
          v[u] = (i < 64) ? __cosf(pv) : __sinf(pv);
        }
        pk[jh] = packbf2(v[0], v[1]);
      }
      q.x = pk[0]; q.y = pk[1]; q.z = pk[2]; q.w = pk[3];
      ff[t][ks] = __builtin_bit_cast(bfrag, q);
    }
  }

#pragma unroll 1
  for (int jt = 0; jt < 8; ++jt) {
    bfrag wf[4];
#pragma unroll
    for (int ks = 0; ks < 4; ++ks)
      wf[ks] = __builtin_bit_cast(bfrag, w1f[(jt * 4 + ks) * 64 + lane]);
    float4 bb = *(const float4*)(bx1 + jt * 16 + gq * 4);
    int cu = jt * 2 + (gq >> 1);
#pragma unroll
    for (int t = 0; t < 3; ++t) {
      f32x4 acc;
      acc[0] = bb.x; acc[1] = bb.y; acc[2] = bb.z; acc[3] = bb.w;
#pragma unroll
      for (int ks = 0; ks < 4; ++ks)
        acc = __builtin_amdgcn_mfma_f32_16x16x32_bf16(wf[ks], ff[t][ks], acc, 0, 0, 0);
      unsigned p0 = packbf2(gelu_t(acc[0]), gelu_t(acc[1]));
      unsigned p1 = packbf2(gelu_t(acc[2]), gelu_t(acc[3]));
      ((uint2*)&hb[w][t][0])[r * 32 + ((cu ^ r) << 1) + (gq & 1)] = make_uint2(p0, p1);
    }
  }
  bfrag h1f[3][4];
#pragma unroll
  for (int t = 0; t < 3; ++t)
#pragma unroll
    for (int ks = 0; ks < 4; ++ks)
      h1f[t][ks] = __builtin_bit_cast(bfrag, hb[w][t][r * 16 + ((ks * 4 + gq) ^ r)]);

#pragma unroll 1
  for (int jt = 0; jt < 8; ++jt) {
    bfrag wf[4];
#pragma unroll
    for (int ks = 0; ks < 4; ++ks)
      wf[ks] = __builtin_bit_cast(bfrag, w2f[(jt * 4 + ks) * 64 + lane]);
    float4 bb = *(const float4*)(bx2 + jt * 16 + gq * 4);
    int cu = jt * 2 + (gq >> 1);
#pragma unroll
    for (int t = 0; t < 3; ++t) {
      f32x4 acc;
      acc[0] = bb.x; acc[1] = bb.y; acc[2] = bb.z; acc[3] = bb.w;
#pragma unroll
      for (int ks = 0; ks < 4; ++ks)
        acc = __builtin_amdgcn_mfma_f32_16x16x32_bf16(wf[ks], h1f[t][ks], acc, 0, 0, 0);
      unsigned p0 = packbf2(gelu_t(acc[0]), gelu_t(acc[1]));
      unsigned p1 = packbf2(gelu_t(acc[2]), gelu_t(acc[3]));
      ((uint2*)&hb[w][t][0])[r * 32 + ((cu ^ r) << 1) + (gq & 1)] = make_uint2(p0, p1);
    }
  }
  bfrag h2f[3][4];
#pragma unroll
  for (int t = 0; t < 3; ++t)
#pragma unroll
    for (int ks = 0; ks < 4; ++ks)
      h2f[t][ks] = __builtin_bit_cast(bfrag, hb[w][t][r * 16 + ((ks * 4 + gq) ^ r)]);

#pragma unroll 1
  for (int jt = 0; jt < 8; ++jt) {
    bfrag wf[4];
#pragma unroll
    for (int ks = 0; ks < 4; ++ks)
      wf[ks] = __builtin_bit_cast(bfrag, wkf[(jt * 4 + ks) * 64 + lane]);
#pragma unroll
    for (int t = 0; t < 3; ++t) {
      int o = w * 3 + t;
      f32x4 acc;
      acc[0] = 0.f; acc[1] = 0.f; acc[2] = 0.f; acc[3] = 0.f;
#pragma unroll
      for (int ks = 0; ks < 4; ++ks)
        acc = __builtin_amdgcn_mfma_f32_16x16x32_bf16(wf[ks], h2f[t][ks], acc, 0, 0, 0);
      float4 xv = *(const float4*)(x + ((size_t)src * NG + o) * CH + jt * 16 + gq * 4);
      acc[0] *= xv.x; acc[1] *= xv.y; acc[2] *= xv.z; acc[3] *= xv.w;
#pragma unroll
      for (int st = 1; st < 16; st <<= 1) {
        acc[0] += __shfl_xor(acc[0], st, 64);
        acc[1] += __shfl_xor(acc[1], st, 64);
        acc[2] += __shfl_xor(acc[2], st, 64);
        acc[3] += __shfl_xor(acc[3], st, 64);
      }
      if (r == 0) {
        float4 sv;
        sv.x = acc[0] * (1.f / 16.f); sv.y = acc[1] * (1.f / 16.f);
        sv.z = acc[2] * (1.f / 16.f); sv.w = acc[3] * (1.f / 16.f);
        *(float4*)(x1out + ((size_t)m * NG + o) * CH + jt * 16 + gq * 4) = sv;
      }
    }
  }
}

// ---------- LN + ConvNeXt MLP via MFMA, 32 rows/block ----------
// Each weight fragment load now feeds 2 MFMAs (two 16-row groups).
// LDS: [0,512) uint4 = xn 32x128 bf16; [512,2560) = h 32x512 bf16 (40 KB).

__global__ __launch_bounds__(256) void mlp_mfma_kernel(
    const float* __restrict__ xin, const float* __restrict__ x2,
    const float* __restrict__ g, const float* __restrict__ b,
    const uint4* __restrict__ w1t, const float* __restrict__ b1,
    const uint4* __restrict__ w2t, const float* __restrict__ b2,
    const float* __restrict__ s, float* __restrict__ xout) {
  __shared__ uint4 smem[2560];
  int tid = threadIdx.x;
  int rowbase = blockIdx.x * 32;

  // ---- LN: thread handles rows (tid>>4) and (tid>>4)+16
#pragma unroll
  for (int rg = 0; rg < 2; ++rg) {
    int row = (tid >> 4) + rg * 16, p = tid & 15;
    const float4* xr = (const float4*)(x2 + (size_t)(rowbase + row) * CH + p * 8);
    float4 v0 = xr[0], v1 = xr[1];
    float sum = v0.x + v0.y + v0.z + v0.w + v1.x + v1.y + v1.z + v1.w;
    sum = dpp_sum16(sum);
    float mu = sum * (1.0f / CH);
    float sq = 0.f;
    {
      float d;
      d = v0.x - mu; sq += d * d; d = v0.y - mu; sq += d * d;
      d = v0.z - mu; sq += d * d; d = v0.w - mu; sq += d * d;
      d = v1.x - mu; sq += d * d; d = v1.y - mu; sq += d * d;
      d = v1.z - mu; sq += d * d; d = v1.w - mu; sq += d * d;
    }
    sq = dpp_sum16(sq);
    float rstd = rsqrtf(sq * (1.0f / CH) + 1e-5f);
    const float4* gv = (const float4*)(g + p * 8);
    const float4* bv = (const float4*)(b + p * 8);
    float4 g0 = gv[0], g1 = gv[1], b0 = bv[0], b1v = bv[1];
    float n0 = (v0.x - mu) * rstd * g0.x + b0.x;
    float n1 = (v0.y - mu) * rstd * g0.y + b0.y;
    float n2 = (v0.z - mu) * rstd * g0.z + b0.z;
    float n3 = (v0.w - mu) * rstd * g0.w + b0.w;
    float n4 = (v1.x - mu) * rstd * g1.x + b1v.x;
    float n5 = (v1.y - mu) * rstd * g1.y + b1v.y;
    float n6 = (v1.z - mu) * rstd * g1.z + b1v.z;
    float n7 = (v1.w - mu) * rstd * g1.w + b1v.w;
    uint4 pk;
    pk.x = pkcvt(n0, n1); pk.y = pkcvt(n2, n3);
    pk.z = pkcvt(n4, n5); pk.w = pkcvt(n6, n7);
    smem[row * 16 + (p ^ (row & 15))] = pk;
  }
  __syncthreads();

  int lane = tid & 63, w = tid >> 6;
  int r = lane & 15, gq = lane >> 4;

  bfrag xf[2][4];
#pragma unroll
  for (int rg = 0; rg < 2; ++rg)
#pragma unroll
    for (int ks = 0; ks < 4; ++ks)
      xf[rg][ks] = __builtin_bit_cast(bfrag,
          smem[(rg * 16 + r) * 16 + ((ks * 4 + gq) ^ r)]);

  uint2* hb2 = (uint2*)smem;
#pragma unroll 2
  for (int jj = 0; jj < 8; ++jj) {
    int jt = w * 8 + jj;
    bfrag a[4];
#pragma unroll
    for (int ks = 0; ks < 4; ++ks)
      a[ks] = __builtin_bit_cast(bfrag, w1t[(jt * 4 + ks) * 64 + lane]);
    float4 bb = *(const float4*)(b1 + jt * 16 + gq * 4);
    int sl = jt * 2 + (gq >> 1);
#pragma unroll
    for (int rg = 0; rg < 2; ++rg) {
      f32x4 acc;
      acc[0] = bb.x; acc[1] = bb.y; acc[2] = bb.z; acc[3] = bb.w;
#pragma unroll
      for (int ks = 0; ks < 4; ++ks)
        acc = __builtin_amdgcn_mfma_f32_16x16x32_bf16(a[ks], xf[rg][ks], acc, 0, 0, 0);
      unsigned p0 = pkcvt(gelu_s(acc[0]), gelu_s(acc[1]));
      unsigned p1 = pkcvt(gelu_s(acc[2]), gelu_s(acc[3]));
      int row = rg * 16 + r;
      hb2[1024 + row * 128 + ((sl ^ r) << 1) + (gq & 1)] = make_uint2(p0, p1);
    }
  }
  __syncthreads();

#pragma unroll 2
  for (int cc = 0; cc < 2; ++cc) {
    int ct = w * 2 + cc;
    float4 bb = *(const float4*)(b2 + ct * 16 + gq * 4);
    f32x4 acc0, acc1;
    acc0[0] = bb.x; acc0[1] = bb.y; acc0[2] = bb.z; acc0[3] = bb.w;
    acc1[0] = bb.x; acc1[1] = bb.y; acc1[2] = bb.z; acc1[3] = bb.w;
#pragma unroll
    for (int ks = 0; ks < 16; ++ks) {
      bfrag wf = __builtin_bit_cast(bfrag, w2t[(ct * 16 + ks) * 64 + lane]);
      bfrag h0 = __builtin_bit_cast(bfrag,
          smem[512 + r * 64 + ((ks * 4 + gq) ^ r)]);
      bfrag h1v = __builtin_bit_cast(bfrag,
          smem[512 + (16 + r) * 64 + ((ks * 4 + gq) ^ r)]);
      acc0 = __builtin_amdgcn_mfma_f32_16x16x32_bf16(wf, h0, acc0, 0, 0, 0);
      acc1 = __builtin_amdgcn_mfma_f32_16x16x32_bf16(wf, h1v, acc1, 0, 0, 0);
    }
    int c0 = ct * 16 + gq * 4;
    float4 sv = *(const float4*)(s + c0);
#pragma unroll
    for (int rg = 0; rg < 2; ++rg) {
      size_t ro = (size_t)(rowbase + rg * 16 + r) * CH + c0;
      float4 xi = *(const float4*)(xin + ro);
      float4 ov;
      float a0 = (rg == 0) ? acc0[0] : acc1[0];
      float a1 = (rg == 0) ? acc0[1] : acc1[1];
      float a2 = (rg == 0) ? acc0[2] : acc1[2];
      float a3 = (rg == 0) ? acc0[3] : acc1[3];
      ov.x = xi.x + sv.x * a0;
      ov.y = xi.y + sv.y * a1;
      ov.z = xi.z + sv.z * a2;
      ov.w = xi.w + sv.w * a3;
      *(float4*)(xout + ro) = ov;
    }
  }
}

// ---------- launch ----------

extern "C" void kernel_launch(void* const* d_in, const int* in_sizes, int n_in,
                              void* d_out, int out_size, void* d_ws, size_t ws_size,
                              hipStream_t stream) {
  (void)in_sizes; (void)n_in; (void)out_size;
  const float* x    = (const float*)d_in[0];
  const float* pos  = (const float*)d_in[1];
  const float* grid = (const float*)d_in[2];
  const float* Bx   = (const float*)d_in[3];
  float* out = (float*)d_out;

  char* wsb = (char*)d_ws;
  int* knn   = (int*)wsb;                                   // 131072 B
  float* kR1 = (float*)(wsb + 131072);
  float* kR2 = kR1 + NG * NG * CH;
  float* x1  = kR2 + NG * NG * CH;
  float* x2  = x1 + (size_t)MTOT * NG * CH;
  unsigned short* w1ta = (unsigned short*)(x2 + (size_t)MTOT * NG * CH);
  unsigned short* w2ta = w1ta + 65536;
  unsigned short* w1tb = w2ta + 65536;
  unsigned short* w2tb = w1tb + 65536;
  unsigned short* wx1f = w2tb + 65536;     // 16384 each
  unsigned short* wx2f = wx1f + 16384;
  unsigned short* wk1f = wx2f + 16384;
  unsigned short* wk2f = wk1f + 16384;
  uint2* t2g = (uint2*)(wk2f + 16384);     // 100,663,296 B
  size_t need = (size_t)26099712 + (size_t)MTOT * NG * 4 * 64 * 16;
  bool big_ws = ws_size >= need;

  knn_kernel<<<MTOT / 4, 256, 0, stream>>>(pos, knn);
  kbr_kernel<<<NG * NG, CH, 0, stream>>>(grid, (const float*)d_in[4],
                                         (const float*)d_in[9], (const float*)d_in[10],
                                         (const float*)d_in[11], (const float*)d_in[12],
                                         (const float*)d_in[14], (const float*)d_in[23],
                                         kR1, kR2);
  pack_all_kernel<<<160, 256, 0, stream>>>(
      (const float*)d_in[17], (const float*)d_in[19],
      (const float*)d_in[26], (const float*)d_in[28],
      (const float*)d_in[5], (const float*)d_in[7],
      (const float*)d_in[13], (const float*)d_in[22],
      w1ta, w2ta, w1tb, w2tb, wx1f, wx2f, wk1f, wk2f);

  if (big_ws) {
    // layer 1 (fused edge pipeline + t2 precompute + einsum)
    kbx_fused_kernel<<<MTOT, 256, 0, stream>>>(pos, knn, grid, Bx,
        (const uint4*)wx1f, (const float*)d_in[6],
        (const uint4*)wx2f, (const float*)d_in[8],
        (const uint4*)wk1f, (const uint4*)wk2f,
        x, kR1, t2g, x2);
    mlp_mfma_kernel<<<(MTOT * NG) / 32, 256, 0, stream>>>(x, x2,
        (const float*)d_in[15], (const float*)d_in[16],
        (const uint4*)w1ta, (const float*)d_in[18],
        (const uint4*)w2ta, (const float*)d_in[20],
        (const float*)d_in[21], out);
    // layer 2 (stream t2 + gather out + einsum)
    msg3b_kernel<<<MTOT, 256, 0, stream>>>(out, knn, (const uint2*)t2g, kR2, x2);
    mlp_mfma_kernel<<<(MTOT * NG) / 32, 256, 0, stream>>>(out, x2,
        (const float*)d_in[24], (const float*)d_in[25],
        (const uint4*)w1tb, (const float*)d_in[27],
        (const uint4*)w2tb, (const float*)d_in[29],
        (const float*)d_in[30], out);
  } else {
    msg_mfma_kernel<<<MTOT, 256, 0, stream>>>(x, pos, knn, grid, Bx,
        (const uint4*)wx1f, (const float*)d_in[6],
        (const uint4*)wx2f, (const float*)d_in[8],
        (const uint4*)wk1f, x1);
    einsum_kernel<<<MTOT, CH, 0, stream>>>(x1, kR1, x2);
    mlp_mfma_kernel<<<(MTOT * NG) / 32, 256, 0, stream>>>(x, x2,
        (const float*)d_in[15], (const float*)d_in[16],
        (const uint4*)w1ta, (const float*)d_in[18],
        (const uint4*)w2ta, (const float*)d_in[20],
        (const float*)d_in[21], out);
    msg_mfma_kernel<<<MTOT, 256, 0, stream>>>(out, pos, knn, grid, Bx,
        (const uint4*)wx1f, (const float*)d_in[6],
        (const uint4*)wx2f, (const float*)d_in[8],
        (const uint4*)wk2f, x1);
    einsum_kernel<<<MTOT, CH, 0, stream>>>(x1, kR2, x2);
    mlp_mfma_kernel<<<(MTOT * NG) / 32, 256, 0, stream>>>(out, x2,
        (const float*)d_in[24], (const float*)d_in[25],
        (const uint4*)w1tb, (const float*)d_in[27],
        (const uint4*)w2tb, (const float*)d_in[29],
        (const float*)d_in[30], out);
  }
}

// Round 15
// 197.119 us; speedup vs baseline: 1.3159x; 1.0356x over previous
//
#include <hip/hip_runtime.h>
#include <hip/hip_bf16.h>
#include <math.h>

#define BG 8
#define NNODES 256
#define KNN 16
#define NG 12
#define CH 128
#define MTOT 2048
#define TWO_PI_F 6.283185307179586f

typedef __attribute__((ext_vector_type(8))) short bfrag;
typedef __attribute__((ext_vector_type(4))) float f32x4;

// ---------- helpers ----------

__device__ __forceinline__ float gelu_t(float x) {
  float x3 = x * x * x;
  float y = 0.7978845608028654f * (x + 0.044715f * x3);
  float e = __expf(2.0f * y);
  float th = 1.0f - 2.0f / (e + 1.0f);
  return 0.5f * x * (1.0f + th);
}

__device__ __forceinline__ unsigned packbf2(float a, float b) {
  unsigned ua = __float_as_uint(a), ub = __float_as_uint(b);
  ua = (ua + 0x7fffu + ((ua >> 16) & 1u)) >> 16;    // RNE to bf16
  ub = (ub + 0x7fffu + ((ub >> 16) & 1u)) >> 16;
  return ua | (ub << 16);
}
__device__ __forceinline__ unsigned short f2bf(float f) {
  unsigned u = __float_as_uint(f);
  u = (u + 0x7fffu + ((u >> 16) & 1u)) >> 16;
  return (unsigned short)u;
}
__device__ __forceinline__ float ubf_lo(unsigned p) { return __uint_as_float(p << 16); }
__device__ __forceinline__ float ubf_hi(unsigned p) { return __uint_as_float(p & 0xffff0000u); }

// gelu via sigmoid form; exp2-domain, ~7 insts
__device__ __forceinline__ float gelu_s(float x) {
  const float A  = -2.0f * 0.7978845608028654f * 1.4426950408889634f;
  const float CA = A * 0.044715f;
  float x2 = x * x;
  float q  = __builtin_fmaf(CA, x2, A);
  float t  = x * q;
  float e; asm("v_exp_f32 %0, %1" : "=v"(e) : "v"(t));     // 2^t
  float d = 1.0f + e;
  float r; asm("v_rcp_f32 %0, %1" : "=v"(r) : "v"(d));
  return x * r;
}

__device__ __forceinline__ unsigned pkcvt(float a, float b) {
  unsigned r;
  asm("v_cvt_pk_bf16_f32 %0, %1, %2" : "=v"(r) : "v"(a), "v"(b));
  return r;
}

__device__ __forceinline__ void cossin(float w, float& c, float& s) {
  float f; asm("v_fract_f32 %0, %1" : "=v"(f) : "v"(w));
  asm("v_cos_f32 %0, %1" : "=v"(c) : "v"(f));
  asm("v_sin_f32 %0, %1" : "=v"(s) : "v"(f));
}

// 16-lane row sum via DPP rotate-adds: 4 VALU insts, no LDS/bpermute path.
__device__ __forceinline__ float dpp_sum16(float x) {
  asm("v_add_f32 %0, %0, %0 row_ror:8 row_mask:0xf bank_mask:0xf" : "+v"(x));
  asm("v_add_f32 %0, %0, %0 row_ror:4 row_mask:0xf bank_mask:0xf" : "+v"(x));
  asm("v_add_f32 %0, %0, %0 row_ror:2 row_mask:0xf bank_mask:0xf" : "+v"(x));
  asm("v_add_f32 %0, %0, %0 row_ror:1 row_mask:0xf bank_mask:0xf" : "+v"(x));
  return x;
}

__device__ __forceinline__ unsigned long long shfl_xor64(unsigned long long v, int st) {
  unsigned lo = (unsigned)v, hi = (unsigned)(v >> 32);
  lo = __shfl_xor(lo, st, 64);
  hi = __shfl_xor(hi, st, 64);
  return ((unsigned long long)hi << 32) | lo;
}

// ---------- kNN: one wave per node ----------

__global__ __launch_bounds__(256) void knn_kernel(const float* __restrict__ pos,
                                                  int* __restrict__ knn) {
  __shared__ float sx[NNODES], sy[NNODES], sz[NNODES];
  int w = threadIdx.x >> 6, lane = threadIdx.x & 63;
  int node = blockIdx.x * 4 + w;
  int b = node >> 8;
  int gbase = b * NNODES;
  int t = threadIdx.x;
  sx[t] = pos[(gbase + t) * 3 + 0];
  sy[t] = pos[(gbase + t) * 3 + 1];
  sz[t] = pos[(gbase + t) * 3 + 2];
  __syncthreads();
  int i = node & 255;
  float xi = sx[i], yi = sy[i], zi = sz[i];
  unsigned long long key[4];
#pragma unroll
  for (int u = 0; u < 4; ++u) {
    int j = lane * 4 + u;
    float dx = xi - sx[j], dy = yi - sy[j], dz = zi - sz[j];
    float d = dx * dx + dy * dy + dz * dz;
    key[u] = ((unsigned long long)__float_as_uint(d) << 32) | (unsigned)j;
  }
  {
    unsigned long long tmp;
#define CSWAP(a, bq) if (key[bq] < key[a]) { tmp = key[a]; key[a] = key[bq]; key[bq] = tmp; }
    CSWAP(0, 1) CSWAP(2, 3) CSWAP(0, 2) CSWAP(1, 3) CSWAP(1, 2)
#undef CSWAP
  }
  int ptr = 0;
#pragma unroll 1
  for (int r = 0; r < KNN; ++r) {
    unsigned long long cand = (ptr < 4) ? key[ptr] : ~0ULL;
    unsigned long long mn = cand;
#pragma unroll
    for (int st = 1; st < 64; st <<= 1) {
      unsigned long long o = shfl_xor64(mn, st);
      if (o < mn) mn = o;
    }
    if (cand == mn) ptr++;
    if (lane == 0) knn[node * KNN + r] = gbase + (int)(mn & 0xffffffffu);
  }
}

// ---------- kb_R -> kR ----------

__global__ void kbr_kernel(const float* __restrict__ grid, const float* __restrict__ BR,
                           const float* __restrict__ WR1, const float* __restrict__ bR1,
                           const float* __restrict__ WR2, const float* __restrict__ bR2,
                           const float* __restrict__ WkR1, const float* __restrict__ WkR2,
                           float* __restrict__ kR1, float* __restrict__ kR2) {
  int r = blockIdx.x;
  int p = r / NG, o = r % NG;
  int c = threadIdx.x;
  float a = grid[p * 3 + 0] * grid[o * 3 + 0] + grid[p * 3 + 1] * grid[o * 3 + 1] +
            grid[p * 3 + 2] * grid[o * 3 + 2];
  __shared__ float fb[CH], hh[CH];
  {
    int j = c & 63;
    float pv = TWO_PI_F * (a * BR[j]);
    fb[c] = (c < 64) ? cosf(pv) : sinf(pv);
  }
  __syncthreads();
  float acc = bR1[c];
  for (int i = 0; i < CH; ++i) acc += fb[i] * WR1[i * CH + c];
  float h1 = gelu_t(acc);
  __syncthreads();
  hh[c] = h1;
  __syncthreads();
  acc = bR2[c];
  for (int i = 0; i < CH; ++i) acc += hh[i] * WR2[i * CH + c];
  float h2 = gelu_t(acc);
  __syncthreads();
  fb[c] = h2;
  __syncthreads();
  float t1 = 0.f, t2 = 0.f;
  for (int i = 0; i < CH; ++i) {
    float v = fb[i];
    t1 += v * WkR1[i * CH + c];
    t2 += v * WkR2[i * CH + c];
  }
  kR1[r * CH + c] = t1;
  kR2[r * CH + c] = t2;
}

// ---------- fiber einsum (fallback path only) ----------

__global__ void einsum_kernel(const float* __restrict__ x1, const float* __restrict__ kR,
                              float* __restrict__ x2) {
  int m = blockIdx.x, c = threadIdx.x;
  float v[NG];
#pragma unroll
  for (int o = 0; o < NG; ++o) v[o] = x1[((size_t)m * NG + o) * CH + c];
#pragma unroll
  for (int p = 0; p < NG; ++p) {
    float acc = 0.f;
#pragma unroll
    for (int o = 0; o < NG; ++o) acc += v[o] * kR[(p * NG + o) * CH + c];
    x2[((size_t)m * NG + p) * CH + c] = acc * (1.0f / NG);
  }
}

// ---------- weight fragment packing (all 8 matrices, one launch) ----------

__device__ __forceinline__ void pack_body(const float* __restrict__ W, int K, int N,
                                          unsigned short* __restrict__ out, int tid) {
  int lane = tid & 63;
  int t = tid >> 6;
  int ksteps = K / 32;
  int ks = t % ksteps, tile = t / ksteps;
  int col = tile * 16 + (lane & 15);
  int k0 = ks * 32 + (lane >> 4) * 8;
#pragma unroll
  for (int j = 0; j < 8; ++j)
    out[(size_t)tid * 8 + j] = f2bf(W[(size_t)(k0 + j) * N + col]);
}

__global__ __launch_bounds__(256) void pack_all_kernel(
    const float* __restrict__ W1a, const float* __restrict__ W2a,
    const float* __restrict__ W1b, const float* __restrict__ W2b,
    const float* __restrict__ wx1, const float* __restrict__ wx2,
    const float* __restrict__ wk1, const float* __restrict__ wk2,
    unsigned short* __restrict__ o1a, unsigned short* __restrict__ o2a,
    unsigned short* __restrict__ o1b, unsigned short* __restrict__ o2b,
    unsigned short* __restrict__ ox1, unsigned short* __restrict__ ox2,
    unsigned short* __restrict__ ok1, unsigned short* __restrict__ ok2) {
  int blk = blockIdx.x;
  if (blk < 32)        pack_body(W1a, CH, 4 * CH, o1a, blk * 256 + threadIdx.x);
  else if (blk < 64)   pack_body(W2a, 4 * CH, CH, o2a, (blk - 32) * 256 + threadIdx.x);
  else if (blk < 96)   pack_body(W1b, CH, 4 * CH, o1b, (blk - 64) * 256 + threadIdx.x);
  else if (blk < 128)  pack_body(W2b, 4 * CH, CH, o2b, (blk - 96) * 256 + threadIdx.x);
  else if (blk < 136)  pack_body(wx1, CH, CH, ox1, (blk - 128) * 256 + threadIdx.x);
  else if (blk < 144)  pack_body(wx2, CH, CH, ox2, (blk - 136) * 256 + threadIdx.x);
  else if (blk < 152)  pack_body(wk1, CH, CH, ok1, (blk - 144) * 256 + threadIdx.x);
  else                 pack_body(wk2, CH, CH, ok2, (blk - 152) * 256 + threadIdx.x);
}

// ---------- fused layer-1 edge pipeline + t2 precompute ----------
// r13 structure + T5 s_setprio around MFMA clusters (waves here are
// barrier-free and phase-skewed -> scheduler role diversity, attn-like regime).

__global__ __launch_bounds__(256) void kbx_fused_kernel(
    const float* __restrict__ pos, const int* __restrict__ knn,
    const float* __restrict__ grid, const float* __restrict__ Bx,
    const uint4* __restrict__ w1f, const float* __restrict__ bx1,
    const uint4* __restrict__ w2f, const float* __restrict__ bx2,
    const uint4* __restrict__ wk1f, const uint4* __restrict__ wk2f,
    const float* __restrict__ x, const float* __restrict__ kR,
    uint2* __restrict__ t2g, float* __restrict__ x2out) {
  __shared__ uint4 hb[4][3][128];          // 24 KB half-tile transpose buffers
  float* x1s = (float*)hb;                 // aliased AFTER barrier (6 KB)
  int m = blockIdx.x;
  int tid = threadIdx.x, lane = tid & 63, w = tid >> 6;
  int r = lane & 15, gq = lane >> 4;

  int src = knn[m * KNN + r];
  float rx = pos[src * 3 + 0] - pos[m * 3 + 0];
  float ry = pos[src * 3 + 1] - pos[m * 3 + 1];
  float rz = pos[src * 3 + 2] - pos[m * 3 + 2];

  float4 brA0 = *(const float4*)(Bx + gq * 8);
  float4 brA1 = *(const float4*)(Bx + gq * 8 + 4);
  float4 brB0 = *(const float4*)(Bx + 32 + gq * 8);
  float4 brB1 = *(const float4*)(Bx + 32 + gq * 8 + 4);
  float4 bzA0 = *(const float4*)(Bx + 64 + gq * 8);
  float4 bzA1 = *(const float4*)(Bx + 64 + gq * 8 + 4);
  float4 bzB0 = *(const float4*)(Bx + 96 + gq * 8);
  float4 bzB1 = *(const float4*)(Bx + 96 + gq * 8 + 4);
  float brA[8] = {brA0.x, brA0.y, brA0.z, brA0.w, brA1.x, brA1.y, brA1.z, brA1.w};
  float brB[8] = {brB0.x, brB0.y, brB0.z, brB0.w, brB1.x, brB1.y, brB1.z, brB1.w};
  float bzA[8] = {bzA0.x, bzA0.y, bzA0.z, bzA0.w, bzA1.x, bzA1.y, bzA1.z, bzA1.w};
  float bzB[8] = {bzB0.x, bzB0.y, bzB0.z, bzB0.w, bzB1.x, bzB1.y, bzB1.z, bzB1.w};

  // ---- RFF features as B-fragments for all 3 tiles
  bfrag ff[3][4];
#pragma unroll
  for (int t = 0; t < 3; ++t) {
    int o = w * 3 + t;
    float gx = grid[o * 3 + 0], gy = grid[o * 3 + 1], gz = grid[o * 3 + 2];
    float z = rx * gx + ry * gy + rz * gz;
    float ux = rx - z * gx, uy = ry - z * gy, uz = rz - z * gz;
    float rxy = sqrtf(ux * ux + uy * uy + uz * uz);
    float cA[8], sA[8], cB[8], sB[8];
#pragma unroll
    for (int u = 0; u < 8; ++u) {
      float wA = __builtin_fmaf(z, bzA[u], rxy * brA[u]);
      float wB = __builtin_fmaf(z, bzB[u], rxy * brB[u]);
      cossin(wA, cA[u], sA[u]);
      cossin(wB, cB[u], sB[u]);
    }
    uint4 q;
    q.x = pkcvt(cA[0], cA[1]); q.y = pkcvt(cA[2], cA[3]);
    q.z = pkcvt(cA[4], cA[5]); q.w = pkcvt(cA[6], cA[7]);
    ff[t][0] = __builtin_bit_cast(bfrag, q);
    q.x = pkcvt(cB[0], cB[1]); q.y = pkcvt(cB[2], cB[3]);
    q.z = pkcvt(cB[4], cB[5]); q.w = pkcvt(cB[6], cB[7]);
    ff[t][1] = __builtin_bit_cast(bfrag, q);
    q.x = pkcvt(sA[0], sA[1]); q.y = pkcvt(sA[2], sA[3]);
    q.z = pkcvt(sA[4], sA[5]); q.w = pkcvt(sA[6], sA[7]);
    ff[t][2] = __builtin_bit_cast(bfrag, q);
    q.x = pkcvt(sB[0], sB[1]); q.y = pkcvt(sB[2], sB[3]);
    q.z = pkcvt(sB[4], sB[5]); q.w = pkcvt(sB[6], sB[7]);
    ff[t][3] = __builtin_bit_cast(bfrag, q);
  }

  // ---- GEMM1: h1 = gelu(f @ Wx1 + bx1), half-phase LDS transpose
  bfrag h1f[3][4];
#pragma unroll
  for (int h = 0; h < 2; ++h) {           // fully unrolled (rule #20)
#pragma unroll 2
    for (int jl = 0; jl < 4; ++jl) {
      int jt = h * 4 + jl;
      bfrag wf[4];
#pragma unroll
      for (int ks = 0; ks < 4; ++ks)
        wf[ks] = __builtin_bit_cast(bfrag, w1f[(jt * 4 + ks) * 64 + lane]);
      float4 bb = *(const float4*)(bx1 + jt * 16 + gq * 4);
      int cu = jl * 2 + (gq >> 1);         // 0..7 within half
#pragma unroll
      for (int t = 0; t < 3; ++t) {
        f32x4 acc;
        acc[0] = bb.x; acc[1] = bb.y; acc[2] = bb.z; acc[3] = bb.w;
        __builtin_amdgcn_s_setprio(1);
#pragma unroll
        for (int ks = 0; ks < 4; ++ks)
          acc = __builtin_amdgcn_mfma_f32_16x16x32_bf16(wf[ks], ff[t][ks], acc, 0, 0, 0);
        __builtin_amdgcn_s_setprio(0);
        unsigned p0 = pkcvt(gelu_s(acc[0]), gelu_s(acc[1]));
        unsigned p1 = pkcvt(gelu_s(acc[2]), gelu_s(acc[3]));
        ((uint2*)&hb[w][t][0])[r * 16 + ((cu ^ (r & 7)) << 1) + (gq & 1)] =
            make_uint2(p0, p1);
      }
    }
#pragma unroll
    for (int t = 0; t < 3; ++t)
#pragma unroll
      for (int ksl = 0; ksl < 2; ++ksl)
        h1f[t][h * 2 + ksl] = __builtin_bit_cast(bfrag,
            hb[w][t][r * 8 + ((ksl * 4 + gq) ^ (r & 7))]);
  }

  // ---- GEMM2: h2 = gelu(h1 @ Wx2 + bx2), half-phase LDS transpose
  bfrag h2f[3][4];
#pragma unroll
  for (int h = 0; h < 2; ++h) {
#pragma unroll 2
    for (int jl = 0; jl < 4; ++jl) {
      int jt = h * 4 + jl;
      bfrag wf[4];
#pragma unroll
      for (int ks = 0; ks < 4; ++ks)
        wf[ks] = __builtin_bit_cast(bfrag, w2f[(jt * 4 + ks) * 64 + lane]);
      float4 bb = *(const float4*)(bx2 + jt * 16 + gq * 4);
      int cu = jl * 2 + (gq >> 1);
#pragma unroll
      for (int t = 0; t < 3; ++t) {
        f32x4 acc;
        acc[0] = bb.x; acc[1] = bb.y; acc[2] = bb.z; acc[3] = bb.w;
        __builtin_amdgcn_s_setprio(1);
#pragma unroll
        for (int ks = 0; ks < 4; ++ks)
          acc = __builtin_amdgcn_mfma_f32_16x16x32_bf16(wf[ks], h1f[t][ks], acc, 0, 0, 0);
        __builtin_amdgcn_s_setprio(0);
        unsigned p0 = pkcvt(gelu_s(acc[0]), gelu_s(acc[1]));
        unsigned p1 = pkcvt(gelu_s(acc[2]), gelu_s(acc[3]));
        ((uint2*)&hb[w][t][0])[r * 16 + ((cu ^ (r & 7)) << 1) + (gq & 1)] =
            make_uint2(p0, p1);
      }
    }
#pragma unroll
    for (int t = 0; t < 3; ++t)
#pragma unroll
      for (int ksl = 0; ksl < 2; ++ksl)
        h2f[t][h * 2 + ksl] = __builtin_bit_cast(bfrag,
            hb[w][t][r * 8 + ((ksl * 4 + gq) ^ (r & 7))]);
  }

  __syncthreads();   // all transpose reads done -> x1s may alias hb

  // ---- merged GEMM3a+3b with DPP reductions
#pragma unroll 2
  for (int jt = 0; jt < 8; ++jt) {
    bfrag wfa[4], wfb[4];
#pragma unroll
    for (int ks = 0; ks < 4; ++ks) {
      wfa[ks] = __builtin_bit_cast(bfrag, wk1f[(jt * 4 + ks) * 64 + lane]);
      wfb[ks] = __builtin_bit_cast(bfrag, wk2f[(jt * 4 + ks) * 64 + lane]);
    }
#pragma unroll
    for (int t = 0; t < 3; ++t) {
      int o = w * 3 + t;
      int tile = m * NG + o;
      float4 xv = *(const float4*)(x + ((size_t)src * NG + o) * CH + jt * 16 + gq * 4);
      f32x4 acc1, acc2;
      acc1[0] = 0.f; acc1[1] = 0.f; acc1[2] = 0.f; acc1[3] = 0.f;
      acc2[0] = 0.f; acc2[1] = 0.f; acc2[2] = 0.f; acc2[3] = 0.f;
      __builtin_amdgcn_s_setprio(1);
#pragma unroll
      for (int ks = 0; ks < 4; ++ks) {
        acc1 = __builtin_amdgcn_mfma_f32_16x16x32_bf16(wfa[ks], h2f[t][ks], acc1, 0, 0, 0);
        acc2 = __builtin_amdgcn_mfma_f32_16x16x32_bf16(wfb[ks], h2f[t][ks], acc2, 0, 0, 0);
      }
      __builtin_amdgcn_s_setprio(0);
      uint2 pv;
      pv.x = pkcvt(acc2[0], acc2[1]);
      pv.y = pkcvt(acc2[2], acc2[3]);
      t2g[((size_t)tile * 8 + jt) * 64 + lane] = pv;
      float s0 = dpp_sum16(acc1[0] * xv.x);
      float s1 = dpp_sum16(acc1[1] * xv.y);
      float s2 = dpp_sum16(acc1[2] * xv.z);
      float s3 = dpp_sum16(acc1[3] * xv.w);
      if (r == 0) {
        int c0 = jt * 16 + gq * 4;
        float4 sv;
        sv.x = s0 * (1.f / 16.f); sv.y = s1 * (1.f / 16.f);
        sv.z = s2 * (1.f / 16.f); sv.w = s3 * (1.f / 16.f);
        *(float4*)&x1s[o * CH + c0] = sv;
      }
    }
  }
  __syncthreads();

  // ---- fused fiber einsum
  int c = tid & 127, p0 = tid >> 7;
  float v[NG];
#pragma unroll
  for (int o = 0; o < NG; ++o) v[o] = x1s[o * CH + c];
#pragma unroll
  for (int pp = 0; pp < 6; ++pp) {
    int p = p0 * 6 + pp;
    float acc = 0.f;
#pragma unroll
    for (int o = 0; o < NG; ++o) acc += v[o] * kR[(p * NG + o) * CH + c];
    x2out[((size_t)m * NG + p) * CH + c] = acc * (1.0f / NG);
  }
}

// ---------- layer-2: stream t2, gather out, k-mean (DPP), fused einsum ----------

__global__ __launch_bounds__(256) void msg3b_kernel(
    const float* __restrict__ x, const int* __restrict__ knn,
    const uint2* __restrict__ t2g, const float* __restrict__ kR,
    float* __restrict__ x2out) {
  __shared__ float x1s[NG][CH];   // 6 KB
  int m = blockIdx.x;
  int tid = threadIdx.x, lane = tid & 63, w = tid >> 6;
  int r = lane & 15, gq = lane >> 4;
  int src = knn[m * KNN + r];

#pragma unroll 1
  for (int jt = 0; jt < 8; ++jt) {
#pragma unroll
    for (int t = 0; t < 3; ++t) {
      int o = w * 3 + t;
      int tile = m * NG + o;
      uint2 tv = t2g[((size_t)tile * 8 + jt) * 64 + lane];
      float4 xv = *(const float4*)(x + ((size_t)src * NG + o) * CH + jt * 16 + gq * 4);
      float a0 = dpp_sum16(ubf_lo(tv.x) * xv.x);
      float a1 = dpp_sum16(ubf_hi(tv.x) * xv.y);
      float a2 = dpp_sum16(ubf_lo(tv.y) * xv.z);
      float a3 = dpp_sum16(ubf_hi(tv.y) * xv.w);
      if (r == 0) {
        int c0 = jt * 16 + gq * 4;
        x1s[o][c0 + 0] = a0 * (1.f / 16.f);
        x1s[o][c0 + 1] = a1 * (1.f / 16.f);
        x1s[o][c0 + 2] = a2 * (1.f / 16.f);
        x1s[o][c0 + 3] = a3 * (1.f / 16.f);
      }
    }
  }
  __syncthreads();

  int c = tid & 127, p0 = tid >> 7;
  float v[NG];
#pragma unroll
  for (int o = 0; o < NG; ++o) v[o] = x1s[o][c];
#pragma unroll
  for (int pp = 0; pp < 6; ++pp) {
    int p = p0 * 6 + pp;
    float acc = 0.f;
#pragma unroll
    for (int o = 0; o < NG; ++o) acc += v[o] * kR[(p * NG + o) * CH + c];
    x2out[((size_t)m * NG + p) * CH + c] = acc * (1.0f / NG);
  }
}

// ---------- FALLBACK: round-4 fused edge pipeline (used if ws too small) ----------

__global__ __launch_bounds__(256) void msg_mfma_kernel(
    const float* __restrict__ x, const float* __restrict__ pos,
    const int* __restrict__ knn, const float* __restrict__ grid,
    const float* __restrict__ Bx,
    const uint4* __restrict__ w1f, const float* __restrict__ bx1,
    const uint4* __restrict__ w2f, const float* __restrict__ bx2,
    const uint4* __restrict__ wkf,
    float* __restrict__ x1out) {
  __shared__ uint4 hb[4][3][256];
  int m = blockIdx.x;
  int tid = threadIdx.x, lane = tid & 63, w = tid >> 6;
  int r = lane & 15, gq = lane >> 4;

  int src = knn[m * KNN + r];
  float rx = pos[src * 3 + 0] - pos[m * 3 + 0];
  float ry = pos[src * 3 + 1] - pos[m * 3 + 1];
  float rz = pos[src * 3 + 2] - pos[m * 3 + 2];

  bfrag ff[3][4];
#pragma unroll
  for (int t = 0; t < 3; ++t) {
    int o = w * 3 + t;
    float gx = grid[o * 3 + 0], gy = grid[o * 3 + 1], gz = grid[o * 3 + 2];
    float z = rx * gx + ry * gy + rz * gz;
    float ux = rx - z * gx, uy = ry - z * gy, uz = rz - z * gz;
    float rxy = sqrtf(ux * ux + uy * uy + uz * uz);
#pragma unroll
    for (int ks = 0; ks < 4; ++ks) {
      uint4 q;
      unsigned pk[4];
#pragma unroll
      for (int jh = 0; jh < 4; ++jh) {
        float v[2];
#pragma unroll
        for (int u = 0; u < 2; ++u) {
          int i = ks * 32 + gq * 8 + jh * 2 + u;
          int j = i & 63;
          float pv = TWO_PI_F * (rxy * Bx[j] + z * Bx[64 + j]);
          v[u] = (i < 64) ? __cosf(pv) : __sinf(pv);
        }
        pk[jh] = packbf2(v[0], v[1]);
      }
      q.x = pk[0]; q.y = pk[1]; q.z = pk[2]; q.w = pk[3];
      ff[t][ks] = __builtin_bit_cast(bfrag, q);
    }
  }

#pragma unroll 1
  for (int jt = 0; jt < 8; ++jt) {
    bfrag wf[4];
#pragma unroll
    for (int ks = 0; ks < 4; ++ks)
      wf[ks] = __builtin_bit_cast(bfrag, w1f[(jt * 4 + ks) * 64 + lane]);
    float4 bb = *(const float4*)(bx1 + jt * 16 + gq * 4);
    int cu = jt * 2 + (gq >> 1);
#pragma unroll
    for (int t = 0; t < 3; ++t) {
      f32x4 acc;
      acc[0] = bb.x; acc[1] = bb.y; acc[2] = bb.z; acc[3] = bb.w;
#pragma unroll
      for (int ks = 0; ks < 4; ++ks)
        acc = __builtin_amdgcn_mfma_f32_16x16x32_bf16(wf[ks], ff[t][ks], acc, 0, 0, 0);
      unsigned p0 = packbf2(gelu_t(acc[0]), gelu_t(acc[1]));
      unsigned p1 = packbf2(gelu_t(acc[2]), gelu_t(acc[3]));
      ((uint2*)&hb[w][t][0])[r * 32 + ((cu ^ r) << 1) + (gq & 1)] = make_uint2(p0, p1);
    }
  }
  bfrag h1f[3][4];
#pragma unroll
  for (int t = 0; t < 3; ++t)
#pragma unroll
    for (int ks = 0; ks < 4; ++ks)
      h1f[t][ks] = __builtin_bit_cast(bfrag, hb[w][t][r * 16 + ((ks * 4 + gq) ^ r)]);

#pragma unroll 1
  for (int jt = 0; jt < 8; ++jt) {
    bfrag wf[4];
#pragma unroll
    for (int ks = 0; ks < 4; ++ks)
      wf[ks] = __builtin_bit_cast(bfrag, w2f[(jt * 4 + ks) * 64 + lane]);
    float4 bb = *(const float4*)(bx2 + jt * 16 + gq * 4);
    int cu = jt * 2 + (gq >> 1);
#pragma unroll
    for (int t = 0; t < 3; ++t) {
      f32x4 acc;
      acc[0] = bb.x; acc[1] = bb.y; acc[2] = bb.z; acc[3] = bb.w;
#pragma unroll
      for (int ks = 0; ks < 4; ++ks)
        acc = __builtin_amdgcn_mfma_f32_16x16x32_bf16(wf[ks], h1f[t][ks], acc, 0, 0, 0);
      unsigned p0 = packbf2(gelu_t(acc[0]), gelu_t(acc[1]));
      unsigned p1 = packbf2(gelu_t(acc[2]), gelu_t(acc[3]));
      ((uint2*)&hb[w][t][0])[r * 32 + ((cu ^ r) << 1) + (gq & 1)] = make_uint2(p0, p1);
    }
  }
  bfrag h2f[3][4];
#pragma unroll
  for (int t = 0; t < 3; ++t)
#pragma unroll
    for (int ks = 0; ks < 4; ++ks)
      h2f[t][ks] = __builtin_bit_cast(bfrag, hb[w][t][r * 16 + ((ks * 4 + gq) ^ r)]);

#pragma unroll 1
  for (int jt = 0; jt < 8; ++jt) {
    bfrag wf[4];
#pragma unroll
    for (int ks = 0; ks < 4; ++ks)
      wf[ks] = __builtin_bit_cast(bfrag, wkf[(jt * 4 + ks) * 64 + lane]);
#pragma unroll
    for (int t = 0; t < 3; ++t) {
      int o = w * 3 + t;
      f32x4 acc;
      acc[0] = 0.f; acc[1] = 0.f; acc[2] = 0.f; acc[3] = 0.f;
#pragma unroll
      for (int ks = 0; ks < 4; ++ks)
        acc = __builtin_amdgcn_mfma_f32_16x16x32_bf16(wf[ks], h2f[t][ks], acc, 0, 0, 0);
      float4 xv = *(const float4*)(x + ((size_t)src * NG + o) * CH + jt * 16 + gq * 4);
      acc[0] *= xv.x; acc[1] *= xv.y; acc[2] *= xv.z; acc[3] *= xv.w;
#pragma unroll
      for (int st = 1; st < 16; st <<= 1) {
        acc[0] += __shfl_xor(acc[0], st, 64);
        acc[1] += __shfl_xor(acc[1], st, 64);
        acc[2] += __shfl_xor(acc[2], st, 64);
        acc[3] += __shfl_xor(acc[3], st, 64);
      }
      if (r == 0) {
        float4 sv;
        sv.x = acc[0] * (1.f / 16.f); sv.y = acc[1] * (1.f / 16.f);
        sv.z = acc[2] * (1.f / 16.f); sv.w = acc[3] * (1.f / 16.f);
        *(float4*)(x1out + ((size_t)m * NG + o) * CH + jt * 16 + gq * 4) = sv;
      }
    }
  }
}

// ---------- LN + ConvNeXt MLP via MFMA, 32 rows/block ----------

__global__ __launch_bounds__(256) void mlp_mfma_kernel(
    const float* __restrict__ xin, const float* __restrict__ x2,
    const float* __restrict__ g, const float* __restrict__ b,
    const uint4* __restrict__ w1t, const float* __restrict__ b1,
    const uint4* __restrict__ w2t, const float* __restrict__ b2,
    const float* __restrict__ s, float* __restrict__ xout) {
  __shared__ uint4 smem[2560];
  int tid = threadIdx.x;
  int rowbase = blockIdx.x * 32;

  // ---- LN: thread handles rows (tid>>4) and (tid>>4)+16
#pragma unroll
  for (int rg = 0; rg < 2; ++rg) {
    int row = (tid >> 4) + rg * 16, p = tid & 15;
    const float4* xr = (const float4*)(x2 + (size_t)(rowbase + row) * CH + p * 8);
    float4 v0 = xr[0], v1 = xr[1];
    float sum = v0.x + v0.y + v0.z + v0.w + v1.x + v1.y + v1.z + v1.w;
    sum = dpp_sum16(sum);
    float mu = sum * (1.0f / CH);
    float sq = 0.f;
    {
      float d;
      d = v0.x - mu; sq += d * d; d = v0.y - mu; sq += d * d;
      d = v0.z - mu; sq += d * d; d = v0.w - mu; sq += d * d;
      d = v1.x - mu; sq += d * d; d = v1.y - mu; sq += d * d;
      d = v1.z - mu; sq += d * d; d = v1.w - mu; sq += d * d;
    }
    sq = dpp_sum16(sq);
    float rstd = rsqrtf(sq * (1.0f / CH) + 1e-5f);
    const float4* gv = (const float4*)(g + p * 8);
    const float4* bv = (const float4*)(b + p * 8);
    float4 g0 = gv[0], g1 = gv[1], b0 = bv[0], b1v = bv[1];
    float n0 = (v0.x - mu) * rstd * g0.x + b0.x;
    float n1 = (v0.y - mu) * rstd * g0.y + b0.y;
    float n2 = (v0.z - mu) * rstd * g0.z + b0.z;
    float n3 = (v0.w - mu) * rstd * g0.w + b0.w;
    float n4 = (v1.x - mu) * rstd * g1.x + b1v.x;
    float n5 = (v1.y - mu) * rstd * g1.y + b1v.y;
    float n6 = (v1.z - mu) * rstd * g1.z + b1v.z;
    float n7 = (v1.w - mu) * rstd * g1.w + b1v.w;
    uint4 pk;
    pk.x = pkcvt(n0, n1); pk.y = pkcvt(n2, n3);
    pk.z = pkcvt(n4, n5); pk.w = pkcvt(n6, n7);
    smem[row * 16 + (p ^ (row & 15))] = pk;
  }
  __syncthreads();

  int lane = tid & 63, w = tid >> 6;
  int r = lane & 15, gq = lane >> 4;

  bfrag xf[2][4];
#pragma unroll
  for (int rg = 0; rg < 2; ++rg)
#pragma unroll
    for (int ks = 0; ks < 4; ++ks)
      xf[rg][ks] = __builtin_bit_cast(bfrag,
          smem[(rg * 16 + r) * 16 + ((ks * 4 + gq) ^ r)]);

  uint2* hb2 = (uint2*)smem;
#pragma unroll 2
  for (int jj = 0; jj < 8; ++jj) {
    int jt = w * 8 + jj;
    bfrag a[4];
#pragma unroll
    for (int ks = 0; ks < 4; ++ks)
      a[ks] = __builtin_bit_cast(bfrag, w1t[(jt * 4 + ks) * 64 + lane]);
    float4 bb = *(const float4*)(b1 + jt * 16 + gq * 4);
    int sl = jt * 2 + (gq >> 1);
#pragma unroll
    for (int rg = 0; rg < 2; ++rg) {
      f32x4 acc;
      acc[0] = bb.x; acc[1] = bb.y; acc[2] = bb.z; acc[3] = bb.w;
      __builtin_amdgcn_s_setprio(1);
#pragma unroll
      for (int ks = 0; ks < 4; ++ks)
        acc = __builtin_amdgcn_mfma_f32_16x16x32_bf16(a[ks], xf[rg][ks], acc, 0, 0, 0);
      __builtin_amdgcn_s_setprio(0);
      unsigned p0 = pkcvt(gelu_s(acc[0]), gelu_s(acc[1]));
      unsigned p1 = pkcvt(gelu_s(acc[2]), gelu_s(acc[3]));
      int row = rg * 16 + r;
      hb2[1024 + row * 128 + ((sl ^ r) << 1) + (gq & 1)] = make_uint2(p0, p1);
    }
  }
  __syncthreads();

#pragma unroll 2
  for (int cc = 0; cc < 2; ++cc) {
    int ct = w * 2 + cc;
    float4 bb = *(const float4*)(b2 + ct * 16 + gq * 4);
    f32x4 acc0, acc1;
    acc0[0] = bb.x; acc0[1] = bb.y; acc0[2] = bb.z; acc0[3] = bb.w;
    acc1[0] = bb.x; acc1[1] = bb.y; acc1[2] = bb.z; acc1[3] = bb.w;
#pragma unroll
    for (int ks = 0; ks < 16; ++ks) {
      bfrag wf = __builtin_bit_cast(bfrag, w2t[(ct * 16 + ks) * 64 + lane]);
      bfrag h0 = __builtin_bit_cast(bfrag,
          smem[512 + r * 64 + ((ks * 4 + gq) ^ r)]);
      bfrag h1v = __builtin_bit_cast(bfrag,
          smem[512 + (16 + r) * 64 + ((ks * 4 + gq) ^ r)]);
      __builtin_amdgcn_s_setprio(1);
      acc0 = __builtin_amdgcn_mfma_f32_16x16x32_bf16(wf, h0, acc0, 0, 0, 0);
      acc1 = __builtin_amdgcn_mfma_f32_16x16x32_bf16(wf, h1v, acc1, 0, 0, 0);
      __builtin_amdgcn_s_setprio(0);
    }
    int c0 = ct * 16 + gq * 4;
    float4 sv = *(const float4*)(s + c0);
#pragma unroll
    for (int rg = 0; rg < 2; ++rg) {
      size_t ro = (size_t)(rowbase + rg * 16 + r) * CH + c0;
      float4 xi = *(const float4*)(xin + ro);
      float4 ov;
      float a0 = (rg == 0) ? acc0[0] : acc1[0];
      float a1 = (rg == 0) ? acc0[1] : acc1[1];
      float a2 = (rg == 0) ? acc0[2] : acc1[2];
      float a3 = (rg == 0) ? acc0[3] : acc1[3];
      ov.x = xi.x + sv.x * a0;
      ov.y = xi.y + sv.y * a1;
      ov.z = xi.z + sv.z * a2;
      ov.w = xi.w + sv.w * a3;
      *(float4*)(xout + ro) = ov;
    }
  }
}

// ---------- launch ----------

extern "C" void kernel_launch(void* const* d_in, const int* in_sizes, int n_in,
                              void* d_out, int out_size, void* d_ws, size_t ws_size,
                              hipStream_t stream) {
  (void)in_sizes; (void)n_in; (void)out_size;
  const float* x    = (const float*)d_in[0];
  const float* pos  = (const float*)d_in[1];
  const float* grid = (const float*)d_in[2];
  const float* Bx   = (const float*)d_in[3];
  float* out = (float*)d_out;

  char* wsb = (char*)d_ws;
  int* knn   = (int*)wsb;                                   // 131072 B
  float* kR1 = (float*)(wsb + 131072);
  float* kR2 = kR1 + NG * NG * CH;
  float* x1  = kR2 + NG * NG * CH;
  float* x2  = x1 + (size_t)MTOT * NG * CH;
  unsigned short* w1ta = (unsigned short*)(x2 + (size_t)MTOT * NG * CH);
  unsigned short* w2ta = w1ta + 65536;
  unsigned short* w1tb = w2ta + 65536;
  unsigned short* w2tb = w1tb + 65536;
  unsigned short* wx1f = w2tb + 65536;     // 16384 each
  unsigned short* wx2f = wx1f + 16384;
  unsigned short* wk1f = wx2f + 16384;
  unsigned short* wk2f = wk1f + 16384;
  uint2* t2g = (uint2*)(wk2f + 16384);     // 100,663,296 B
  size_t need = (size_t)26099712 + (size_t)MTOT * NG * 4 * 64 * 16;
  bool big_ws = ws_size >= need;

  knn_kernel<<<MTOT / 4, 256, 0, stream>>>(pos, knn);
  kbr_kernel<<<NG * NG, CH, 0, stream>>>(grid, (const float*)d_in[4],
                                         (const float*)d_in[9], (const float*)d_in[10],
                                         (const float*)d_in[11], (const float*)d_in[12],
                                         (const float*)d_in[14], (const float*)d_in[23],
                                         kR1, kR2);
  pack_all_kernel<<<160, 256, 0, stream>>>(
      (const float*)d_in[17], (const float*)d_in[19],
      (const float*)d_in[26], (const float*)d_in[28],
      (const float*)d_in[5], (const float*)d_in[7],
      (const float*)d_in[13], (const float*)d_in[22],
      w1ta, w2ta, w1tb, w2tb, wx1f, wx2f, wk1f, wk2f);

  if (big_ws) {
    // layer 1 (fused edge pipeline + t2 precompute + einsum)
    kbx_fused_kernel<<<MTOT, 256, 0, stream>>>(pos, knn, grid, Bx,
        (const uint4*)wx1f, (const float*)d_in[6],
        (const uint4*)wx2f, (const float*)d_in[8],
        (const uint4*)wk1f, (const uint4*)wk2f,
        x, kR1, t2g, x2);
    mlp_mfma_kernel<<<(MTOT * NG) / 32, 256, 0, stream>>>(x, x2,
        (const float*)d_in[15], (const float*)d_in[16],
        (const uint4*)w1ta, (const float*)d_in[18],
        (const uint4*)w2ta, (const float*)d_in[20],
        (const float*)d_in[21], out);
    // layer 2 (stream t2 + gather out + einsum)
    msg3b_kernel<<<MTOT, 256, 0, stream>>>(out, knn, (const uint2*)t2g, kR2, x2);
    mlp_mfma_kernel<<<(MTOT * NG) / 32, 256, 0, stream>>>(out, x2,
        (const float*)d_in[24], (const float*)d_in[25],
        (const uint4*)w1tb, (const float*)d_in[27],
        (const uint4*)w2tb, (const float*)d_in[29],
        (const float*)d_in[30], out);
  } else {
    msg_mfma_kernel<<<MTOT, 256, 0, stream>>>(x, pos, knn, grid, Bx,
        (const uint4*)wx1f, (const float*)d_in[6],
        (const uint4*)wx2f, (const float*)d_in[8],
        (const uint4*)wk1f, x1);
    einsum_kernel<<<MTOT, CH, 0, stream>>>(x1, kR1, x2);
    mlp_mfma_kernel<<<(MTOT * NG) / 32, 256, 0, stream>>>(x, x2,
        (const float*)d_in[15], (const float*)d_in[16],
        (const uint4*)w1ta, (const float*)d_in[18],
        (const uint4*)w2ta, (const float*)d_in[20],
        (const float*)d_in[21], out);
    msg_mfma_kernel<<<MTOT, 256, 0, stream>>>(out, pos, knn, grid, Bx,
        (const uint4*)wx1f, (const float*)d_in[6],
        (const uint4*)wx2f, (const float*)d_in[8],
        (const uint4*)wk2f, x1);
    einsum_kernel<<<MTOT, CH, 0, stream>>>(x1, kR2, x2);
    mlp_mfma_kernel<<<(MTOT * NG) / 32, 256, 0, stream>>>(out, x2,
        (const float*)d_in[24], (const float*)d_in[25],
        (const uint4*)w1tb, (const float*)d_in[27],
        (const uint4*)w2tb, (const float*)d_in[29],
        (const float*)d_in[30], out);
  }
}